// Round 4
// baseline (938.616 us; speedup 1.0000x reference)
//
#include <hip/hip_runtime.h>
#include <hip/hip_bf16.h>

#define FLT_BIG 3.0e38f

// ---------------------------------------------------------------------------
// kNN via radix select (unchanged).
// ---------------------------------------------------------------------------
__global__ __launch_bounds__(256) void knn_select_kernel(
    const float* __restrict__ x, int N_pts, int K, int P, int* __restrict__ idx_out) {
    int bp = blockIdx.x;
    int b = bp / P, p = bp - b * P;
    const float* xyz = x + (size_t)b * 24576;
    __shared__ unsigned int keys[4096];
    __shared__ unsigned int hist[2048];
    __shared__ unsigned int scanbuf[256];
    __shared__ unsigned int candK[512];
    __shared__ int candI[512];
    __shared__ int outIdx[64];
    __shared__ int sBM[2];
    __shared__ unsigned int cnts[2];
    __shared__ unsigned int wK[4];
    __shared__ int wI[4];
    int t = threadIdx.x;
    for (int i = t; i < 2048; i += 256) hist[i] = 0u;
    if (t < 2) cnts[t] = 0u;
    float qx = xyz[p], qy = xyz[4096 + p], qz = xyz[8192 + p];
    float xs = (qx * qx + qy * qy) + qz * qz;
    __syncthreads();
    for (int n = t; n < N_pts; n += 256) {
        float yx = xyz[n], yy = xyz[4096 + n], yz = xyz[8192 + n];
        float ys = (yx * yx + yy * yy) + yz * yz;
        float dot = (qx * yx + qy * yy) + qz * yz;
        float d2 = (xs + ys) - 2.0f * dot;
        unsigned int k = __float_as_uint(d2);
        k = (k & 0x80000000u) ? ~k : (k | 0x80000000u);
        keys[n] = k;
        atomicAdd(&hist[k >> 21], 1u);
    }
    __syncthreads();
    unsigned int h8[8], mysum = 0u;
#pragma unroll
    for (int i = 0; i < 8; i++) { h8[i] = hist[t * 8 + i]; mysum += h8[i]; }
    scanbuf[t] = mysum;
    __syncthreads();
    for (int s = 1; s < 256; s <<= 1) {
        unsigned int v = (t >= s) ? scanbuf[t - s] : 0u;
        __syncthreads();
        scanbuf[t] += v;
        __syncthreads();
    }
    unsigned int cum = scanbuf[t] - mysum;
#pragma unroll
    for (int i = 0; i < 8; i++) {
        if (cum < (unsigned)K && cum + h8[i] >= (unsigned)K) { sBM[0] = t * 8 + i; sBM[1] = (int)cum; }
        cum += h8[i];
    }
    __syncthreads();
    int B = sBM[0], m = sBM[1], r = K - m;
    for (int n = t; n < N_pts; n += 256) {
        unsigned int k = keys[n];
        int bin = (int)(k >> 21);
        if (bin < B) {
            outIdx[atomicAdd(&cnts[0], 1u)] = n;
        } else if (bin == B) {
            unsigned int ci = atomicAdd(&cnts[1], 1u);
            if (ci < 512u) { candK[ci] = k; candI[ci] = n; }
        }
    }
    __syncthreads();
    int nc = (int)cnts[1];
    if (nc <= 512) {
        for (int ci = t; ci < nc; ci += 256) {
            unsigned int ki = candK[ci];
            int ii = candI[ci];
            int rank = 0;
            for (int j = 0; j < nc; j++) {
                unsigned int kj = candK[j];
                rank += (kj < ki || (kj == ki && candI[j] < ii)) ? 1 : 0;
            }
            if (rank < r) outIdx[m + rank] = ii;
        }
    } else {
        for (int rr = 0; rr < r; ++rr) {
            unsigned int best = 0xFFFFFFFFu;
            int bi = 0x7fffffff;
            for (int n = t; n < N_pts; n += 256) {
                unsigned int k2 = keys[n];
                if ((int)(k2 >> 21) == B && (k2 < best || (k2 == best && n < bi))) { best = k2; bi = n; }
            }
#pragma unroll
            for (int s = 32; s > 0; s >>= 1) {
                unsigned int ov = (unsigned int)__shfl_down((int)best, s);
                int oi = __shfl_down(bi, s);
                if (ov < best || (ov == best && oi < bi)) { best = ov; bi = oi; }
            }
            int lane = t & 63, wv = t >> 6;
            if (lane == 0) { wK[wv] = best; wI[wv] = bi; }
            __syncthreads();
            if (t == 0) {
                unsigned int bb = wK[0];
                int ii = wI[0];
                for (int w = 1; w < 4; ++w)
                    if (wK[w] < bb || (wK[w] == bb && wI[w] < ii)) { bb = wK[w]; ii = wI[w]; }
                outIdx[m + rr] = ii;
                keys[ii] = 0xFFFFFFFFu;
            }
            __syncthreads();
        }
    }
    __syncthreads();
    if (t < K) idx_out[(size_t)bp * K + t] = outIdx[t];
}

// ---------------------------------------------------------------------------
// SA1 precompute: A1t[b][n][o] = b1[o] + sum_c w1[o][c]*x[b][c][n] (unchanged).
// ---------------------------------------------------------------------------
__global__ __launch_bounds__(256) void sa1_pre_kernel(
    const float* __restrict__ x, const float* __restrict__ w1, const float* __restrict__ b1,
    float* __restrict__ a1t) {
    int bid = blockIdx.x;
    int b = bid >> 5, nt = bid & 31, n0 = nt << 7;
    __shared__ float xsh[6 * 128];
    __shared__ float wt[6 * 68];
    const float* xb = x + (size_t)b * 24576;
    int t = threadIdx.x;
    for (int id = t; id < 768; id += 256) {
        int c = id >> 7, n = id & 127;
        xsh[c * 128 + n] = xb[c * 4096 + n0 + n];
    }
    for (int id = t; id < 384; id += 256) {
        int c = id >> 6, o = id & 63;
        wt[c * 68 + o] = w1[o * 6 + c];
    }
    __syncthreads();
    int o = t & 63, ng = t >> 6;
    float acc[32];
    float bias = b1[o];
#pragma unroll
    for (int j = 0; j < 32; j++) acc[j] = bias;
    for (int c = 0; c < 6; c++) {
        float w = wt[c * 68 + o];
        const float* f = &xsh[c * 128 + ng * 32];
#pragma unroll
        for (int j = 0; j < 32; j++) acc[j] += w * f[j];
    }
#pragma unroll
    for (int j = 0; j < 32; j++)
        a1t[((size_t)b * 4096 + n0 + ng * 32 + j) * 64 + o] = acc[j];
}

// ---------------------------------------------------------------------------
// SA1 fused v2: per-lane weight reads (b128/b64), wave-uniform activation
// reads. Block = 2 queries (64 cols = 2q x 32k), 256 thr, ~27KB LDS.
// Phase1 (L2 64->64): tile 4o x 4j; Phase2 (L3 64->128): tile 2o x 16j.
// ---------------------------------------------------------------------------
__global__ __launch_bounds__(256) void sa1_fused_kernel(
    const float* __restrict__ x, const float* __restrict__ a1t,
    const int* __restrict__ idx1, const float* __restrict__ w1,
    const float* __restrict__ w2, const float* __restrict__ b2,
    const float* __restrict__ w3, const float* __restrict__ b3,
    float* __restrict__ p1) {
    int bp = blockIdx.x;  // 32*256
    int b = bp >> 8, pp = bp & 255, p0 = pp * 2;
    // floats: H2[4096] | region[2048]: {H1[1024], W2T[1024]} / {W3T[2048]} | MX2[512]
    __shared__ float smem[6656];
    __shared__ int nbr[64];
    __shared__ float dshq[2][64];
    float* H2 = smem;            // 64c x 64j
    float* H1 = smem + 4096;     // 16c x 64j (phase1)
    float* W2T = smem + 5120;    // 16c x 64o (phase1)
    float* W3T = smem + 4096;    // 16c x 128o (phase2)
    float* MX2 = smem + 6144;    // 4w x 128o
    const float* xb = x + (size_t)b * 24576;
    int t = threadIdx.x;
    int w = t >> 6, l = t & 63;
    if (t < 64) nbr[t] = idx1[((size_t)b * 512 + p0) * 32 + t];
    if (t < 128) {
        int qi = t >> 6, c = t & 63;
        float qx = xb[p0 + qi], qy = xb[4096 + p0 + qi], qz = xb[8192 + p0 + qi];
        dshq[qi][c] = -(w1[c * 6 + 0] * qx + w1[c * 6 + 1] * qy + w1[c * 6 + 2] * qz);
    }
    __syncthreads();
    // ================= phase 1: L2 (64 -> 64, relu) =================
    {
        int o4 = (l & 15) * 4;
        int jb = w * 16 + (l >> 4) * 4;
        int qj = l >> 5;  // query of gather column l
        float acc2[4][4];
#pragma unroll
        for (int oi = 0; oi < 4; oi++) {
            float bv = b2[o4 + oi];
#pragma unroll
            for (int ji = 0; ji < 4; ji++) acc2[oi][ji] = bv;
        }
        // stage roles
        const float* gsrc = &a1t[((size_t)b * 4096 + nbr[l]) * 64 + w * 4];   // gather col l, ch w*4..+4
        int so = t & 63, sh = t >> 6;                                          // W2T: o=so, cc sh*4..+4
        float4 rg = *(const float4*)&gsrc[0];
        float4 rw = *(const float4*)&w2[so * 64 + sh * 4];
        for (int sl = 0; sl < 4; sl++) {
            int cc0 = sl * 16;
            // write staged regs to LDS
            {
                const float* d = &dshq[qj][cc0 + w * 4];
                H1[(w * 4 + 0) * 64 + l] = fmaxf(rg.x + d[0], 0.f);
                H1[(w * 4 + 1) * 64 + l] = fmaxf(rg.y + d[1], 0.f);
                H1[(w * 4 + 2) * 64 + l] = fmaxf(rg.z + d[2], 0.f);
                H1[(w * 4 + 3) * 64 + l] = fmaxf(rg.w + d[3], 0.f);
                W2T[(sh * 4 + 0) * 64 + so] = rw.x;
                W2T[(sh * 4 + 1) * 64 + so] = rw.y;
                W2T[(sh * 4 + 2) * 64 + so] = rw.z;
                W2T[(sh * 4 + 3) * 64 + so] = rw.w;
            }
            __syncthreads();
            if (sl < 3) {
                int cc0n = cc0 + 16;
                rg = *(const float4*)&gsrc[cc0n];
                rw = *(const float4*)&w2[so * 64 + cc0n + sh * 4];
            }
#pragma unroll
            for (int lc = 0; lc < 16; lc++) {
                float4 wv = *(const float4*)&W2T[lc * 64 + o4];
                float4 fv = *(const float4*)&H1[lc * 64 + jb];
                float wl[4] = {wv.x, wv.y, wv.z, wv.w};
                float fl[4] = {fv.x, fv.y, fv.z, fv.w};
#pragma unroll
                for (int oi = 0; oi < 4; oi++)
#pragma unroll
                    for (int ji = 0; ji < 4; ji++) acc2[oi][ji] += wl[oi] * fl[ji];
            }
            __syncthreads();
        }
        // epilogue: relu -> H2[o][j] (16-way conflict, once per kernel)
#pragma unroll
        for (int oi = 0; oi < 4; oi++) {
            float4 s;
            s.x = fmaxf(acc2[oi][0], 0.f); s.y = fmaxf(acc2[oi][1], 0.f);
            s.z = fmaxf(acc2[oi][2], 0.f); s.w = fmaxf(acc2[oi][3], 0.f);
            *(float4*)&H2[(o4 + oi) * 64 + jb] = s;
        }
    }
    // ================= phase 2: L3 (64 -> 128) + max over k=32 =============
    {
        int o2 = l * 2;
        int jb2 = w * 16;  // wave-uniform; waves 0,1 -> query 0; 2,3 -> query 1
        float acc3[2][16];
#pragma unroll
        for (int oi = 0; oi < 2; oi++) {
            float bv = b3[o2 + oi];
#pragma unroll
            for (int ji = 0; ji < 16; ji++) acc3[oi][ji] = bv;
        }
        int so = t & 127, sh = t >> 7;  // W3T: o=so, cc sh*8..+8
        float4 rw0 = *(const float4*)&w3[so * 64 + sh * 8];
        float4 rw1 = *(const float4*)&w3[so * 64 + sh * 8 + 4];
        for (int sl = 0; sl < 4; sl++) {
            int cc0 = sl * 16;
            W3T[(sh * 8 + 0) * 128 + so] = rw0.x;
            W3T[(sh * 8 + 1) * 128 + so] = rw0.y;
            W3T[(sh * 8 + 2) * 128 + so] = rw0.z;
            W3T[(sh * 8 + 3) * 128 + so] = rw0.w;
            W3T[(sh * 8 + 4) * 128 + so] = rw1.x;
            W3T[(sh * 8 + 5) * 128 + so] = rw1.y;
            W3T[(sh * 8 + 6) * 128 + so] = rw1.z;
            W3T[(sh * 8 + 7) * 128 + so] = rw1.w;
            __syncthreads();
            if (sl < 3) {
                int cc0n = cc0 + 16;
                rw0 = *(const float4*)&w3[so * 64 + cc0n + sh * 8];
                rw1 = *(const float4*)&w3[so * 64 + cc0n + sh * 8 + 4];
            }
#pragma unroll
            for (int lc = 0; lc < 16; lc++) {
                float2 wv = *(const float2*)&W3T[lc * 128 + o2];
                const float* f = &H2[(cc0 + lc) * 64 + jb2];
                float4 f0 = *(const float4*)&f[0];
                float4 f1 = *(const float4*)&f[4];
                float4 f2 = *(const float4*)&f[8];
                float4 f3 = *(const float4*)&f[12];
                float fl[16] = {f0.x, f0.y, f0.z, f0.w, f1.x, f1.y, f1.z, f1.w,
                                f2.x, f2.y, f2.z, f2.w, f3.x, f3.y, f3.z, f3.w};
#pragma unroll
                for (int ji = 0; ji < 16; ji++) {
                    acc3[0][ji] += wv.x * fl[ji];
                    acc3[1][ji] += wv.y * fl[ji];
                }
            }
            __syncthreads();
        }
        // epilogue: per-lane max over 16 j (one query) -> MX2[w][o]
        float2 mv;
        {
            float m0 = acc3[0][0], m1 = acc3[1][0];
#pragma unroll
            for (int ji = 1; ji < 16; ji++) { m0 = fmaxf(m0, acc3[0][ji]); m1 = fmaxf(m1, acc3[1][ji]); }
            mv.x = m0; mv.y = m1;
        }
        *(float2*)&MX2[w * 128 + o2] = mv;
    }
    __syncthreads();
    {
        int o = t & 127, q = t >> 7;
        float v = fmaxf(MX2[(q * 2) * 128 + o], MX2[(q * 2 + 1) * 128 + o]);
        p1[((size_t)b * 128 + o) * 512 + p0 + q] = v;
    }
}

// ---------------------------------------------------------------------------
// SA2 precompute: A2t[b][n][o] = b1[o] + sum_c w1[o][c]*[xyz;p1][b][c][n]
// (unchanged).
// ---------------------------------------------------------------------------
__global__ __launch_bounds__(256) void sa2_pre_kernel(
    const float* __restrict__ x, const float* __restrict__ p1,
    const float* __restrict__ w1, const float* __restrict__ b1,
    float* __restrict__ a2t) {
    int bid = blockIdx.x;
    int b = bid >> 2, nt = bid & 3, n0 = nt << 7;
    __shared__ float ins[2][16 * 128];
    __shared__ float wt[2][16 * 132];
    const float* xb = x + (size_t)b * 24576;
    const float* p1b = p1 + (size_t)b * 65536;
    int t = threadIdx.x;
    int og = t >> 3, pg = t & 7;
    int o0 = og * 4;
    float acc[4][16];
    {
        float bl[4] = {b1[o0], b1[o0 + 1], b1[o0 + 2], b1[o0 + 3]};
#pragma unroll
        for (int oi = 0; oi < 4; oi++)
#pragma unroll
            for (int j = 0; j < 16; j++) acc[oi][j] = bl[oi];
    }
    for (int id = t; id < 16 * 128; id += 256) {
        int n = id & 127, c = id >> 7;
        ins[0][c * 128 + n] = (c < 3) ? xb[c * 4096 + n0 + n]
                                      : p1b[(size_t)(c - 3) * 512 + n0 + n];
    }
    for (int id = t; id < 2048; id += 256) {
        int c = id & 15, oo = id >> 4;
        wt[0][c * 132 + oo] = w1[oo * 131 + c];
    }
    __syncthreads();
    for (int ch = 0; ch < 9; ch++) {
        int cs = (ch == 8) ? 3 : 16;
        if (ch < 8) {
            int c0n = (ch + 1) * 16;
            int csn = (ch == 7) ? 3 : 16;
            int nb = (ch + 1) & 1;
            for (int id = t; id < csn * 128; id += 256) {
                int n = id & 127, c = id >> 7;
                int cg = c0n + c;
                ins[nb][c * 128 + n] = (cg < 3) ? xb[cg * 4096 + n0 + n]
                                                : p1b[(size_t)(cg - 3) * 512 + n0 + n];
            }
            for (int id = t; id < 2048; id += 256) {
                int c = id & 15, oo = id >> 4;
                if (c < csn) wt[nb][c * 132 + oo] = w1[oo * 131 + c0n + c];
            }
        }
        const float* wb = wt[ch & 1];
        const float* ib = ins[ch & 1];
        for (int cc = 0; cc < cs; cc++) {
            float4 wv = *(const float4*)&wb[cc * 132 + o0];
            float wl[4] = {wv.x, wv.y, wv.z, wv.w};
#pragma unroll
            for (int c4 = 0; c4 < 4; c4++) {
                float4 fv = *(const float4*)&ib[cc * 128 + pg * 4 + c4 * 32];
                float fl[4] = {fv.x, fv.y, fv.z, fv.w};
#pragma unroll
                for (int j = 0; j < 4; j++)
#pragma unroll
                    for (int oi = 0; oi < 4; oi++) acc[oi][c4 * 4 + j] += wl[oi] * fl[j];
            }
        }
        __syncthreads();
    }
#pragma unroll
    for (int c4 = 0; c4 < 4; c4++)
#pragma unroll
        for (int j = 0; j < 4; j++) {
            int n = n0 + pg * 4 + c4 * 32 + j;
            float4 v;
            v.x = acc[0][c4 * 4 + j]; v.y = acc[1][c4 * 4 + j];
            v.z = acc[2][c4 * 4 + j]; v.w = acc[3][c4 * 4 + j];
            *(float4*)&a2t[((size_t)b * 512 + n) * 128 + o0] = v;
        }
}

// ---------------------------------------------------------------------------
// SA2 fused v2: per-lane weight b128 reads + wave-uniform activation reads.
// Block = 1 query (64 cols = k=64), 256 thr, ~45KB LDS.
// Phase1 (L2 128->128): tile 4o x 8j; Phase2 (L3 128->256): tile 4o x 16j.
// ---------------------------------------------------------------------------
__global__ __launch_bounds__(256) void sa2_fused_kernel(
    const float* __restrict__ x, const float* __restrict__ a2t,
    const int* __restrict__ idx2, const float* __restrict__ w1,
    const float* __restrict__ w2, const float* __restrict__ b2,
    const float* __restrict__ w3, const float* __restrict__ b3,
    float* __restrict__ p2) {
    int bp = blockIdx.x;  // 32*128
    int b = bp >> 7, p = bp & 127;
    // floats: H2[8192] | region: {H1[1024]@8192, W2T[2048]@9216} / {W3T[2048]@8192} | MX2[1024]@10240
    __shared__ float smem[11264];
    __shared__ int nbr[64];
    __shared__ float dsh[128];
    float* H2 = smem;            // 128c x 64j
    float* H1 = smem + 8192;     // 16c x 64j  (phase1)
    float* W2T = smem + 9216;    // 16c x 128o (phase1)
    float* W3T = smem + 8192;    // 8c x 256o  (phase2)
    float* MX2 = smem + 10240;   // 4grp x 256o
    const float* xb = x + (size_t)b * 24576;
    int t = threadIdx.x;
    int w = t >> 6, l = t & 63;
    if (t < 64) nbr[t] = idx2[((size_t)b * 128 + p) * 64 + t];
    if (t < 128) {
        float qx = xb[p], qy = xb[4096 + p], qz = xb[8192 + p];
        dsh[t] = -(w1[t * 131 + 0] * qx + w1[t * 131 + 1] * qy + w1[t * 131 + 2] * qz);
    }
    __syncthreads();
    // ================= phase 1: L2 (128 -> 128, relu) ======================
    {
        int o4 = (l & 31) * 4;
        int jb = w * 16 + (l >> 5) * 8;
        float acc2[4][8];
#pragma unroll
        for (int oi = 0; oi < 4; oi++) {
            float bv = b2[o4 + oi];
#pragma unroll
            for (int ji = 0; ji < 8; ji++) acc2[oi][ji] = bv;
        }
        const float* gsrc = &a2t[((size_t)b * 512 + nbr[l]) * 128 + w * 4];  // gather col l, ch w*4..+4
        int so = t & 127, sh = t >> 7;                                        // W2T: o=so, cc sh*8..+8
        float4 rg = *(const float4*)&gsrc[0];
        float4 rw0 = *(const float4*)&w2[so * 128 + sh * 8];
        float4 rw1 = *(const float4*)&w2[so * 128 + sh * 8 + 4];
        for (int sl = 0; sl < 8; sl++) {
            int cc0 = sl * 16;
            {
                const float* d = &dsh[cc0 + w * 4];
                H1[(w * 4 + 0) * 64 + l] = fmaxf(rg.x + d[0], 0.f);
                H1[(w * 4 + 1) * 64 + l] = fmaxf(rg.y + d[1], 0.f);
                H1[(w * 4 + 2) * 64 + l] = fmaxf(rg.z + d[2], 0.f);
                H1[(w * 4 + 3) * 64 + l] = fmaxf(rg.w + d[3], 0.f);
                W2T[(sh * 8 + 0) * 128 + so] = rw0.x;
                W2T[(sh * 8 + 1) * 128 + so] = rw0.y;
                W2T[(sh * 8 + 2) * 128 + so] = rw0.z;
                W2T[(sh * 8 + 3) * 128 + so] = rw0.w;
                W2T[(sh * 8 + 4) * 128 + so] = rw1.x;
                W2T[(sh * 8 + 5) * 128 + so] = rw1.y;
                W2T[(sh * 8 + 6) * 128 + so] = rw1.z;
                W2T[(sh * 8 + 7) * 128 + so] = rw1.w;
            }
            __syncthreads();
            if (sl < 7) {
                int cc0n = cc0 + 16;
                rg = *(const float4*)&gsrc[cc0n];
                rw0 = *(const float4*)&w2[so * 128 + cc0n + sh * 8];
                rw1 = *(const float4*)&w2[so * 128 + cc0n + sh * 8 + 4];
            }
#pragma unroll
            for (int lc = 0; lc < 16; lc++) {
                float4 wv = *(const float4*)&W2T[lc * 128 + o4];
                float4 f0 = *(const float4*)&H1[lc * 64 + jb];
                float4 f1 = *(const float4*)&H1[lc * 64 + jb + 4];
                float wl[4] = {wv.x, wv.y, wv.z, wv.w};
                float fl[8] = {f0.x, f0.y, f0.z, f0.w, f1.x, f1.y, f1.z, f1.w};
#pragma unroll
                for (int oi = 0; oi < 4; oi++)
#pragma unroll
                    for (int ji = 0; ji < 8; ji++) acc2[oi][ji] += wl[oi] * fl[ji];
            }
            __syncthreads();
        }
        // epilogue: relu -> H2[o][j] (b128 column writes, once per kernel)
#pragma unroll
        for (int oi = 0; oi < 4; oi++) {
            float4 s0, s1;
            s0.x = fmaxf(acc2[oi][0], 0.f); s0.y = fmaxf(acc2[oi][1], 0.f);
            s0.z = fmaxf(acc2[oi][2], 0.f); s0.w = fmaxf(acc2[oi][3], 0.f);
            s1.x = fmaxf(acc2[oi][4], 0.f); s1.y = fmaxf(acc2[oi][5], 0.f);
            s1.z = fmaxf(acc2[oi][6], 0.f); s1.w = fmaxf(acc2[oi][7], 0.f);
            *(float4*)&H2[(o4 + oi) * 64 + jb] = s0;
            *(float4*)&H2[(o4 + oi) * 64 + jb + 4] = s1;
        }
    }
    // ================= phase 2: L3 (128 -> 256) + max over k=64 ============
    {
        int o4b = (w & 1) * 128 + (l & 31) * 4;
        int jb2 = (w >> 1) * 32 + (l >> 5) * 16;
        float acc3[4][16];
#pragma unroll
        for (int oi = 0; oi < 4; oi++) {
            float bv = b3[o4b + oi];
#pragma unroll
            for (int ji = 0; ji < 16; ji++) acc3[oi][ji] = bv;
        }
        const float* w3row = &w3[(size_t)t * 128];  // W3T: o=t, cc 0..8 per slab
        float4 rw0 = *(const float4*)&w3row[0];
        float4 rw1 = *(const float4*)&w3row[4];
        for (int sl = 0; sl < 16; sl++) {
            int cc0 = sl * 8;
            W3T[0 * 256 + t] = rw0.x;
            W3T[1 * 256 + t] = rw0.y;
            W3T[2 * 256 + t] = rw0.z;
            W3T[3 * 256 + t] = rw0.w;
            W3T[4 * 256 + t] = rw1.x;
            W3T[5 * 256 + t] = rw1.y;
            W3T[6 * 256 + t] = rw1.z;
            W3T[7 * 256 + t] = rw1.w;
            __syncthreads();
            if (sl < 15) {
                int cc0n = cc0 + 8;
                rw0 = *(const float4*)&w3row[cc0n];
                rw1 = *(const float4*)&w3row[cc0n + 4];
            }
#pragma unroll
            for (int lc = 0; lc < 8; lc++) {
                float4 wv = *(const float4*)&W3T[lc * 256 + o4b];
                const float* f = &H2[(cc0 + lc) * 64 + jb2];
                float4 f0 = *(const float4*)&f[0];
                float4 f1 = *(const float4*)&f[4];
                float4 f2 = *(const float4*)&f[8];
                float4 f3 = *(const float4*)&f[12];
                float wl[4] = {wv.x, wv.y, wv.z, wv.w};
                float fl[16] = {f0.x, f0.y, f0.z, f0.w, f1.x, f1.y, f1.z, f1.w,
                                f2.x, f2.y, f2.z, f2.w, f3.x, f3.y, f3.z, f3.w};
#pragma unroll
                for (int oi = 0; oi < 4; oi++)
#pragma unroll
                    for (int ji = 0; ji < 16; ji++) acc3[oi][ji] += wl[oi] * fl[ji];
            }
            __syncthreads();
        }
        // epilogue: per-lane max over 16 j -> MX2[jgrp][o] (coalesced b128)
        int jgrp = (w >> 1) * 2 + (l >> 5);
        float4 mv;
        {
            float m0 = acc3[0][0], m1 = acc3[1][0], m2 = acc3[2][0], m3 = acc3[3][0];
#pragma unroll
            for (int ji = 1; ji < 16; ji++) {
                m0 = fmaxf(m0, acc3[0][ji]); m1 = fmaxf(m1, acc3[1][ji]);
                m2 = fmaxf(m2, acc3[2][ji]); m3 = fmaxf(m3, acc3[3][ji]);
            }
            mv.x = m0; mv.y = m1; mv.z = m2; mv.w = m3;
        }
        *(float4*)&MX2[jgrp * 256 + o4b] = mv;
    }
    __syncthreads();
    {
        float v = fmaxf(fmaxf(MX2[t], MX2[256 + t]), fmaxf(MX2[512 + t], MX2[768 + t]));
        p2[((size_t)b * 256 + t) * 128 + p] = v;
    }
}

// ---------------------------------------------------------------------------
// SA3 batched GEMM over 128 points (unchanged).
// ---------------------------------------------------------------------------
__global__ __launch_bounds__(256) void mlp128_kernel(
    const float* __restrict__ in, const float* __restrict__ W,
    const float* __restrict__ bias, float* __restrict__ out,
    int Cin, int Cout, int relu, int wstride, int woff, int reduce) {
    int bid = blockIdx.x;
    int tiles = Cout >> 6;
    int b = bid / tiles, ot = bid - b * tiles;
    int o0t = ot << 6;
    __shared__ float ins[64 * 128];
    __shared__ float wt[2][16 * 68];
    __shared__ float gmx[64 * 8];
    int t = threadIdx.x;
    int og = t >> 3, pg = t & 7;
    int o = o0t + og * 2;
    float acc[2][16];
    {
        float bb0 = bias[o], bb1 = bias[o + 1];
#pragma unroll
        for (int j = 0; j < 16; j++) { acc[0][j] = bb0; acc[1][j] = bb1; }
    }
    int nslab = Cin >> 6;
    for (int sl = 0; sl < nslab; sl++) {
        __syncthreads();
        for (int id = t; id < 2048; id += 256) {
            int p4 = id & 31, c = id >> 5;
            *(float4*)&ins[c * 128 + p4 * 4] =
                *(const float4*)&in[((size_t)b * Cin + sl * 64 + c) * 128 + p4 * 4];
        }
        for (int id = t; id < 1024; id += 256) {
            int c = id & 15, oo = id >> 4;
            wt[0][c * 68 + oo] = W[(size_t)(o0t + oo) * wstride + woff + sl * 64 + c];
        }
        __syncthreads();
        for (int ch = 0; ch < 4; ch++) {
            if (ch < 3) {
                int nb = (ch + 1) & 1;
                for (int id = t; id < 1024; id += 256) {
                    int c = id & 15, oo = id >> 4;
                    wt[nb][c * 68 + oo] =
                        W[(size_t)(o0t + oo) * wstride + woff + sl * 64 + (ch + 1) * 16 + c];
                }
            }
            const float* wb = wt[ch & 1];
#pragma unroll
            for (int cc = 0; cc < 16; cc++) {
                float2 wv = *(const float2*)&wb[cc * 68 + og * 2];
                const float* f = &ins[(ch * 16 + cc) * 128 + pg * 4];
#pragma unroll
                for (int c4 = 0; c4 < 4; c4++) {
                    float4 fv = *(const float4*)&f[c4 * 32];
                    float fl[4] = {fv.x, fv.y, fv.z, fv.w};
#pragma unroll
                    for (int j = 0; j < 4; j++) {
                        acc[0][c4 * 4 + j] += wv.x * fl[j];
                        acc[1][c4 * 4 + j] += wv.y * fl[j];
                    }
                }
            }
            __syncthreads();
        }
    }
    if (!reduce) {
#pragma unroll
        for (int oi = 0; oi < 2; oi++)
#pragma unroll
            for (int c4 = 0; c4 < 4; c4++) {
                float4 v;
                v.x = acc[oi][c4 * 4 + 0]; v.y = acc[oi][c4 * 4 + 1];
                v.z = acc[oi][c4 * 4 + 2]; v.w = acc[oi][c4 * 4 + 3];
                if (relu) {
                    v.x = fmaxf(v.x, 0.f); v.y = fmaxf(v.y, 0.f);
                    v.z = fmaxf(v.z, 0.f); v.w = fmaxf(v.w, 0.f);
                }
                *(float4*)&out[((size_t)b * Cout + o + oi) * 128 + pg * 4 + c4 * 32] = v;
            }
    } else {
#pragma unroll
        for (int oi = 0; oi < 2; oi++) {
            float mm = acc[oi][0];
#pragma unroll
            for (int j = 1; j < 16; j++) mm = fmaxf(mm, acc[oi][j]);
            gmx[(og * 2 + oi) * 8 + pg] = mm;
        }
        __syncthreads();
        if (t < 64) {
            float mm = gmx[t * 8];
#pragma unroll
            for (int i = 1; i < 8; i++) mm = fmaxf(mm, gmx[t * 8 + i]);
            out[(size_t)b * Cout + o0t + t] = mm;
        }
    }
}

// ---------------------------------------------------------------------------
// Head: FC 1024->512->256->40 (unchanged).
// ---------------------------------------------------------------------------
__global__ __launch_bounds__(256) void head_kernel(
    const float* __restrict__ g,
    const float* __restrict__ fw1, const float* __restrict__ fb1,
    const float* __restrict__ fw2, const float* __restrict__ fb2,
    const float* __restrict__ fw3, const float* __restrict__ fb3,
    float* __restrict__ out) {
    int b = blockIdx.x;
    int t = threadIdx.x;
    __shared__ float gs[1024];
    __shared__ float h1[512];
    __shared__ float h2[256];
    for (int i = t; i < 1024; i += 256) gs[i] = g[(size_t)b * 1024 + i];
    __syncthreads();
    for (int oo = 0; oo < 2; oo++) {
        int o = t + oo * 256;
        float acc = fb1[o];
        const float4* wr = (const float4*)&fw1[(size_t)o * 1024];
        for (int c = 0; c < 256; c++) {
            float4 wv = wr[c];
            acc += wv.x * gs[c * 4] + wv.y * gs[c * 4 + 1] + wv.z * gs[c * 4 + 2] + wv.w * gs[c * 4 + 3];
        }
        h1[o] = fmaxf(acc, 0.f);
    }
    __syncthreads();
    {
        float acc = fb2[t];
        const float4* wr = (const float4*)&fw2[(size_t)t * 512];
        for (int c = 0; c < 128; c++) {
            float4 wv = wr[c];
            acc += wv.x * h1[c * 4] + wv.y * h1[c * 4 + 1] + wv.z * h1[c * 4 + 2] + wv.w * h1[c * 4 + 3];
        }
        h2[t] = fmaxf(acc, 0.f);
    }
    __syncthreads();
    if (t < 40) {
        float acc = fb3[t];
        const float4* wr = (const float4*)&fw3[(size_t)t * 256];
        for (int c = 0; c < 64; c++) {
            float4 wv = wr[c];
            acc += wv.x * h2[c * 4] + wv.y * h2[c * 4 + 1] + wv.z * h2[c * 4 + 2] + wv.w * h2[c * 4 + 3];
        }
        out[b * 40 + t] = acc;
    }
}

extern "C" void kernel_launch(void* const* d_in, const int* in_sizes, int n_in,
                              void* d_out, int out_size, void* d_ws, size_t ws_size,
                              hipStream_t stream) {
    const float* x      = (const float*)d_in[0];
    const float* sa1_w1 = (const float*)d_in[1];
    const float* sa1_b1 = (const float*)d_in[2];
    const float* sa1_w2 = (const float*)d_in[3];
    const float* sa1_b2 = (const float*)d_in[4];
    const float* sa1_w3 = (const float*)d_in[5];
    const float* sa1_b3 = (const float*)d_in[6];
    const float* sa2_w1 = (const float*)d_in[7];
    const float* sa2_b1 = (const float*)d_in[8];
    const float* sa2_w2 = (const float*)d_in[9];
    const float* sa2_b2 = (const float*)d_in[10];
    const float* sa2_w3 = (const float*)d_in[11];
    const float* sa2_b3 = (const float*)d_in[12];
    const float* sa3_w1 = (const float*)d_in[13];
    const float* sa3_b1 = (const float*)d_in[14];
    const float* sa3_w2 = (const float*)d_in[15];
    const float* sa3_b2 = (const float*)d_in[16];
    const float* sa3_w3 = (const float*)d_in[17];
    const float* sa3_b3 = (const float*)d_in[18];
    const float* fc1_w  = (const float*)d_in[19];
    const float* fc1_b  = (const float*)d_in[20];
    const float* fc2_w  = (const float*)d_in[21];
    const float* fc2_b  = (const float*)d_in[22];
    const float* fc3_w  = (const float*)d_in[23];
    const float* fc3_b  = (const float*)d_in[24];

    char* ws = (char*)d_ws;
    const size_t MB = 1048576;
    int*   idx1 = (int*)  (ws + 0 * MB);    //  2 MB: (32,512,32)
    float* a1t  = (float*)(ws + 2 * MB);    // 32 MB: (32,4096,64) -- dead after sa1_fused
    float* p1   = (float*)(ws + 34 * MB);   //  8 MB: (32,128,512) c-major
    int*   idx2 = (int*)  (ws + 42 * MB);   //  1 MB: (32,128,64)
    float* a2t  = (float*)(ws + 2 * MB);    //  8 MB: (32,512,128) overlays dead a1t
    float* p2   = (float*)(ws + 10 * MB);   //  4 MB: (32,256,128)
    float* h1s  = (float*)(ws + 14 * MB);   //  4 MB: (32,256,128)
    float* h2s  = (float*)(ws + 18 * MB);   //  8 MB: (32,512,128)
    float* g    = (float*)(ws + 26 * MB);   //  128 KB: (32,1024)

    knn_select_kernel<<<32 * 512, 256, 0, stream>>>(x, 4096, 32, 512, idx1);
    sa1_pre_kernel<<<32 * 32, 256, 0, stream>>>(x, sa1_w1, sa1_b1, a1t);
    sa1_fused_kernel<<<32 * 256, 256, 0, stream>>>(x, a1t, idx1, sa1_w1,
                                                   sa1_w2, sa1_b2, sa1_w3, sa1_b3, p1);
    knn_select_kernel<<<32 * 128, 256, 0, stream>>>(x, 512, 64, 128, idx2);
    sa2_pre_kernel<<<32 * 4, 256, 0, stream>>>(x, p1, sa2_w1, sa2_b1, a2t);
    sa2_fused_kernel<<<32 * 128, 256, 0, stream>>>(x, a2t, idx2, sa2_w1,
                                                   sa2_w2, sa2_b2, sa2_w3, sa2_b3, p2);
    mlp128_kernel<<<32 * 4, 256, 0, stream>>>(p2, sa3_w1, sa3_b1, h1s, 256, 256, 1, 259, 3, 0);
    mlp128_kernel<<<32 * 8, 256, 0, stream>>>(h1s, sa3_w2, sa3_b2, h2s, 256, 512, 1, 256, 0, 0);
    mlp128_kernel<<<32 * 16, 256, 0, stream>>>(h2s, sa3_w3, sa3_b3, g, 512, 1024, 0, 512, 0, 1);
    head_kernel<<<32, 256, 0, stream>>>(g, fc1_w, fc1_b, fc2_w, fc2_b, fc3_w, fc3_b,
                                        (float*)d_out);
}

// Round 6
// 823.569 us; speedup vs baseline: 1.1397x; 1.1397x over previous
//
#include <hip/hip_runtime.h>
#include <hip/hip_bf16.h>

#define FLT_BIG 3.0e38f

typedef __attribute__((ext_vector_type(8))) short s8v;
typedef __attribute__((ext_vector_type(4))) float f4v;

// ---------------------------------------------------------------------------
// bf16 3-plane split helpers (RNE). x ~= x0 + x1 + x2 exactly to ~2^-27 rel.
// ---------------------------------------------------------------------------
__device__ inline unsigned short bf_hi(float v, float& res) {
    unsigned int u = __float_as_uint(v);
    unsigned int r = (u + 0x7FFFu + ((u >> 16) & 1u)) >> 16;
    res = v - __uint_as_float(r << 16);
    return (unsigned short)r;
}
__device__ inline void split3(float v, unsigned short& h0, unsigned short& h1,
                              unsigned short& h2) {
    float r1, r2, r3;
    h0 = bf_hi(v, r1);
    h1 = bf_hi(r1, r2);
    h2 = bf_hi(r2, r3);
}

// ---------------------------------------------------------------------------
// Weight fragment precompute: W[O][K] row-major fp32 -> frag-ordered bf16
// planes. Fragment (ks, ot): lane l holds W[ot*16 + (l&15)][ks*32 + (l>>4)*8
// + e], e=0..7, stored at out[((ks*no + ot)*3 + plane)*64*8 + l*8 + e].
// Same layout serves the A-operand (m = l&15) and B-operand (n = l&15).
// ---------------------------------------------------------------------------
__global__ __launch_bounds__(64) void wfrag_kernel(
    const float* __restrict__ W, int K, int no, unsigned short* __restrict__ out) {
    int bid = blockIdx.x;              // = ks*no + ot
    int l = threadIdx.x;
    int ks = bid / no, ot = bid - ks * no;
    int o = ot * 16 + (l & 15);
    int k0 = ks * 32 + (l >> 4) * 8;
    const float* src = W + (size_t)o * K + k0;
    unsigned short h[3][8];
#pragma unroll
    for (int e = 0; e < 8; e++) split3(src[e], h[0][e], h[1][e], h[2][e]);
#pragma unroll
    for (int p = 0; p < 3; p++) {
        s8v v;
#pragma unroll
        for (int e = 0; e < 8; e++) v[e] = (short)h[p][e];
        *(s8v*)(out + ((size_t)(bid * 3 + p) * 64 + l) * 8) = v;
    }
}

// ---------------------------------------------------------------------------
// kNN via radix select (unchanged).
// ---------------------------------------------------------------------------
__global__ __launch_bounds__(256) void knn_select_kernel(
    const float* __restrict__ x, int N_pts, int K, int P, int* __restrict__ idx_out) {
    int bp = blockIdx.x;
    int b = bp / P, p = bp - b * P;
    const float* xyz = x + (size_t)b * 24576;
    __shared__ unsigned int keys[4096];
    __shared__ unsigned int hist[2048];
    __shared__ unsigned int scanbuf[256];
    __shared__ unsigned int candK[512];
    __shared__ int candI[512];
    __shared__ int outIdx[64];
    __shared__ int sBM[2];
    __shared__ unsigned int cnts[2];
    __shared__ unsigned int wK[4];
    __shared__ int wI[4];
    int t = threadIdx.x;
    for (int i = t; i < 2048; i += 256) hist[i] = 0u;
    if (t < 2) cnts[t] = 0u;
    float qx = xyz[p], qy = xyz[4096 + p], qz = xyz[8192 + p];
    float xs = (qx * qx + qy * qy) + qz * qz;
    __syncthreads();
    for (int n = t; n < N_pts; n += 256) {
        float yx = xyz[n], yy = xyz[4096 + n], yz = xyz[8192 + n];
        float ys = (yx * yx + yy * yy) + yz * yz;
        float dot = (qx * yx + qy * yy) + qz * yz;
        float d2 = (xs + ys) - 2.0f * dot;
        unsigned int k = __float_as_uint(d2);
        k = (k & 0x80000000u) ? ~k : (k | 0x80000000u);
        keys[n] = k;
        atomicAdd(&hist[k >> 21], 1u);
    }
    __syncthreads();
    unsigned int h8[8], mysum = 0u;
#pragma unroll
    for (int i = 0; i < 8; i++) { h8[i] = hist[t * 8 + i]; mysum += h8[i]; }
    scanbuf[t] = mysum;
    __syncthreads();
    for (int s = 1; s < 256; s <<= 1) {
        unsigned int v = (t >= s) ? scanbuf[t - s] : 0u;
        __syncthreads();
        scanbuf[t] += v;
        __syncthreads();
    }
    unsigned int cum = scanbuf[t] - mysum;
#pragma unroll
    for (int i = 0; i < 8; i++) {
        if (cum < (unsigned)K && cum + h8[i] >= (unsigned)K) { sBM[0] = t * 8 + i; sBM[1] = (int)cum; }
        cum += h8[i];
    }
    __syncthreads();
    int B = sBM[0], m = sBM[1], r = K - m;
    for (int n = t; n < N_pts; n += 256) {
        unsigned int k = keys[n];
        int bin = (int)(k >> 21);
        if (bin < B) {
            outIdx[atomicAdd(&cnts[0], 1u)] = n;
        } else if (bin == B) {
            unsigned int ci = atomicAdd(&cnts[1], 1u);
            if (ci < 512u) { candK[ci] = k; candI[ci] = n; }
        }
    }
    __syncthreads();
    int nc = (int)cnts[1];
    if (nc <= 512) {
        for (int ci = t; ci < nc; ci += 256) {
            unsigned int ki = candK[ci];
            int ii = candI[ci];
            int rank = 0;
            for (int j = 0; j < nc; j++) {
                unsigned int kj = candK[j];
                rank += (kj < ki || (kj == ki && candI[j] < ii)) ? 1 : 0;
            }
            if (rank < r) outIdx[m + rank] = ii;
        }
    } else {
        for (int rr = 0; rr < r; ++rr) {
            unsigned int best = 0xFFFFFFFFu;
            int bi = 0x7fffffff;
            for (int n = t; n < N_pts; n += 256) {
                unsigned int k2 = keys[n];
                if ((int)(k2 >> 21) == B && (k2 < best || (k2 == best && n < bi))) { best = k2; bi = n; }
            }
#pragma unroll
            for (int s = 32; s > 0; s >>= 1) {
                unsigned int ov = (unsigned int)__shfl_down((int)best, s);
                int oi = __shfl_down(bi, s);
                if (ov < best || (ov == best && oi < bi)) { best = ov; bi = oi; }
            }
            int lane = t & 63, wv = t >> 6;
            if (lane == 0) { wK[wv] = best; wI[wv] = bi; }
            __syncthreads();
            if (t == 0) {
                unsigned int bb = wK[0];
                int ii = wI[0];
                for (int w = 1; w < 4; ++w)
                    if (wK[w] < bb || (wK[w] == bb && wI[w] < ii)) { bb = wK[w]; ii = wI[w]; }
                outIdx[m + rr] = ii;
                keys[ii] = 0xFFFFFFFFu;
            }
            __syncthreads();
        }
    }
    __syncthreads();
    if (t < K) idx_out[(size_t)bp * K + t] = outIdx[t];
}

// ---------------------------------------------------------------------------
// SA1 precompute: A1t[b][n][o] = b1[o] + sum_c w1[o][c]*x[b][c][n] (unchanged).
// ---------------------------------------------------------------------------
__global__ __launch_bounds__(256) void sa1_pre_kernel(
    const float* __restrict__ x, const float* __restrict__ w1, const float* __restrict__ b1,
    float* __restrict__ a1t) {
    int bid = blockIdx.x;
    int b = bid >> 5, nt = bid & 31, n0 = nt << 7;
    __shared__ float xsh[6 * 128];
    __shared__ float wt[6 * 68];
    const float* xb = x + (size_t)b * 24576;
    int t = threadIdx.x;
    for (int id = t; id < 768; id += 256) {
        int c = id >> 7, n = id & 127;
        xsh[c * 128 + n] = xb[c * 4096 + n0 + n];
    }
    for (int id = t; id < 384; id += 256) {
        int c = id >> 6, o = id & 63;
        wt[c * 68 + o] = w1[o * 6 + c];
    }
    __syncthreads();
    int o = t & 63, ng = t >> 6;
    float acc[32];
    float bias = b1[o];
#pragma unroll
    for (int j = 0; j < 32; j++) acc[j] = bias;
    for (int c = 0; c < 6; c++) {
        float w = wt[c * 68 + o];
        const float* f = &xsh[c * 128 + ng * 32];
#pragma unroll
        for (int j = 0; j < 32; j++) acc[j] += w * f[j];
    }
#pragma unroll
    for (int j = 0; j < 32; j++)
        a1t[((size_t)b * 4096 + n0 + ng * 32 + j) * 64 + o] = acc[j];
}

// ---------------------------------------------------------------------------
// SA1 MFMA fused: gather h1 = relu(A1t[nbr]+D) -> L2 (64->64, relu) ->
// L3 (64->128) -> max over k=32. Block = 2 queries (64 j-cols), 256 thr.
// ---------------------------------------------------------------------------
__global__ __launch_bounds__(256) void sa1_mfma_kernel(
    const float* __restrict__ x, const float* __restrict__ a1t,
    const int* __restrict__ idx1, const float* __restrict__ w1,
    const unsigned short* __restrict__ w2f, const float* __restrict__ b2,
    const unsigned short* __restrict__ w3f, const float* __restrict__ b3,
    float* __restrict__ p1) {
    int bp = blockIdx.x;  // 32*256
    int b = bp >> 8, pp = bp & 255, p0 = pp * 2;
    __shared__ float dshq[2][64];
    __shared__ int nbr[64];
    __shared__ unsigned short A1buf[2 * 4 * 3 * 64 * 8];  // 24KB
    __shared__ float MX[4 * 128];
    const float* xb = x + (size_t)b * 24576;
    int t = threadIdx.x;
    int w = t >> 6, l = t & 63;
    int n16 = l & 15, og = l >> 4;
    if (t < 64) nbr[t] = idx1[((size_t)b * 512 + p0) * 32 + t];
    if (t < 128) {
        int qi = t >> 6, c = t & 63;
        float qx = xb[p0 + qi], qy = xb[4096 + p0 + qi], qz = xb[8192 + p0 + qi];
        dshq[qi][c] = -(w1[c * 6 + 0] * qx + w1[c * 6 + 1] * qy + w1[c * 6 + 2] * qz);
    }
    __syncthreads();
    int q = w >> 1;  // query of this wave's jtile
    // ---- phase 1: L2 (64 -> 64), K = 64c (2 ksteps), 4 otiles
    f4v acc1[4];
#pragma unroll
    for (int ot = 0; ot < 4; ot++) acc1[ot] = (f4v){0.f, 0.f, 0.f, 0.f};
    const float* gsrc = a1t + ((size_t)b * 4096 + nbr[w * 16 + n16]) * 64 + og * 8;
    for (int ks = 0; ks < 2; ks++) {
        f4v v0 = *(const f4v*)(gsrc + ks * 32);
        f4v v1 = *(const f4v*)(gsrc + ks * 32 + 4);
        const float* d = &dshq[q][ks * 32 + og * 8];
        s8v bf[3];
#pragma unroll
        for (int e = 0; e < 8; e++) {
            float hv = fmaxf(((e < 4) ? v0[e] : v1[e - 4]) + d[e], 0.f);
            unsigned short h0, h1, h2;
            split3(hv, h0, h1, h2);
            bf[0][e] = (short)h0; bf[1][e] = (short)h1; bf[2][e] = (short)h2;
        }
        const s8v* wr = (const s8v*)w2f + (size_t)(ks * 4) * 3 * 64;
#pragma unroll
        for (int ot = 0; ot < 4; ot++) {
            s8v a0 = wr[(ot * 3 + 0) * 64 + l];
            s8v a1 = wr[(ot * 3 + 1) * 64 + l];
            s8v a2 = wr[(ot * 3 + 2) * 64 + l];
            f4v c = acc1[ot];
            c = __builtin_amdgcn_mfma_f32_16x16x32_bf16(a2, bf[0], c, 0, 0, 0);
            c = __builtin_amdgcn_mfma_f32_16x16x32_bf16(a0, bf[2], c, 0, 0, 0);
            c = __builtin_amdgcn_mfma_f32_16x16x32_bf16(a1, bf[1], c, 0, 0, 0);
            c = __builtin_amdgcn_mfma_f32_16x16x32_bf16(a1, bf[0], c, 0, 0, 0);
            c = __builtin_amdgcn_mfma_f32_16x16x32_bf16(a0, bf[1], c, 0, 0, 0);
            c = __builtin_amdgcn_mfma_f32_16x16x32_bf16(a0, bf[0], c, 0, 0, 0);
            acc1[ot] = c;
        }
    }
    // ---- handoff: bias + relu + split -> A1buf (phase-2 A-frag order)
#pragma unroll
    for (int ot = 0; ot < 4; ot++) {
        f4v bv = *(const f4v*)(b2 + ot * 16 + og * 4);
        int ks2 = ot >> 1;
        int l2 = n16 + ((ot & 1) * 2 + (og >> 1)) * 16;
        int half = og & 1;
        unsigned short hh[3][4];
#pragma unroll
        for (int r = 0; r < 4; r++) {
            float y = fmaxf(acc1[ot][r] + bv[r], 0.f);
            split3(y, hh[0][r], hh[1][r], hh[2][r]);
        }
#pragma unroll
        for (int pl = 0; pl < 3; pl++) {
            unsigned long long pk = (unsigned long long)hh[pl][0] |
                ((unsigned long long)hh[pl][1] << 16) |
                ((unsigned long long)hh[pl][2] << 32) |
                ((unsigned long long)hh[pl][3] << 48);
            *(unsigned long long*)&A1buf[((((ks2 * 4 + w) * 3 + pl) * 64 + l2) * 8) + half * 4] = pk;
        }
    }
    // ---- phase 2: L3 (64 -> 128), K = 64 (2 ksteps), 8 otiles
    f4v acc2[8];
#pragma unroll
    for (int ot = 0; ot < 8; ot++) acc2[ot] = (f4v){0.f, 0.f, 0.f, 0.f};
    for (int ks2 = 0; ks2 < 2; ks2++) {
        s8v af0 = *(const s8v*)&A1buf[(((ks2 * 4 + w) * 3 + 0) * 64 + l) * 8];
        s8v af1 = *(const s8v*)&A1buf[(((ks2 * 4 + w) * 3 + 1) * 64 + l) * 8];
        s8v af2 = *(const s8v*)&A1buf[(((ks2 * 4 + w) * 3 + 2) * 64 + l) * 8];
        const s8v* wr = (const s8v*)w3f + (size_t)(ks2 * 8) * 3 * 64;
#pragma unroll
        for (int ot = 0; ot < 8; ot++) {
            s8v g0 = wr[(ot * 3 + 0) * 64 + l];
            s8v g1 = wr[(ot * 3 + 1) * 64 + l];
            s8v g2 = wr[(ot * 3 + 2) * 64 + l];
            f4v c = acc2[ot];
            c = __builtin_amdgcn_mfma_f32_16x16x32_bf16(af2, g0, c, 0, 0, 0);
            c = __builtin_amdgcn_mfma_f32_16x16x32_bf16(af0, g2, c, 0, 0, 0);
            c = __builtin_amdgcn_mfma_f32_16x16x32_bf16(af1, g1, c, 0, 0, 0);
            c = __builtin_amdgcn_mfma_f32_16x16x32_bf16(af1, g0, c, 0, 0, 0);
            c = __builtin_amdgcn_mfma_f32_16x16x32_bf16(af0, g1, c, 0, 0, 0);
            c = __builtin_amdgcn_mfma_f32_16x16x32_bf16(af0, g0, c, 0, 0, 0);
            acc2[ot] = c;
        }
    }
    // ---- epilogue: bias-after-max, reduce over j within wave -> MX[w][o2]
#pragma unroll
    for (int ot = 0; ot < 8; ot++) {
        float m = fmaxf(fmaxf(acc2[ot][0], acc2[ot][1]), fmaxf(acc2[ot][2], acc2[ot][3]));
        m = fmaxf(m, __shfl_xor(m, 16));
        m = fmaxf(m, __shfl_xor(m, 32));
        if (og == 0) MX[w * 128 + ot * 16 + n16] = m + b3[ot * 16 + n16];
    }
    __syncthreads();
    {
        int o = t & 127, qq = t >> 7;
        float v = fmaxf(MX[(qq * 2) * 128 + o], MX[(qq * 2 + 1) * 128 + o]);
        p1[((size_t)b * 128 + o) * 512 + p0 + qq] = v;
    }
}

// ---------------------------------------------------------------------------
// SA2 precompute: A2t[b][n][o] = b1[o] + sum_c w1[o][c]*[xyz;p1][b][c][n]
// (unchanged).
// ---------------------------------------------------------------------------
__global__ __launch_bounds__(256) void sa2_pre_kernel(
    const float* __restrict__ x, const float* __restrict__ p1,
    const float* __restrict__ w1, const float* __restrict__ b1,
    float* __restrict__ a2t) {
    int bid = blockIdx.x;
    int b = bid >> 2, nt = bid & 3, n0 = nt << 7;
    __shared__ float ins[2][16 * 128];
    __shared__ float wt[2][16 * 132];
    const float* xb = x + (size_t)b * 24576;
    const float* p1b = p1 + (size_t)b * 65536;
    int t = threadIdx.x;
    int og = t >> 3, pg = t & 7;
    int o0 = og * 4;
    float acc[4][16];
    {
        float bl[4] = {b1[o0], b1[o0 + 1], b1[o0 + 2], b1[o0 + 3]};
#pragma unroll
        for (int oi = 0; oi < 4; oi++)
#pragma unroll
            for (int j = 0; j < 16; j++) acc[oi][j] = bl[oi];
    }
    for (int id = t; id < 16 * 128; id += 256) {
        int n = id & 127, c = id >> 7;
        ins[0][c * 128 + n] = (c < 3) ? xb[c * 4096 + n0 + n]
                                      : p1b[(size_t)(c - 3) * 512 + n0 + n];
    }
    for (int id = t; id < 2048; id += 256) {
        int c = id & 15, oo = id >> 4;
        wt[0][c * 132 + oo] = w1[oo * 131 + c];
    }
    __syncthreads();
    for (int ch = 0; ch < 9; ch++) {
        int cs = (ch == 8) ? 3 : 16;
        if (ch < 8) {
            int c0n = (ch + 1) * 16;
            int csn = (ch == 7) ? 3 : 16;
            int nb = (ch + 1) & 1;
            for (int id = t; id < csn * 128; id += 256) {
                int n = id & 127, c = id >> 7;
                int cg = c0n + c;
                ins[nb][c * 128 + n] = (cg < 3) ? xb[cg * 4096 + n0 + n]
                                                : p1b[(size_t)(cg - 3) * 512 + n0 + n];
            }
            for (int id = t; id < 2048; id += 256) {
                int c = id & 15, oo = id >> 4;
                if (c < csn) wt[nb][c * 132 + oo] = w1[oo * 131 + c0n + c];
            }
        }
        const float* wb = wt[ch & 1];
        const float* ib = ins[ch & 1];
        for (int cc = 0; cc < cs; cc++) {
            float4 wv = *(const float4*)&wb[cc * 132 + o0];
            float wl[4] = {wv.x, wv.y, wv.z, wv.w};
#pragma unroll
            for (int c4 = 0; c4 < 4; c4++) {
                float4 fv = *(const float4*)&ib[cc * 128 + pg * 4 + c4 * 32];
                float fl[4] = {fv.x, fv.y, fv.z, fv.w};
#pragma unroll
                for (int j = 0; j < 4; j++)
#pragma unroll
                    for (int oi = 0; oi < 4; oi++) acc[oi][c4 * 4 + j] += wl[oi] * fl[j];
            }
        }
        __syncthreads();
    }
#pragma unroll
    for (int c4 = 0; c4 < 4; c4++)
#pragma unroll
        for (int j = 0; j < 4; j++) {
            int n = n0 + pg * 4 + c4 * 32 + j;
            float4 v;
            v.x = acc[0][c4 * 4 + j]; v.y = acc[1][c4 * 4 + j];
            v.z = acc[2][c4 * 4 + j]; v.w = acc[3][c4 * 4 + j];
            *(float4*)&a2t[((size_t)b * 512 + n) * 128 + o0] = v;
        }
}

// ---------------------------------------------------------------------------
// SA2 MFMA fused: gather h1 = relu(A2t[nbr]+D) -> L2 (128->128, relu) ->
// L3 (128->256) -> max over k=64. Block = 1 query, 256 thr, ~53KB LDS.
// ---------------------------------------------------------------------------
__global__ __launch_bounds__(256) void sa2_mfma_kernel(
    const float* __restrict__ x, const float* __restrict__ a2t,
    const int* __restrict__ idx2, const float* __restrict__ w1,
    const unsigned short* __restrict__ w2f, const float* __restrict__ b2,
    const unsigned short* __restrict__ w3f, const float* __restrict__ b3,
    float* __restrict__ p2) {
    int bp = blockIdx.x;  // 32*128
    int b = bp >> 7, p = bp & 127;
    __shared__ float dsh[128];
    __shared__ int nbr[64];
    __shared__ unsigned short A2buf[4 * 4 * 3 * 64 * 8];  // 48KB
    __shared__ float MX[4 * 256];
    const float* xb = x + (size_t)b * 24576;
    int t = threadIdx.x;
    int w = t >> 6, l = t & 63;
    int n16 = l & 15, og = l >> 4;
    if (t < 64) nbr[t] = idx2[((size_t)b * 128 + p) * 64 + t];
    if (t < 128) {
        float qx = xb[p], qy = xb[4096 + p], qz = xb[8192 + p];
        dsh[t] = -(w1[t * 131 + 0] * qx + w1[t * 131 + 1] * qy + w1[t * 131 + 2] * qz);
    }
    __syncthreads();
    // ---- phase 1: L2 (128 -> 128), K = 128c (4 ksteps), 8 otiles
    f4v acc1[8];
#pragma unroll
    for (int ot = 0; ot < 8; ot++) acc1[ot] = (f4v){0.f, 0.f, 0.f, 0.f};
    const float* gsrc = a2t + ((size_t)b * 512 + nbr[w * 16 + n16]) * 128 + og * 8;
    for (int ks = 0; ks < 4; ks++) {
        f4v v0 = *(const f4v*)(gsrc + ks * 32);
        f4v v1 = *(const f4v*)(gsrc + ks * 32 + 4);
        const float* d = &dsh[ks * 32 + og * 8];
        s8v bf[3];
#pragma unroll
        for (int e = 0; e < 8; e++) {
            float hv = fmaxf(((e < 4) ? v0[e] : v1[e - 4]) + d[e], 0.f);
            unsigned short h0, h1, h2;
            split3(hv, h0, h1, h2);
            bf[0][e] = (short)h0; bf[1][e] = (short)h1; bf[2][e] = (short)h2;
        }
        const s8v* wr = (const s8v*)w2f + (size_t)(ks * 8) * 3 * 64;
#pragma unroll
        for (int ot = 0; ot < 8; ot++) {
            s8v a0 = wr[(ot * 3 + 0) * 64 + l];
            s8v a1 = wr[(ot * 3 + 1) * 64 + l];
            s8v a2 = wr[(ot * 3 + 2) * 64 + l];
            f4v c = acc1[ot];
            c = __builtin_amdgcn_mfma_f32_16x16x32_bf16(a2, bf[0], c, 0, 0, 0);
            c = __builtin_amdgcn_mfma_f32_16x16x32_bf16(a0, bf[2], c, 0, 0, 0);
            c = __builtin_amdgcn_mfma_f32_16x16x32_bf16(a1, bf[1], c, 0, 0, 0);
            c = __builtin_amdgcn_mfma_f32_16x16x32_bf16(a1, bf[0], c, 0, 0, 0);
            c = __builtin_amdgcn_mfma_f32_16x16x32_bf16(a0, bf[1], c, 0, 0, 0);
            c = __builtin_amdgcn_mfma_f32_16x16x32_bf16(a0, bf[0], c, 0, 0, 0);
            acc1[ot] = c;
        }
    }
    // ---- handoff: bias + relu + split -> A2buf (phase-2 A-frag order)
#pragma unroll
    for (int ot = 0; ot < 8; ot++) {
        f4v bv = *(const f4v*)(b2 + ot * 16 + og * 4);
        int ks2 = ot >> 1;
        int l2 = n16 + ((ot & 1) * 2 + (og >> 1)) * 16;
        int half = og & 1;
        unsigned short hh[3][4];
#pragma unroll
        for (int r = 0; r < 4; r++) {
            float y = fmaxf(acc1[ot][r] + bv[r], 0.f);
            split3(y, hh[0][r], hh[1][r], hh[2][r]);
        }
#pragma unroll
        for (int pl = 0; pl < 3; pl++) {
            unsigned long long pk = (unsigned long long)hh[pl][0] |
                ((unsigned long long)hh[pl][1] << 16) |
                ((unsigned long long)hh[pl][2] << 32) |
                ((unsigned long long)hh[pl][3] << 48);
            *(unsigned long long*)&A2buf[((((ks2 * 4 + w) * 3 + pl) * 64 + l2) * 8) + half * 4] = pk;
        }
    }
    // ---- phase 2: L3 (128 -> 256), K = 128 (4 ksteps), 16 otiles
    f4v acc2[16];
#pragma unroll
    for (int ot = 0; ot < 16; ot++) acc2[ot] = (f4v){0.f, 0.f, 0.f, 0.f};
    for (int ks2 = 0; ks2 < 4; ks2++) {
        s8v af0 = *(const s8v*)&A2buf[(((ks2 * 4 + w) * 3 + 0) * 64 + l) * 8];
        s8v af1 = *(const s8v*)&A2buf[(((ks2 * 4 + w) * 3 + 1) * 64 + l) * 8];
        s8v af2 = *(const s8v*)&A2buf[(((ks2 * 4 + w) * 3 + 2) * 64 + l) * 8];
        const s8v* wr = (const s8v*)w3f + (size_t)(ks2 * 16) * 3 * 64;
#pragma unroll
        for (int ot = 0; ot < 16; ot++) {
            s8v g0 = wr[(ot * 3 + 0) * 64 + l];
            s8v g1 = wr[(ot * 3 + 1) * 64 + l];
            s8v g2 = wr[(ot * 3 + 2) * 64 + l];
            f4v c = acc2[ot];
            c = __builtin_amdgcn_mfma_f32_16x16x32_bf16(af2, g0, c, 0, 0, 0);
            c = __builtin_amdgcn_mfma_f32_16x16x32_bf16(af0, g2, c, 0, 0, 0);
            c = __builtin_amdgcn_mfma_f32_16x16x32_bf16(af1, g1, c, 0, 0, 0);
            c = __builtin_amdgcn_mfma_f32_16x16x32_bf16(af1, g0, c, 0, 0, 0);
            c = __builtin_amdgcn_mfma_f32_16x16x32_bf16(af0, g1, c, 0, 0, 0);
            c = __builtin_amdgcn_mfma_f32_16x16x32_bf16(af0, g0, c, 0, 0, 0);
            acc2[ot] = c;
        }
    }
    // ---- epilogue: bias-after-max, reduce over j within wave -> MX[w][o2]
#pragma unroll
    for (int ot = 0; ot < 16; ot++) {
        float m = fmaxf(fmaxf(acc2[ot][0], acc2[ot][1]), fmaxf(acc2[ot][2], acc2[ot][3]));
        m = fmaxf(m, __shfl_xor(m, 16));
        m = fmaxf(m, __shfl_xor(m, 32));
        if (og == 0) MX[w * 256 + ot * 16 + n16] = m + b3[ot * 16 + n16];
    }
    __syncthreads();
    {
        float v = fmaxf(fmaxf(MX[t], MX[256 + t]), fmaxf(MX[512 + t], MX[768 + t]));
        p2[((size_t)b * 256 + t) * 128 + p] = v;
    }
}

// ---------------------------------------------------------------------------
// SA3 batched GEMM over 128 points (unchanged).
// ---------------------------------------------------------------------------
__global__ __launch_bounds__(256) void mlp128_kernel(
    const float* __restrict__ in, const float* __restrict__ W,
    const float* __restrict__ bias, float* __restrict__ out,
    int Cin, int Cout, int relu, int wstride, int woff, int reduce) {
    int bid = blockIdx.x;
    int tiles = Cout >> 6;
    int b = bid / tiles, ot = bid - b * tiles;
    int o0t = ot << 6;
    __shared__ float ins[64 * 128];
    __shared__ float wt[2][16 * 68];
    __shared__ float gmx[64 * 8];
    int t = threadIdx.x;
    int og = t >> 3, pg = t & 7;
    int o = o0t + og * 2;
    float acc[2][16];
    {
        float bb0 = bias[o], bb1 = bias[o + 1];
#pragma unroll
        for (int j = 0; j < 16; j++) { acc[0][j] = bb0; acc[1][j] = bb1; }
    }
    int nslab = Cin >> 6;
    for (int sl = 0; sl < nslab; sl++) {
        __syncthreads();
        for (int id = t; id < 2048; id += 256) {
            int p4 = id & 31, c = id >> 5;
            *(float4*)&ins[c * 128 + p4 * 4] =
                *(const float4*)&in[((size_t)b * Cin + sl * 64 + c) * 128 + p4 * 4];
        }
        for (int id = t; id < 1024; id += 256) {
            int c = id & 15, oo = id >> 4;
            wt[0][c * 68 + oo] = W[(size_t)(o0t + oo) * wstride + woff + sl * 64 + c];
        }
        __syncthreads();
        for (int ch = 0; ch < 4; ch++) {
            if (ch < 3) {
                int nb = (ch + 1) & 1;
                for (int id = t; id < 1024; id += 256) {
                    int c = id & 15, oo = id >> 4;
                    wt[nb][c * 68 + oo] =
                        W[(size_t)(o0t + oo) * wstride + woff + sl * 64 + (ch + 1) * 16 + c];
                }
            }
            const float* wb = wt[ch & 1];
#pragma unroll
            for (int cc = 0; cc < 16; cc++) {
                float2 wv = *(const float2*)&wb[cc * 68 + og * 2];
                const float* f = &ins[(ch * 16 + cc) * 128 + pg * 4];
#pragma unroll
                for (int c4 = 0; c4 < 4; c4++) {
                    float4 fv = *(const float4*)&f[c4 * 32];
                    float fl[4] = {fv.x, fv.y, fv.z, fv.w};
#pragma unroll
                    for (int j = 0; j < 4; j++) {
                        acc[0][c4 * 4 + j] += wv.x * fl[j];
                        acc[1][c4 * 4 + j] += wv.y * fl[j];
                    }
                }
            }
            __syncthreads();
        }
    }
    if (!reduce) {
#pragma unroll
        for (int oi = 0; oi < 2; oi++)
#pragma unroll
            for (int c4 = 0; c4 < 4; c4++) {
                float4 v;
                v.x = acc[oi][c4 * 4 + 0]; v.y = acc[oi][c4 * 4 + 1];
                v.z = acc[oi][c4 * 4 + 2]; v.w = acc[oi][c4 * 4 + 3];
                if (relu) {
                    v.x = fmaxf(v.x, 0.f); v.y = fmaxf(v.y, 0.f);
                    v.z = fmaxf(v.z, 0.f); v.w = fmaxf(v.w, 0.f);
                }
                *(float4*)&out[((size_t)b * Cout + o + oi) * 128 + pg * 4 + c4 * 32] = v;
            }
    } else {
#pragma unroll
        for (int oi = 0; oi < 2; oi++) {
            float mm = acc[oi][0];
#pragma unroll
            for (int j = 1; j < 16; j++) mm = fmaxf(mm, acc[oi][j]);
            gmx[(og * 2 + oi) * 8 + pg] = mm;
        }
        __syncthreads();
        if (t < 64) {
            float mm = gmx[t * 8];
#pragma unroll
            for (int i = 1; i < 8; i++) mm = fmaxf(mm, gmx[t * 8 + i]);
            out[(size_t)b * Cout + o0t + t] = mm;
        }
    }
}

// ---------------------------------------------------------------------------
// Head: FC 1024->512->256->40 (unchanged).
// ---------------------------------------------------------------------------
__global__ __launch_bounds__(256) void head_kernel(
    const float* __restrict__ g,
    const float* __restrict__ fw1, const float* __restrict__ fb1,
    const float* __restrict__ fw2, const float* __restrict__ fb2,
    const float* __restrict__ fw3, const float* __restrict__ fb3,
    float* __restrict__ out) {
    int b = blockIdx.x;
    int t = threadIdx.x;
    __shared__ float gs[1024];
    __shared__ float h1[512];
    __shared__ float h2[256];
    for (int i = t; i < 1024; i += 256) gs[i] = g[(size_t)b * 1024 + i];
    __syncthreads();
    for (int oo = 0; oo < 2; oo++) {
        int o = t + oo * 256;
        float acc = fb1[o];
        const float4* wr = (const float4*)&fw1[(size_t)o * 1024];
        for (int c = 0; c < 256; c++) {
            float4 wv = wr[c];
            acc += wv.x * gs[c * 4] + wv.y * gs[c * 4 + 1] + wv.z * gs[c * 4 + 2] + wv.w * gs[c * 4 + 3];
        }
        h1[o] = fmaxf(acc, 0.f);
    }
    __syncthreads();
    {
        float acc = fb2[t];
        const float4* wr = (const float4*)&fw2[(size_t)t * 512];
        for (int c = 0; c < 128; c++) {
            float4 wv = wr[c];
            acc += wv.x * h1[c * 4] + wv.y * h1[c * 4 + 1] + wv.z * h1[c * 4 + 2] + wv.w * h1[c * 4 + 3];
        }
        h2[t] = fmaxf(acc, 0.f);
    }
    __syncthreads();
    if (t < 40) {
        float acc = fb3[t];
        const float4* wr = (const float4*)&fw3[(size_t)t * 256];
        for (int c = 0; c < 64; c++) {
            float4 wv = wr[c];
            acc += wv.x * h2[c * 4] + wv.y * h2[c * 4 + 1] + wv.z * h2[c * 4 + 2] + wv.w * h2[c * 4 + 3];
        }
        out[b * 40 + t] = acc;
    }
}

extern "C" void kernel_launch(void* const* d_in, const int* in_sizes, int n_in,
                              void* d_out, int out_size, void* d_ws, size_t ws_size,
                              hipStream_t stream) {
    const float* x      = (const float*)d_in[0];
    const float* sa1_w1 = (const float*)d_in[1];
    const float* sa1_b1 = (const float*)d_in[2];
    const float* sa1_w2 = (const float*)d_in[3];
    const float* sa1_b2 = (const float*)d_in[4];
    const float* sa1_w3 = (const float*)d_in[5];
    const float* sa1_b3 = (const float*)d_in[6];
    const float* sa2_w1 = (const float*)d_in[7];
    const float* sa2_b1 = (const float*)d_in[8];
    const float* sa2_w2 = (const float*)d_in[9];
    const float* sa2_b2 = (const float*)d_in[10];
    const float* sa2_w3 = (const float*)d_in[11];
    const float* sa2_b3 = (const float*)d_in[12];
    const float* sa3_w1 = (const float*)d_in[13];
    const float* sa3_b1 = (const float*)d_in[14];
    const float* sa3_w2 = (const float*)d_in[15];
    const float* sa3_b2 = (const float*)d_in[16];
    const float* sa3_w3 = (const float*)d_in[17];
    const float* sa3_b3 = (const float*)d_in[18];
    const float* fc1_w  = (const float*)d_in[19];
    const float* fc1_b  = (const float*)d_in[20];
    const float* fc2_w  = (const float*)d_in[21];
    const float* fc2_b  = (const float*)d_in[22];
    const float* fc3_w  = (const float*)d_in[23];
    const float* fc3_b  = (const float*)d_in[24];

    char* ws = (char*)d_ws;
    const size_t MB = 1048576;
    const size_t KB = 1024;
    // Fragment buffers live in [0, 0.5MB) — nothing else touches this range.
    unsigned short* s1w2f = (unsigned short*)(ws + 0);          //  24 KB
    unsigned short* s1w3f = (unsigned short*)(ws + 32 * KB);    //  48 KB
    unsigned short* s2w2f = (unsigned short*)(ws + 128 * KB);   //  96 KB
    unsigned short* s2w3f = (unsigned short*)(ws + 224 * KB);   // 192 KB (ends 416KB)
    int*   idx1 = (int*)  (ws + 512 * KB);  //  2 MB: (32,512,32)  [0.5..2.5MB)
    float* a1t  = (float*)(ws + 3 * MB);    // 32 MB: (32,4096,64) [3..35MB) dead after sa1_mfma
    float* p1   = (float*)(ws + 35 * MB);   //  8 MB: (32,128,512) [35..43MB)
    int*   idx2 = (int*)  (ws + 3 * MB);    //  1 MB: overlays dead a1t
    float* a2t  = (float*)(ws + 4 * MB);    //  8 MB: overlays dead a1t [4..12MB)
    float* p2   = (float*)(ws + 12 * MB);   //  4 MB: [12..16MB)
    float* h1s  = (float*)(ws + 16 * MB);   //  4 MB: [16..20MB)
    float* h2s  = (float*)(ws + 20 * MB);   //  8 MB: [20..28MB)
    float* g    = (float*)(ws + 28 * MB);   //  128 KB

    // Weight fragment precompute (tiny): grid = (K/32) * (O/16), 64 thr.
    wfrag_kernel<<<2 * 4, 64, 0, stream>>>(sa1_w2, 64, 4, s1w2f);
    wfrag_kernel<<<2 * 8, 64, 0, stream>>>(sa1_w3, 64, 8, s1w3f);
    wfrag_kernel<<<4 * 8, 64, 0, stream>>>(sa2_w2, 128, 8, s2w2f);
    wfrag_kernel<<<4 * 16, 64, 0, stream>>>(sa2_w3, 128, 16, s2w3f);

    knn_select_kernel<<<32 * 512, 256, 0, stream>>>(x, 4096, 32, 512, idx1);
    sa1_pre_kernel<<<32 * 32, 256, 0, stream>>>(x, sa1_w1, sa1_b1, a1t);
    sa1_mfma_kernel<<<32 * 256, 256, 0, stream>>>(x, a1t, idx1, sa1_w1,
                                                  s1w2f, sa1_b2, s1w3f, sa1_b3, p1);
    knn_select_kernel<<<32 * 128, 256, 0, stream>>>(x, 512, 64, 128, idx2);
    sa2_pre_kernel<<<32 * 4, 256, 0, stream>>>(x, p1, sa2_w1, sa2_b1, a2t);
    sa2_mfma_kernel<<<32 * 128, 256, 0, stream>>>(x, a2t, idx2, sa2_w1,
                                                  s2w2f, sa2_b2, s2w3f, sa2_b3, p2);
    mlp128_kernel<<<32 * 4, 256, 0, stream>>>(p2, sa3_w1, sa3_b1, h1s, 256, 256, 1, 259, 3, 0);
    mlp128_kernel<<<32 * 8, 256, 0, stream>>>(h1s, sa3_w2, sa3_b2, h2s, 256, 512, 1, 256, 0, 0);
    mlp128_kernel<<<32 * 16, 256, 0, stream>>>(h2s, sa3_w3, sa3_b3, g, 512, 1024, 0, 512, 0, 1);
    head_kernel<<<32, 256, 0, stream>>>(g, fc1_w, fc1_b, fc2_w, fc2_b, fc3_w, fc3_b,
                                        (float*)d_out);
}

// Round 7
// 662.393 us; speedup vs baseline: 1.4170x; 1.2433x over previous
//
#include <hip/hip_runtime.h>
#include <hip/hip_bf16.h>

#define FLT_BIG 3.0e38f

typedef __attribute__((ext_vector_type(8))) short s8v;
typedef __attribute__((ext_vector_type(4))) float f4v;

// ---------------------------------------------------------------------------
// bf16 3-plane split helpers (RNE). x ~= x0 + x1 + x2 exactly to ~2^-27 rel.
// ---------------------------------------------------------------------------
__device__ inline unsigned short bf_hi(float v, float& res) {
    unsigned int u = __float_as_uint(v);
    unsigned int r = (u + 0x7FFFu + ((u >> 16) & 1u)) >> 16;
    res = v - __uint_as_float(r << 16);
    return (unsigned short)r;
}
__device__ inline void split3(float v, unsigned short& h0, unsigned short& h1,
                              unsigned short& h2) {
    float r1, r2, r3;
    h0 = bf_hi(v, r1);
    h1 = bf_hi(r1, r2);
    h2 = bf_hi(r2, r3);
}

// MFMA plane-combo steps, smallest products first (matches prior rounds).
// Phase1: A = weight frags aw[oi][pl], B = act frags bfr[jf][pl].
#define SA2_P1(AI, BI)                                                          \
    _Pragma("unroll") for (int oi = 0; oi < 2; oi++) {                          \
        _Pragma("unroll") for (int jf = 0; jf < 4; jf++)                        \
            acc1[oi][jf] = __builtin_amdgcn_mfma_f32_16x16x32_bf16(             \
                aw[oi][AI], bfr[jf][BI], acc1[oi][jf], 0, 0, 0);                \
    }
#define SA1_P1(AI, BI)                                                          \
    _Pragma("unroll") for (int jf = 0; jf < 4; jf++)                            \
        acc1[jf] = __builtin_amdgcn_mfma_f32_16x16x32_bf16(                     \
            aw[AI], bfr[jf][BI], acc1[jf], 0, 0, 0);
// Phase2: A = act frags af[jf][pl], B = weight frags gw[oi][pl].
#define MM_P2(AI, BI)                                                           \
    _Pragma("unroll") for (int oi = 0; oi < 2; oi++) {                          \
        _Pragma("unroll") for (int jf = 0; jf < 4; jf++)                        \
            acc2[oi][jf] = __builtin_amdgcn_mfma_f32_16x16x32_bf16(             \
                af[jf][AI], gw[oi][BI], acc2[oi][jf], 0, 0, 0);                 \
    }

// ---------------------------------------------------------------------------
// Weight fragment precompute: W[O][K] row-major fp32 -> frag-ordered bf16
// planes. Fragment (ks, ot): lane l holds W[ot*16 + (l&15)][ks*32 + (l>>4)*8
// + e], e=0..7, at out[((ks*no + ot)*3 + plane)*64*8 + l*8 + e].
// ---------------------------------------------------------------------------
__global__ __launch_bounds__(64) void wfrag_kernel(
    const float* __restrict__ W, int K, int no, unsigned short* __restrict__ out) {
    int bid = blockIdx.x;              // = ks*no + ot
    int l = threadIdx.x;
    int ks = bid / no, ot = bid - ks * no;
    int o = ot * 16 + (l & 15);
    int k0 = ks * 32 + (l >> 4) * 8;
    const float* src = W + (size_t)o * K + k0;
    unsigned short h[3][8];
#pragma unroll
    for (int e = 0; e < 8; e++) split3(src[e], h[0][e], h[1][e], h[2][e]);
#pragma unroll
    for (int p = 0; p < 3; p++) {
        s8v v;
#pragma unroll
        for (int e = 0; e < 8; e++) v[e] = (short)h[p][e];
        *(s8v*)(out + ((size_t)(bid * 3 + p) * 64 + l) * 8) = v;
    }
}

// ---------------------------------------------------------------------------
// kNN via radix select (unchanged).
// ---------------------------------------------------------------------------
__global__ __launch_bounds__(256) void knn_select_kernel(
    const float* __restrict__ x, int N_pts, int K, int P, int* __restrict__ idx_out) {
    int bp = blockIdx.x;
    int b = bp / P, p = bp - b * P;
    const float* xyz = x + (size_t)b * 24576;
    __shared__ unsigned int keys[4096];
    __shared__ unsigned int hist[2048];
    __shared__ unsigned int scanbuf[256];
    __shared__ unsigned int candK[512];
    __shared__ int candI[512];
    __shared__ int outIdx[64];
    __shared__ int sBM[2];
    __shared__ unsigned int cnts[2];
    __shared__ unsigned int wK[4];
    __shared__ int wI[4];
    int t = threadIdx.x;
    for (int i = t; i < 2048; i += 256) hist[i] = 0u;
    if (t < 2) cnts[t] = 0u;
    float qx = xyz[p], qy = xyz[4096 + p], qz = xyz[8192 + p];
    float xs = (qx * qx + qy * qy) + qz * qz;
    __syncthreads();
    for (int n = t; n < N_pts; n += 256) {
        float yx = xyz[n], yy = xyz[4096 + n], yz = xyz[8192 + n];
        float ys = (yx * yx + yy * yy) + yz * yz;
        float dot = (qx * yx + qy * yy) + qz * yz;
        float d2 = (xs + ys) - 2.0f * dot;
        unsigned int k = __float_as_uint(d2);
        k = (k & 0x80000000u) ? ~k : (k | 0x80000000u);
        keys[n] = k;
        atomicAdd(&hist[k >> 21], 1u);
    }
    __syncthreads();
    unsigned int h8[8], mysum = 0u;
#pragma unroll
    for (int i = 0; i < 8; i++) { h8[i] = hist[t * 8 + i]; mysum += h8[i]; }
    scanbuf[t] = mysum;
    __syncthreads();
    for (int s = 1; s < 256; s <<= 1) {
        unsigned int v = (t >= s) ? scanbuf[t - s] : 0u;
        __syncthreads();
        scanbuf[t] += v;
        __syncthreads();
    }
    unsigned int cum = scanbuf[t] - mysum;
#pragma unroll
    for (int i = 0; i < 8; i++) {
        if (cum < (unsigned)K && cum + h8[i] >= (unsigned)K) { sBM[0] = t * 8 + i; sBM[1] = (int)cum; }
        cum += h8[i];
    }
    __syncthreads();
    int B = sBM[0], m = sBM[1], r = K - m;
    for (int n = t; n < N_pts; n += 256) {
        unsigned int k = keys[n];
        int bin = (int)(k >> 21);
        if (bin < B) {
            outIdx[atomicAdd(&cnts[0], 1u)] = n;
        } else if (bin == B) {
            unsigned int ci = atomicAdd(&cnts[1], 1u);
            if (ci < 512u) { candK[ci] = k; candI[ci] = n; }
        }
    }
    __syncthreads();
    int nc = (int)cnts[1];
    if (nc <= 512) {
        for (int ci = t; ci < nc; ci += 256) {
            unsigned int ki = candK[ci];
            int ii = candI[ci];
            int rank = 0;
            for (int j = 0; j < nc; j++) {
                unsigned int kj = candK[j];
                rank += (kj < ki || (kj == ki && candI[j] < ii)) ? 1 : 0;
            }
            if (rank < r) outIdx[m + rank] = ii;
        }
    } else {
        for (int rr = 0; rr < r; ++rr) {
            unsigned int best = 0xFFFFFFFFu;
            int bi = 0x7fffffff;
            for (int n = t; n < N_pts; n += 256) {
                unsigned int k2 = keys[n];
                if ((int)(k2 >> 21) == B && (k2 < best || (k2 == best && n < bi))) { best = k2; bi = n; }
            }
#pragma unroll
            for (int s = 32; s > 0; s >>= 1) {
                unsigned int ov = (unsigned int)__shfl_down((int)best, s);
                int oi = __shfl_down(bi, s);
                if (ov < best || (ov == best && oi < bi)) { best = ov; bi = oi; }
            }
            int lane = t & 63, wv = t >> 6;
            if (lane == 0) { wK[wv] = best; wI[wv] = bi; }
            __syncthreads();
            if (t == 0) {
                unsigned int bb = wK[0];
                int ii = wI[0];
                for (int w = 1; w < 4; ++w)
                    if (wK[w] < bb || (wK[w] == bb && wI[w] < ii)) { bb = wK[w]; ii = wI[w]; }
                outIdx[m + rr] = ii;
                keys[ii] = 0xFFFFFFFFu;
            }
            __syncthreads();
        }
    }
    __syncthreads();
    if (t < K) idx_out[(size_t)bp * K + t] = outIdx[t];
}

// ---------------------------------------------------------------------------
// SA1 precompute: A1t[b][n][o] = b1[o] + sum_c w1[o][c]*x[b][c][n] (unchanged).
// ---------------------------------------------------------------------------
__global__ __launch_bounds__(256) void sa1_pre_kernel(
    const float* __restrict__ x, const float* __restrict__ w1, const float* __restrict__ b1,
    float* __restrict__ a1t) {
    int bid = blockIdx.x;
    int b = bid >> 5, nt = bid & 31, n0 = nt << 7;
    __shared__ float xsh[6 * 128];
    __shared__ float wt[6 * 68];
    const float* xb = x + (size_t)b * 24576;
    int t = threadIdx.x;
    for (int id = t; id < 768; id += 256) {
        int c = id >> 7, n = id & 127;
        xsh[c * 128 + n] = xb[c * 4096 + n0 + n];
    }
    for (int id = t; id < 384; id += 256) {
        int c = id >> 6, o = id & 63;
        wt[c * 68 + o] = w1[o * 6 + c];
    }
    __syncthreads();
    int o = t & 63, ng = t >> 6;
    float acc[32];
    float bias = b1[o];
#pragma unroll
    for (int j = 0; j < 32; j++) acc[j] = bias;
    for (int c = 0; c < 6; c++) {
        float w = wt[c * 68 + o];
        const float* f = &xsh[c * 128 + ng * 32];
#pragma unroll
        for (int j = 0; j < 32; j++) acc[j] += w * f[j];
    }
#pragma unroll
    for (int j = 0; j < 32; j++)
        a1t[((size_t)b * 4096 + n0 + ng * 32 + j) * 64 + o] = acc[j];
}

// ---------------------------------------------------------------------------
// SA1 MFMA fused v2: weights read once per BLOCK (otiles split across waves,
// activations shared via LDS). Block = 2 queries (64 j = 4 jfrags), 256 thr.
// Phase1 (L2 64->64): wave w owns otile w, all 4 jfrags.
// Phase2 (L3 64->128): wave w owns otiles {2w,2w+1}, all 4 jfrags.
// LDS ~26KB -> 6 blocks/CU. MFMA plane-combo-major (no dependent chains).
// ---------------------------------------------------------------------------
__global__ __launch_bounds__(256) void sa1_mfma_kernel(
    const float* __restrict__ x, const float* __restrict__ a1t,
    const int* __restrict__ idx1, const float* __restrict__ w1,
    const unsigned short* __restrict__ w2f, const float* __restrict__ b2,
    const unsigned short* __restrict__ w3f, const float* __restrict__ b3,
    float* __restrict__ p1) {
    int bp = blockIdx.x;  // 32*256
    int b = bp >> 8, pp = bp & 255, p0 = pp * 2;
    __shared__ float dshq[2][64];
    __shared__ int nbr[64];
    __shared__ unsigned short A1buf[8 * 3 * 64 * 8];  // 24KB; first 12KB doubles as BF
    __shared__ float MX[2][128];
    unsigned short* BF = A1buf;  // [jf*3+pl][64][8] phase1 act frags (aliased)
    const float* xb = x + (size_t)b * 24576;
    int t = threadIdx.x;
    int w = t >> 6, l = t & 63;
    int n16 = l & 15, og = l >> 4;
    if (t < 64) nbr[t] = idx1[((size_t)b * 512 + p0) * 32 + t];
    if (t < 128) {
        int qi = t >> 6, c = t & 63;
        float qx = xb[p0 + qi], qy = xb[4096 + p0 + qi], qz = xb[8192 + p0 + qi];
        dshq[qi][c] = -(w1[c * 6 + 0] * qx + w1[c * 6 + 1] * qy + w1[c * 6 + 2] * qz);
    }
    __syncthreads();
    int q = w >> 1;  // query of this wave's gathered jfrag
    // ---- phase 1: L2 (64->64), 2 ksteps; wave owns otile w, all jfrags
    f4v acc1[4];
#pragma unroll
    for (int jf = 0; jf < 4; jf++) acc1[jf] = (f4v){0.f, 0.f, 0.f, 0.f};
    const float* gsrc = a1t + ((size_t)b * 4096 + nbr[w * 16 + n16]) * 64 + og * 8;
    for (int ks = 0; ks < 2; ks++) {
        f4v v0 = *(const f4v*)(gsrc + ks * 32);
        f4v v1 = *(const f4v*)(gsrc + ks * 32 + 4);
        const float* d = &dshq[q][ks * 32 + og * 8];
        s8v sp0, sp1, sp2;
#pragma unroll
        for (int e = 0; e < 8; e++) {
            float hv = fmaxf(((e < 4) ? v0[e] : v1[e - 4]) + d[e], 0.f);
            unsigned short h0, h1, h2;
            split3(hv, h0, h1, h2);
            sp0[e] = (short)h0; sp1[e] = (short)h1; sp2[e] = (short)h2;
        }
        *(s8v*)&BF[((w * 3 + 0) * 64 + l) * 8] = sp0;
        *(s8v*)&BF[((w * 3 + 1) * 64 + l) * 8] = sp1;
        *(s8v*)&BF[((w * 3 + 2) * 64 + l) * 8] = sp2;
        __syncthreads();
        s8v bfr[4][3];
#pragma unroll
        for (int jf = 0; jf < 4; jf++)
#pragma unroll
            for (int pl = 0; pl < 3; pl++)
                bfr[jf][pl] = *(const s8v*)&BF[((jf * 3 + pl) * 64 + l) * 8];
        const s8v* wr = (const s8v*)w2f + (size_t)(ks * 4) * 3 * 64;
        s8v aw[3];
#pragma unroll
        for (int pl = 0; pl < 3; pl++) aw[pl] = wr[(w * 3 + pl) * 64 + l];
        SA1_P1(2, 0) SA1_P1(0, 2) SA1_P1(1, 1)
        SA1_P1(1, 0) SA1_P1(0, 1) SA1_P1(0, 0)
        __syncthreads();
    }
    // ---- handoff: ot = w -> ks2 = w>>1, oi = w&1
    {
        f4v bv = *(const f4v*)(b2 + w * 16 + og * 4);
        int l2 = n16 + ((w & 1) * 2 + (og >> 1)) * 16;
        int half = og & 1;
#pragma unroll
        for (int jf = 0; jf < 4; jf++) {
            unsigned short hh[3][4];
#pragma unroll
            for (int r = 0; r < 4; r++) {
                float y = fmaxf(acc1[jf][r] + bv[r], 0.f);
                split3(y, hh[0][r], hh[1][r], hh[2][r]);
            }
            int slot = (w >> 1) * 4 + jf;
#pragma unroll
            for (int pl = 0; pl < 3; pl++) {
                unsigned long long pk = (unsigned long long)hh[pl][0] |
                    ((unsigned long long)hh[pl][1] << 16) |
                    ((unsigned long long)hh[pl][2] << 32) |
                    ((unsigned long long)hh[pl][3] << 48);
                *(unsigned long long*)&A1buf[((slot * 3 + pl) * 64 + l2) * 8 + half * 4] = pk;
            }
        }
    }
    __syncthreads();
    // ---- phase 2: L3 (64->128), 2 ksteps; wave owns otiles {2w,2w+1}
    f4v acc2[2][4];
#pragma unroll
    for (int oi = 0; oi < 2; oi++)
#pragma unroll
        for (int jf = 0; jf < 4; jf++) acc2[oi][jf] = (f4v){0.f, 0.f, 0.f, 0.f};
    for (int ks2 = 0; ks2 < 2; ks2++) {
        s8v af[4][3];
#pragma unroll
        for (int jf = 0; jf < 4; jf++)
#pragma unroll
            for (int pl = 0; pl < 3; pl++)
                af[jf][pl] = *(const s8v*)&A1buf[(((ks2 * 4 + jf) * 3 + pl) * 64 + l) * 8];
        const s8v* wr = (const s8v*)w3f + (size_t)(ks2 * 8) * 3 * 64;
        s8v gw[2][3];
#pragma unroll
        for (int oi = 0; oi < 2; oi++)
#pragma unroll
            for (int pl = 0; pl < 3; pl++)
                gw[oi][pl] = wr[((w * 2 + oi) * 3 + pl) * 64 + l];
        MM_P2(2, 0) MM_P2(0, 2) MM_P2(1, 1)
        MM_P2(1, 0) MM_P2(0, 1) MM_P2(0, 0)
    }
    // ---- epilogue: per otile, max over jfrags split by query
#pragma unroll
    for (int oi = 0; oi < 2; oi++) {
        float m0 = fmaxf(fmaxf(acc2[oi][0][0], acc2[oi][0][1]),
                         fmaxf(acc2[oi][0][2], acc2[oi][0][3]));
        m0 = fmaxf(m0, fmaxf(fmaxf(acc2[oi][1][0], acc2[oi][1][1]),
                             fmaxf(acc2[oi][1][2], acc2[oi][1][3])));
        float m1 = fmaxf(fmaxf(acc2[oi][2][0], acc2[oi][2][1]),
                         fmaxf(acc2[oi][2][2], acc2[oi][2][3]));
        m1 = fmaxf(m1, fmaxf(fmaxf(acc2[oi][3][0], acc2[oi][3][1]),
                             fmaxf(acc2[oi][3][2], acc2[oi][3][3])));
        m0 = fmaxf(m0, __shfl_xor(m0, 16));
        m0 = fmaxf(m0, __shfl_xor(m0, 32));
        m1 = fmaxf(m1, __shfl_xor(m1, 16));
        m1 = fmaxf(m1, __shfl_xor(m1, 32));
        if (og == 0) {
            MX[0][(w * 2 + oi) * 16 + n16] = m0;
            MX[1][(w * 2 + oi) * 16 + n16] = m1;
        }
    }
    __syncthreads();
    {
        int o = t & 127, qq = t >> 7;
        p1[((size_t)b * 128 + o) * 512 + p0 + qq] = MX[qq][o] + b3[o];
    }
}

// ---------------------------------------------------------------------------
// SA2 precompute (unchanged).
// ---------------------------------------------------------------------------
__global__ __launch_bounds__(256) void sa2_pre_kernel(
    const float* __restrict__ x, const float* __restrict__ p1,
    const float* __restrict__ w1, const float* __restrict__ b1,
    float* __restrict__ a2t) {
    int bid = blockIdx.x;
    int b = bid >> 2, nt = bid & 3, n0 = nt << 7;
    __shared__ float ins[2][16 * 128];
    __shared__ float wt[2][16 * 132];
    const float* xb = x + (size_t)b * 24576;
    const float* p1b = p1 + (size_t)b * 65536;
    int t = threadIdx.x;
    int og = t >> 3, pg = t & 7;
    int o0 = og * 4;
    float acc[4][16];
    {
        float bl[4] = {b1[o0], b1[o0 + 1], b1[o0 + 2], b1[o0 + 3]};
#pragma unroll
        for (int oi = 0; oi < 4; oi++)
#pragma unroll
            for (int j = 0; j < 16; j++) acc[oi][j] = bl[oi];
    }
    for (int id = t; id < 16 * 128; id += 256) {
        int n = id & 127, c = id >> 7;
        ins[0][c * 128 + n] = (c < 3) ? xb[c * 4096 + n0 + n]
                                      : p1b[(size_t)(c - 3) * 512 + n0 + n];
    }
    for (int id = t; id < 2048; id += 256) {
        int c = id & 15, oo = id >> 4;
        wt[0][c * 132 + oo] = w1[oo * 131 + c];
    }
    __syncthreads();
    for (int ch = 0; ch < 9; ch++) {
        int cs = (ch == 8) ? 3 : 16;
        if (ch < 8) {
            int c0n = (ch + 1) * 16;
            int csn = (ch == 7) ? 3 : 16;
            int nb = (ch + 1) & 1;
            for (int id = t; id < csn * 128; id += 256) {
                int n = id & 127, c = id >> 7;
                int cg = c0n + c;
                ins[nb][c * 128 + n] = (cg < 3) ? xb[cg * 4096 + n0 + n]
                                                : p1b[(size_t)(cg - 3) * 512 + n0 + n];
            }
            for (int id = t; id < 2048; id += 256) {
                int c = id & 15, oo = id >> 4;
                if (c < csn) wt[nb][c * 132 + oo] = w1[oo * 131 + c0n + c];
            }
        }
        const float* wb = wt[ch & 1];
        const float* ib = ins[ch & 1];
        for (int cc = 0; cc < cs; cc++) {
            float4 wv = *(const float4*)&wb[cc * 132 + o0];
            float wl[4] = {wv.x, wv.y, wv.z, wv.w};
#pragma unroll
            for (int c4 = 0; c4 < 4; c4++) {
                float4 fv = *(const float4*)&ib[cc * 128 + pg * 4 + c4 * 32];
                float fl[4] = {fv.x, fv.y, fv.z, fv.w};
#pragma unroll
                for (int j = 0; j < 4; j++)
#pragma unroll
                    for (int oi = 0; oi < 4; oi++) acc[oi][c4 * 4 + j] += wl[oi] * fl[j];
            }
        }
        __syncthreads();
    }
#pragma unroll
    for (int c4 = 0; c4 < 4; c4++)
#pragma unroll
        for (int j = 0; j < 4; j++) {
            int n = n0 + pg * 4 + c4 * 32 + j;
            float4 v;
            v.x = acc[0][c4 * 4 + j]; v.y = acc[1][c4 * 4 + j];
            v.z = acc[2][c4 * 4 + j]; v.w = acc[3][c4 * 4 + j];
            *(float4*)&a2t[((size_t)b * 512 + n) * 128 + o0] = v;
        }
}

// ---------------------------------------------------------------------------
// SA2 MFMA fused v2: weights read once per BLOCK. Block = 1 query, 256 thr.
// Phase1 (L2 128->128): wave w owns otiles {2w,2w+1}, all 4 jfrags.
// Phase2 (L3 128->256): wave w owns otiles {4w..4w+3} (2 halves), all jfrags.
// LDS ~50KB -> 3 blocks/CU.
// ---------------------------------------------------------------------------
__global__ __launch_bounds__(256) void sa2_mfma_kernel(
    const float* __restrict__ x, const float* __restrict__ a2t,
    const int* __restrict__ idx2, const float* __restrict__ w1,
    const unsigned short* __restrict__ w2f, const float* __restrict__ b2,
    const unsigned short* __restrict__ w3f, const float* __restrict__ b3,
    float* __restrict__ p2) {
    int bp = blockIdx.x;  // 32*128
    int b = bp >> 7, p = bp & 127;
    __shared__ float dsh[128];
    __shared__ int nbr[64];
    __shared__ unsigned short A2buf[16 * 3 * 64 * 8];  // 48KB; first 12KB doubles as BF
    __shared__ float MX[256];
    unsigned short* BF = A2buf;
    const float* xb = x + (size_t)b * 24576;
    int t = threadIdx.x;
    int w = t >> 6, l = t & 63;
    int n16 = l & 15, og = l >> 4;
    if (t < 64) nbr[t] = idx2[((size_t)b * 128 + p) * 64 + t];
    if (t < 128) {
        float qx = xb[p], qy = xb[4096 + p], qz = xb[8192 + p];
        dsh[t] = -(w1[t * 131 + 0] * qx + w1[t * 131 + 1] * qy + w1[t * 131 + 2] * qz);
    }
    __syncthreads();
    // ---- phase 1: L2 (128->128), 4 ksteps; wave owns otiles {2w,2w+1}
    f4v acc1[2][4];
#pragma unroll
    for (int oi = 0; oi < 2; oi++)
#pragma unroll
        for (int jf = 0; jf < 4; jf++) acc1[oi][jf] = (f4v){0.f, 0.f, 0.f, 0.f};
    const float* gsrc = a2t + ((size_t)b * 512 + nbr[w * 16 + n16]) * 128 + og * 8;
    for (int ks = 0; ks < 4; ks++) {
        f4v v0 = *(const f4v*)(gsrc + ks * 32);
        f4v v1 = *(const f4v*)(gsrc + ks * 32 + 4);
        const float* d = &dsh[ks * 32 + og * 8];
        s8v sp0, sp1, sp2;
#pragma unroll
        for (int e = 0; e < 8; e++) {
            float hv = fmaxf(((e < 4) ? v0[e] : v1[e - 4]) + d[e], 0.f);
            unsigned short h0, h1, h2;
            split3(hv, h0, h1, h2);
            sp0[e] = (short)h0; sp1[e] = (short)h1; sp2[e] = (short)h2;
        }
        *(s8v*)&BF[((w * 3 + 0) * 64 + l) * 8] = sp0;
        *(s8v*)&BF[((w * 3 + 1) * 64 + l) * 8] = sp1;
        *(s8v*)&BF[((w * 3 + 2) * 64 + l) * 8] = sp2;
        __syncthreads();
        s8v bfr[4][3];
#pragma unroll
        for (int jf = 0; jf < 4; jf++)
#pragma unroll
            for (int pl = 0; pl < 3; pl++)
                bfr[jf][pl] = *(const s8v*)&BF[((jf * 3 + pl) * 64 + l) * 8];
        const s8v* wr = (const s8v*)w2f + (size_t)(ks * 8) * 3 * 64;
        s8v aw[2][3];
#pragma unroll
        for (int oi = 0; oi < 2; oi++)
#pragma unroll
            for (int pl = 0; pl < 3; pl++)
                aw[oi][pl] = wr[((w * 2 + oi) * 3 + pl) * 64 + l];
        SA2_P1(2, 0) SA2_P1(0, 2) SA2_P1(1, 1)
        SA2_P1(1, 0) SA2_P1(0, 1) SA2_P1(0, 0)
        __syncthreads();
    }
    // ---- handoff: ot = 2w+oi -> ks2 = w
#pragma unroll
    for (int oi = 0; oi < 2; oi++) {
        int ot = w * 2 + oi;
        f4v bv = *(const f4v*)(b2 + ot * 16 + og * 4);
        int l2 = n16 + (oi * 2 + (og >> 1)) * 16;
        int half = og & 1;
#pragma unroll
        for (int jf = 0; jf < 4; jf++) {
            unsigned short hh[3][4];
#pragma unroll
            for (int r = 0; r < 4; r++) {
                float y = fmaxf(acc1[oi][jf][r] + bv[r], 0.f);
                split3(y, hh[0][r], hh[1][r], hh[2][r]);
            }
            int slot = w * 4 + jf;
#pragma unroll
            for (int pl = 0; pl < 3; pl++) {
                unsigned long long pk = (unsigned long long)hh[pl][0] |
                    ((unsigned long long)hh[pl][1] << 16) |
                    ((unsigned long long)hh[pl][2] << 32) |
                    ((unsigned long long)hh[pl][3] << 48);
                *(unsigned long long*)&A2buf[((slot * 3 + pl) * 64 + l2) * 8 + half * 4] = pk;
            }
        }
    }
    __syncthreads();
    // ---- phase 2: L3 (128->256), 4 ksteps; wave owns otiles {4w..4w+3}
#pragma unroll
    for (int half2 = 0; half2 < 2; half2++) {
        f4v acc2[2][4];
#pragma unroll
        for (int oi = 0; oi < 2; oi++)
#pragma unroll
            for (int jf = 0; jf < 4; jf++) acc2[oi][jf] = (f4v){0.f, 0.f, 0.f, 0.f};
        for (int ks2 = 0; ks2 < 4; ks2++) {
            s8v af[4][3];
#pragma unroll
            for (int jf = 0; jf < 4; jf++)
#pragma unroll
                for (int pl = 0; pl < 3; pl++)
                    af[jf][pl] = *(const s8v*)&A2buf[(((ks2 * 4 + jf) * 3 + pl) * 64 + l) * 8];
            const s8v* wr = (const s8v*)w3f + (size_t)(ks2 * 16) * 3 * 64;
            s8v gw[2][3];
#pragma unroll
            for (int oi = 0; oi < 2; oi++)
#pragma unroll
                for (int pl = 0; pl < 3; pl++)
                    gw[oi][pl] = wr[((w * 4 + half2 * 2 + oi) * 3 + pl) * 64 + l];
            MM_P2(2, 0) MM_P2(0, 2) MM_P2(1, 1)
            MM_P2(1, 0) MM_P2(0, 1) MM_P2(0, 0)
        }
#pragma unroll
        for (int oi = 0; oi < 2; oi++) {
            float m = -FLT_BIG;
#pragma unroll
            for (int jf = 0; jf < 4; jf++) {
                float mj = fmaxf(fmaxf(acc2[oi][jf][0], acc2[oi][jf][1]),
                                 fmaxf(acc2[oi][jf][2], acc2[oi][jf][3]));
                m = fmaxf(m, mj);
            }
            m = fmaxf(m, __shfl_xor(m, 16));
            m = fmaxf(m, __shfl_xor(m, 32));
            if (og == 0) MX[(w * 4 + half2 * 2 + oi) * 16 + n16] = m;
        }
    }
    __syncthreads();
    p2[((size_t)b * 256 + t) * 128 + p] = MX[t] + b3[t];
}

// ---------------------------------------------------------------------------
// SA3 batched GEMM over 128 points (unchanged).
// ---------------------------------------------------------------------------
__global__ __launch_bounds__(256) void mlp128_kernel(
    const float* __restrict__ in, const float* __restrict__ W,
    const float* __restrict__ bias, float* __restrict__ out,
    int Cin, int Cout, int relu, int wstride, int woff, int reduce) {
    int bid = blockIdx.x;
    int tiles = Cout >> 6;
    int b = bid / tiles, ot = bid - b * tiles;
    int o0t = ot << 6;
    __shared__ float ins[64 * 128];
    __shared__ float wt[2][16 * 68];
    __shared__ float gmx[64 * 8];
    int t = threadIdx.x;
    int og = t >> 3, pg = t & 7;
    int o = o0t + og * 2;
    float acc[2][16];
    {
        float bb0 = bias[o], bb1 = bias[o + 1];
#pragma unroll
        for (int j = 0; j < 16; j++) { acc[0][j] = bb0; acc[1][j] = bb1; }
    }
    int nslab = Cin >> 6;
    for (int sl = 0; sl < nslab; sl++) {
        __syncthreads();
        for (int id = t; id < 2048; id += 256) {
            int p4 = id & 31, c = id >> 5;
            *(float4*)&ins[c * 128 + p4 * 4] =
                *(const float4*)&in[((size_t)b * Cin + sl * 64 + c) * 128 + p4 * 4];
        }
        for (int id = t; id < 1024; id += 256) {
            int c = id & 15, oo = id >> 4;
            wt[0][c * 68 + oo] = W[(size_t)(o0t + oo) * wstride + woff + sl * 64 + c];
        }
        __syncthreads();
        for (int ch = 0; ch < 4; ch++) {
            if (ch < 3) {
                int nb = (ch + 1) & 1;
                for (int id = t; id < 1024; id += 256) {
                    int c = id & 15, oo = id >> 4;
                    wt[nb][c * 68 + oo] =
                        W[(size_t)(o0t + oo) * wstride + woff + sl * 64 + (ch + 1) * 16 + c];
                }
            }
            const float* wb = wt[ch & 1];
#pragma unroll
            for (int cc = 0; cc < 16; cc++) {
                float2 wv = *(const float2*)&wb[cc * 68 + og * 2];
                const float* f = &ins[(ch * 16 + cc) * 128 + pg * 4];
#pragma unroll
                for (int c4 = 0; c4 < 4; c4++) {
                    float4 fv = *(const float4*)&f[c4 * 32];
                    float fl[4] = {fv.x, fv.y, fv.z, fv.w};
#pragma unroll
                    for (int j = 0; j < 4; j++) {
                        acc[0][c4 * 4 + j] += wv.x * fl[j];
                        acc[1][c4 * 4 + j] += wv.y * fl[j];
                    }
                }
            }
            __syncthreads();
        }
    }
    if (!reduce) {
#pragma unroll
        for (int oi = 0; oi < 2; oi++)
#pragma unroll
            for (int c4 = 0; c4 < 4; c4++) {
                float4 v;
                v.x = acc[oi][c4 * 4 + 0]; v.y = acc[oi][c4 * 4 + 1];
                v.z = acc[oi][c4 * 4 + 2]; v.w = acc[oi][c4 * 4 + 3];
                if (relu) {
                    v.x = fmaxf(v.x, 0.f); v.y = fmaxf(v.y, 0.f);
                    v.z = fmaxf(v.z, 0.f); v.w = fmaxf(v.w, 0.f);
                }
                *(float4*)&out[((size_t)b * Cout + o + oi) * 128 + pg * 4 + c4 * 32] = v;
            }
    } else {
#pragma unroll
        for (int oi = 0; oi < 2; oi++) {
            float mm = acc[oi][0];
#pragma unroll
            for (int j = 1; j < 16; j++) mm = fmaxf(mm, acc[oi][j]);
            gmx[(og * 2 + oi) * 8 + pg] = mm;
        }
        __syncthreads();
        if (t < 64) {
            float mm = gmx[t * 8];
#pragma unroll
            for (int i = 1; i < 8; i++) mm = fmaxf(mm, gmx[t * 8 + i]);
            out[(size_t)b * Cout + o0t + t] = mm;
        }
    }
}

// ---------------------------------------------------------------------------
// Head: FC 1024->512->256->40 (unchanged).
// ---------------------------------------------------------------------------
__global__ __launch_bounds__(256) void head_kernel(
    const float* __restrict__ g,
    const float* __restrict__ fw1, const float* __restrict__ fb1,
    const float* __restrict__ fw2, const float* __restrict__ fb2,
    const float* __restrict__ fw3, const float* __restrict__ fb3,
    float* __restrict__ out) {
    int b = blockIdx.x;
    int t = threadIdx.x;
    __shared__ float gs[1024];
    __shared__ float h1[512];
    __shared__ float h2[256];
    for (int i = t; i < 1024; i += 256) gs[i] = g[(size_t)b * 1024 + i];
    __syncthreads();
    for (int oo = 0; oo < 2; oo++) {
        int o = t + oo * 256;
        float acc = fb1[o];
        const float4* wr = (const float4*)&fw1[(size_t)o * 1024];
        for (int c = 0; c < 256; c++) {
            float4 wv = wr[c];
            acc += wv.x * gs[c * 4] + wv.y * gs[c * 4 + 1] + wv.z * gs[c * 4 + 2] + wv.w * gs[c * 4 + 3];
        }
        h1[o] = fmaxf(acc, 0.f);
    }
    __syncthreads();
    {
        float acc = fb2[t];
        const float4* wr = (const float4*)&fw2[(size_t)t * 512];
        for (int c = 0; c < 128; c++) {
            float4 wv = wr[c];
            acc += wv.x * h1[c * 4] + wv.y * h1[c * 4 + 1] + wv.z * h1[c * 4 + 2] + wv.w * h1[c * 4 + 3];
        }
        h2[t] = fmaxf(acc, 0.f);
    }
    __syncthreads();
    if (t < 40) {
        float acc = fb3[t];
        const float4* wr = (const float4*)&fw3[(size_t)t * 256];
        for (int c = 0; c < 64; c++) {
            float4 wv = wr[c];
            acc += wv.x * h2[c * 4] + wv.y * h2[c * 4 + 1] + wv.z * h2[c * 4 + 2] + wv.w * h2[c * 4 + 3];
        }
        out[b * 40 + t] = acc;
    }
}

extern "C" void kernel_launch(void* const* d_in, const int* in_sizes, int n_in,
                              void* d_out, int out_size, void* d_ws, size_t ws_size,
                              hipStream_t stream) {
    const float* x      = (const float*)d_in[0];
    const float* sa1_w1 = (const float*)d_in[1];
    const float* sa1_b1 = (const float*)d_in[2];
    const float* sa1_w2 = (const float*)d_in[3];
    const float* sa1_b2 = (const float*)d_in[4];
    const float* sa1_w3 = (const float*)d_in[5];
    const float* sa1_b3 = (const float*)d_in[6];
    const float* sa2_w1 = (const float*)d_in[7];
    const float* sa2_b1 = (const float*)d_in[8];
    const float* sa2_w2 = (const float*)d_in[9];
    const float* sa2_b2 = (const float*)d_in[10];
    const float* sa2_w3 = (const float*)d_in[11];
    const float* sa2_b3 = (const float*)d_in[12];
    const float* sa3_w1 = (const float*)d_in[13];
    const float* sa3_b1 = (const float*)d_in[14];
    const float* sa3_w2 = (const float*)d_in[15];
    const float* sa3_b2 = (const float*)d_in[16];
    const float* sa3_w3 = (const float*)d_in[17];
    const float* sa3_b3 = (const float*)d_in[18];
    const float* fc1_w  = (const float*)d_in[19];
    const float* fc1_b  = (const float*)d_in[20];
    const float* fc2_w  = (const float*)d_in[21];
    const float* fc2_b  = (const float*)d_in[22];
    const float* fc3_w  = (const float*)d_in[23];
    const float* fc3_b  = (const float*)d_in[24];

    char* ws = (char*)d_ws;
    const size_t MB = 1048576;
    const size_t KB = 1024;
    // Fragment buffers live in [0, 0.5MB) — nothing else touches this range.
    unsigned short* s1w2f = (unsigned short*)(ws + 0);          //  24 KB
    unsigned short* s1w3f = (unsigned short*)(ws + 32 * KB);    //  48 KB
    unsigned short* s2w2f = (unsigned short*)(ws + 128 * KB);   //  96 KB
    unsigned short* s2w3f = (unsigned short*)(ws + 224 * KB);   // 192 KB (ends 416KB)
    int*   idx1 = (int*)  (ws + 512 * KB);  //  2 MB: (32,512,32)  [0.5..2.5MB)
    float* a1t  = (float*)(ws + 3 * MB);    // 32 MB: (32,4096,64) [3..35MB) dead after sa1_mfma
    float* p1   = (float*)(ws + 35 * MB);   //  8 MB: (32,128,512) [35..43MB)
    int*   idx2 = (int*)  (ws + 3 * MB);    //  1 MB: overlays dead a1t
    float* a2t  = (float*)(ws + 4 * MB);    //  8 MB: overlays dead a1t [4..12MB)
    float* p2   = (float*)(ws + 12 * MB);   //  4 MB: [12..16MB)
    float* h1s  = (float*)(ws + 16 * MB);   //  4 MB: [16..20MB)
    float* h2s  = (float*)(ws + 20 * MB);   //  8 MB: [20..28MB)
    float* g    = (float*)(ws + 28 * MB);   //  128 KB

    // Weight fragment precompute (tiny): grid = (K/32) * (O/16), 64 thr.
    wfrag_kernel<<<2 * 4, 64, 0, stream>>>(sa1_w2, 64, 4, s1w2f);
    wfrag_kernel<<<2 * 8, 64, 0, stream>>>(sa1_w3, 64, 8, s1w3f);
    wfrag_kernel<<<4 * 8, 64, 0, stream>>>(sa2_w2, 128, 8, s2w2f);
    wfrag_kernel<<<4 * 16, 64, 0, stream>>>(sa2_w3, 128, 16, s2w3f);

    knn_select_kernel<<<32 * 512, 256, 0, stream>>>(x, 4096, 32, 512, idx1);
    sa1_pre_kernel<<<32 * 32, 256, 0, stream>>>(x, sa1_w1, sa1_b1, a1t);
    sa1_mfma_kernel<<<32 * 256, 256, 0, stream>>>(x, a1t, idx1, sa1_w1,
                                                  s1w2f, sa1_b2, s1w3f, sa1_b3, p1);
    knn_select_kernel<<<32 * 128, 256, 0, stream>>>(x, 512, 64, 128, idx2);
    sa2_pre_kernel<<<32 * 4, 256, 0, stream>>>(x, p1, sa2_w1, sa2_b1, a2t);
    sa2_mfma_kernel<<<32 * 128, 256, 0, stream>>>(x, a2t, idx2, sa2_w1,
                                                  s2w2f, sa2_b2, s2w3f, sa2_b3, p2);
    mlp128_kernel<<<32 * 4, 256, 0, stream>>>(p2, sa3_w1, sa3_b1, h1s, 256, 256, 1, 259, 3, 0);
    mlp128_kernel<<<32 * 8, 256, 0, stream>>>(h1s, sa3_w2, sa3_b2, h2s, 256, 512, 1, 256, 0, 0);
    mlp128_kernel<<<32 * 16, 256, 0, stream>>>(h2s, sa3_w3, sa3_b3, g, 512, 1024, 0, 512, 0, 1);
    head_kernel<<<32, 256, 0, stream>>>(g, fc1_w, fc1_b, fc2_w, fc2_b, fc3_w, fc3_b,
                                        (float*)d_out);
}

// Round 8
// 599.513 us; speedup vs baseline: 1.5656x; 1.1049x over previous
//
#include <hip/hip_runtime.h>
#include <hip/hip_bf16.h>

#define FLT_BIG 3.0e38f

typedef __attribute__((ext_vector_type(8))) short s8v;
typedef __attribute__((ext_vector_type(4))) float f4v;

// ---------------------------------------------------------------------------
// bf16 3-plane split helpers (RNE). x ~= x0 + x1 + x2 exactly to ~2^-27 rel.
// ---------------------------------------------------------------------------
__device__ inline unsigned short bf_hi(float v, float& res) {
    unsigned int u = __float_as_uint(v);
    unsigned int r = (u + 0x7FFFu + ((u >> 16) & 1u)) >> 16;
    res = v - __uint_as_float(r << 16);
    return (unsigned short)r;
}
__device__ inline void split3(float v, unsigned short& h0, unsigned short& h1,
                              unsigned short& h2) {
    float r1, r2, r3;
    h0 = bf_hi(v, r1);
    h1 = bf_hi(r1, r2);
    h2 = bf_hi(r2, r3);
}

// MFMA plane-combo steps, smallest products first.
#define SA2_P1(AI, BI)                                                          \
    _Pragma("unroll") for (int oi = 0; oi < 2; oi++) {                          \
        _Pragma("unroll") for (int jf = 0; jf < 4; jf++)                        \
            acc1[oi][jf] = __builtin_amdgcn_mfma_f32_16x16x32_bf16(             \
                aw[oi][AI], bfr[jf][BI], acc1[oi][jf], 0, 0, 0);                \
    }
#define SA1_P1(AI, BI)                                                          \
    _Pragma("unroll") for (int jf = 0; jf < 4; jf++)                            \
        acc1[jf] = __builtin_amdgcn_mfma_f32_16x16x32_bf16(                     \
            aw[AI], bfr[jf][BI], acc1[jf], 0, 0, 0);
#define MM_P2(AI, BI)                                                           \
    _Pragma("unroll") for (int oi = 0; oi < 2; oi++) {                          \
        _Pragma("unroll") for (int jf = 0; jf < 4; jf++)                        \
            acc2[oi][jf] = __builtin_amdgcn_mfma_f32_16x16x32_bf16(             \
                af[jf][AI], gw[oi][BI], acc2[oi][jf], 0, 0, 0);                 \
    }

// Monotonic key for d2, pinned FMA order (identical in both kNN passes).
#define MKKEY(QX, QY, QZ, XS)                                                   \
    ({  float dot_ = fmaf((QZ), yz, fmaf((QY), yy, (QX) * yx));                 \
        float d2_ = fmaf(-2.0f, dot_, (XS) + ys);                               \
        unsigned int kk_ = __float_as_uint(d2_);                                \
        (kk_ & 0x80000000u) ? ~kk_ : (kk_ | 0x80000000u); })

// ---------------------------------------------------------------------------
// Weight fragment precompute (unchanged).
// ---------------------------------------------------------------------------
__global__ __launch_bounds__(64) void wfrag_kernel(
    const float* __restrict__ W, int K, int no, unsigned short* __restrict__ out) {
    int bid = blockIdx.x;              // = ks*no + ot
    int l = threadIdx.x;
    int ks = bid / no, ot = bid - ks * no;
    int o = ot * 16 + (l & 15);
    int k0 = ks * 32 + (l >> 4) * 8;
    const float* src = W + (size_t)o * K + k0;
    unsigned short h[3][8];
#pragma unroll
    for (int e = 0; e < 8; e++) split3(src[e], h[0][e], h[1][e], h[2][e]);
#pragma unroll
    for (int p = 0; p < 3; p++) {
        s8v v;
#pragma unroll
        for (int e = 0; e < 8; e++) v[e] = (short)h[p][e];
        *(s8v*)(out + ((size_t)(bid * 3 + p) * 64 + l) * 8) = v;
    }
}

// ---------------------------------------------------------------------------
// kNN v2: 4 queries per block, 2-pass (hist + classify), per-wave scan and
// rank-select. Keys recomputed (pinned-FMA macro) instead of stored.
// Selection = exact top-K set of (key, idx) lexicographic — equivalent to
// jax.lax.top_k on -d2 (downstream max-pool is order-invariant).
// ---------------------------------------------------------------------------
__global__ __launch_bounds__(256) void knn4_kernel(
    const float* __restrict__ x, int N_pts, int K, int P, int* __restrict__ idx_out) {
#define KNN_CAP 192
    int bq = blockIdx.x;
    int pg = P >> 2;
    int b = bq / pg, p0 = (bq - b * pg) * 4;
    const float* xyz = x + (size_t)b * 24576;
    __shared__ unsigned int hist[2][2048];   // packed ushort: pair p holds q=2p (lo), 2p+1 (hi)
    __shared__ unsigned int candK[4][KNN_CAP];
    __shared__ int candI[4][KNN_CAP];
    __shared__ int outIdx[4][64];
    __shared__ unsigned int cnts[4][2];      // [q][0]=below, [q][1]=cand
    __shared__ int sB[4], sM[4];
    __shared__ float qcoord[4][4];           // qx,qy,qz,xs (for fallback)
    int t = threadIdx.x;
    int w = t >> 6, lane = t & 63;
    for (int i = t; i < 4096; i += 256) ((unsigned int*)hist)[i] = 0u;
    if (t < 8) cnts[t >> 1][t & 1] = 0u;
    float qx[4], qy[4], qz[4], xs[4];
#pragma unroll
    for (int q = 0; q < 4; q++) {
        float a = xyz[p0 + q], c1 = xyz[4096 + p0 + q], c2 = xyz[8192 + p0 + q];
        qx[q] = a; qy[q] = c1; qz[q] = c2;
        xs[q] = fmaf(c2, c2, fmaf(c1, c1, a * a));
    }
    if (t < 4) {
        qcoord[t][0] = qx[t]; qcoord[t][1] = qy[t];
        qcoord[t][2] = qz[t]; qcoord[t][3] = xs[t];
    }
    __syncthreads();
    // ---- pass A: histogram
    for (int n = t; n < N_pts; n += 256) {
        float yx = xyz[n], yy = xyz[4096 + n], yz = xyz[8192 + n];
        float ys = fmaf(yz, yz, fmaf(yy, yy, yx * yx));
#pragma unroll
        for (int q = 0; q < 4; q++) {
            unsigned int key = MKKEY(qx[q], qy[q], qz[q], xs[q]);
            atomicAdd(&hist[q >> 1][key >> 21], 1u << ((q & 1) * 16));
        }
    }
    __syncthreads();
    // ---- pass B: per-wave scan; wave w finds boundary bin for query w
    {
        int pair = w >> 1, sh = (w & 1) * 16;
        unsigned int lsum = 0;
        for (int i = 0; i < 32; i++)
            lsum += (hist[pair][lane * 32 + i] >> sh) & 0xFFFFu;
        unsigned int incl = lsum;
        for (int s = 1; s < 64; s <<= 1) {
            unsigned int v = (unsigned int)__shfl_up((int)incl, s);
            if (lane >= s) incl += v;
        }
        unsigned int excl = incl - lsum;
        if (excl < (unsigned)K && excl + lsum >= (unsigned)K) {
            unsigned int cum = excl;
            for (int i = 0; i < 32; i++) {
                unsigned int h = (hist[pair][lane * 32 + i] >> sh) & 0xFFFFu;
                if (cum < (unsigned)K && cum + h >= (unsigned)K) {
                    sB[w] = lane * 32 + i; sM[w] = (int)cum; break;
                }
                cum += h;
            }
        }
    }
    __syncthreads();
    // ---- pass C: classify (recompute keys, identical MKKEY)
    for (int n = t; n < N_pts; n += 256) {
        float yx = xyz[n], yy = xyz[4096 + n], yz = xyz[8192 + n];
        float ys = fmaf(yz, yz, fmaf(yy, yy, yx * yx));
#pragma unroll
        for (int q = 0; q < 4; q++) {
            unsigned int key = MKKEY(qx[q], qy[q], qz[q], xs[q]);
            int bin = (int)(key >> 21);
            int Bq = sB[q];
            if (bin < Bq) {
                outIdx[q][atomicAdd(&cnts[q][0], 1u)] = n;
            } else if (bin == Bq) {
                unsigned int ci = atomicAdd(&cnts[q][1], 1u);
                if (ci < KNN_CAP) { candK[q][ci] = key; candI[q][ci] = n; }
            }
        }
    }
    __syncthreads();
    // ---- pass D: per-wave rank-select for query w
    {
        int nc = (int)cnts[w][1];
        int m = sM[w], r = K - m, Bw = sB[w];
        if (nc <= KNN_CAP) {
            for (int ci = lane; ci < nc; ci += 64) {
                unsigned int ki = candK[w][ci];
                int ii = candI[w][ci];
                int rank = 0;
                for (int j = 0; j < nc; j++) {
                    unsigned int kj = candK[w][j];
                    rank += (kj < ki || (kj == ki && candI[w][j] < ii)) ? 1 : 0;
                }
                if (rank < r) outIdx[w][m + rank] = ii;
            }
        } else {
            // fallback (never hit for benign data): successive wave-argmin
            float fqx = qcoord[w][0], fqy = qcoord[w][1];
            float fqz = qcoord[w][2], fxs = qcoord[w][3];
            unsigned int lastK = 0u; int lastI = -1;
            for (int rr = 0; rr < r; rr++) {
                unsigned int bk = 0xFFFFFFFFu; int bi = 0x7fffffff;
                for (int n = lane; n < N_pts; n += 64) {
                    float yx = xyz[n], yy = xyz[4096 + n], yz = xyz[8192 + n];
                    float ys = fmaf(yz, yz, fmaf(yy, yy, yx * yx));
                    unsigned int key = MKKEY(fqx, fqy, fqz, fxs);
                    if ((int)(key >> 21) == Bw) {
                        bool gt = (key > lastK) || (key == lastK && n > lastI);
                        if (gt && (key < bk || (key == bk && n < bi))) { bk = key; bi = n; }
                    }
                }
#pragma unroll
                for (int s = 32; s > 0; s >>= 1) {
                    unsigned int ok = (unsigned int)__shfl_xor((int)bk, s);
                    int oi = __shfl_xor(bi, s);
                    if (ok < bk || (ok == bk && oi < bi)) { bk = ok; bi = oi; }
                }
                if (lane == 0) outIdx[w][m + rr] = bi;
                lastK = bk; lastI = bi;
            }
        }
    }
    __syncthreads();
    if (t < 4 * K) {
        int q = t / K, k = t - q * K;
        idx_out[((size_t)(b * P) + p0 + q) * K + k] = outIdx[q][k];
    }
}

// ---------------------------------------------------------------------------
// SA1 precompute (unchanged).
// ---------------------------------------------------------------------------
__global__ __launch_bounds__(256) void sa1_pre_kernel(
    const float* __restrict__ x, const float* __restrict__ w1, const float* __restrict__ b1,
    float* __restrict__ a1t) {
    int bid = blockIdx.x;
    int b = bid >> 5, nt = bid & 31, n0 = nt << 7;
    __shared__ float xsh[6 * 128];
    __shared__ float wt[6 * 68];
    const float* xb = x + (size_t)b * 24576;
    int t = threadIdx.x;
    for (int id = t; id < 768; id += 256) {
        int c = id >> 7, n = id & 127;
        xsh[c * 128 + n] = xb[c * 4096 + n0 + n];
    }
    for (int id = t; id < 384; id += 256) {
        int c = id >> 6, o = id & 63;
        wt[c * 68 + o] = w1[o * 6 + c];
    }
    __syncthreads();
    int o = t & 63, ng = t >> 6;
    float acc[32];
    float bias = b1[o];
#pragma unroll
    for (int j = 0; j < 32; j++) acc[j] = bias;
    for (int c = 0; c < 6; c++) {
        float w = wt[c * 68 + o];
        const float* f = &xsh[c * 128 + ng * 32];
#pragma unroll
        for (int j = 0; j < 32; j++) acc[j] += w * f[j];
    }
#pragma unroll
    for (int j = 0; j < 32; j++)
        a1t[((size_t)b * 4096 + n0 + ng * 32 + j) * 64 + o] = acc[j];
}

// ---------------------------------------------------------------------------
// SA1 MFMA fused v2 (unchanged from round 7).
// ---------------------------------------------------------------------------
__global__ __launch_bounds__(256) void sa1_mfma_kernel(
    const float* __restrict__ x, const float* __restrict__ a1t,
    const int* __restrict__ idx1, const float* __restrict__ w1,
    const unsigned short* __restrict__ w2f, const float* __restrict__ b2,
    const unsigned short* __restrict__ w3f, const float* __restrict__ b3,
    float* __restrict__ p1) {
    int bp = blockIdx.x;  // 32*256
    int b = bp >> 8, pp = bp & 255, p0 = pp * 2;
    __shared__ float dshq[2][64];
    __shared__ int nbr[64];
    __shared__ unsigned short A1buf[8 * 3 * 64 * 8];  // 24KB; first 12KB doubles as BF
    __shared__ float MX[2][128];
    unsigned short* BF = A1buf;
    const float* xb = x + (size_t)b * 24576;
    int t = threadIdx.x;
    int w = t >> 6, l = t & 63;
    int n16 = l & 15, og = l >> 4;
    if (t < 64) nbr[t] = idx1[((size_t)b * 512 + p0) * 32 + t];
    if (t < 128) {
        int qi = t >> 6, c = t & 63;
        float qx = xb[p0 + qi], qy = xb[4096 + p0 + qi], qz = xb[8192 + p0 + qi];
        dshq[qi][c] = -(w1[c * 6 + 0] * qx + w1[c * 6 + 1] * qy + w1[c * 6 + 2] * qz);
    }
    __syncthreads();
    int q = w >> 1;
    f4v acc1[4];
#pragma unroll
    for (int jf = 0; jf < 4; jf++) acc1[jf] = (f4v){0.f, 0.f, 0.f, 0.f};
    const float* gsrc = a1t + ((size_t)b * 4096 + nbr[w * 16 + n16]) * 64 + og * 8;
    for (int ks = 0; ks < 2; ks++) {
        f4v v0 = *(const f4v*)(gsrc + ks * 32);
        f4v v1 = *(const f4v*)(gsrc + ks * 32 + 4);
        const float* d = &dshq[q][ks * 32 + og * 8];
        s8v sp0, sp1, sp2;
#pragma unroll
        for (int e = 0; e < 8; e++) {
            float hv = fmaxf(((e < 4) ? v0[e] : v1[e - 4]) + d[e], 0.f);
            unsigned short h0, h1, h2;
            split3(hv, h0, h1, h2);
            sp0[e] = (short)h0; sp1[e] = (short)h1; sp2[e] = (short)h2;
        }
        *(s8v*)&BF[((w * 3 + 0) * 64 + l) * 8] = sp0;
        *(s8v*)&BF[((w * 3 + 1) * 64 + l) * 8] = sp1;
        *(s8v*)&BF[((w * 3 + 2) * 64 + l) * 8] = sp2;
        __syncthreads();
        s8v bfr[4][3];
#pragma unroll
        for (int jf = 0; jf < 4; jf++)
#pragma unroll
            for (int pl = 0; pl < 3; pl++)
                bfr[jf][pl] = *(const s8v*)&BF[((jf * 3 + pl) * 64 + l) * 8];
        const s8v* wr = (const s8v*)w2f + (size_t)(ks * 4) * 3 * 64;
        s8v aw[3];
#pragma unroll
        for (int pl = 0; pl < 3; pl++) aw[pl] = wr[(w * 3 + pl) * 64 + l];
        SA1_P1(2, 0) SA1_P1(0, 2) SA1_P1(1, 1)
        SA1_P1(1, 0) SA1_P1(0, 1) SA1_P1(0, 0)
        __syncthreads();
    }
    {
        f4v bv = *(const f4v*)(b2 + w * 16 + og * 4);
        int l2 = n16 + ((w & 1) * 2 + (og >> 1)) * 16;
        int half = og & 1;
#pragma unroll
        for (int jf = 0; jf < 4; jf++) {
            unsigned short hh[3][4];
#pragma unroll
            for (int r = 0; r < 4; r++) {
                float y = fmaxf(acc1[jf][r] + bv[r], 0.f);
                split3(y, hh[0][r], hh[1][r], hh[2][r]);
            }
            int slot = (w >> 1) * 4 + jf;
#pragma unroll
            for (int pl = 0; pl < 3; pl++) {
                unsigned long long pk = (unsigned long long)hh[pl][0] |
                    ((unsigned long long)hh[pl][1] << 16) |
                    ((unsigned long long)hh[pl][2] << 32) |
                    ((unsigned long long)hh[pl][3] << 48);
                *(unsigned long long*)&A1buf[((slot * 3 + pl) * 64 + l2) * 8 + half * 4] = pk;
            }
        }
    }
    __syncthreads();
    f4v acc2[2][4];
#pragma unroll
    for (int oi = 0; oi < 2; oi++)
#pragma unroll
        for (int jf = 0; jf < 4; jf++) acc2[oi][jf] = (f4v){0.f, 0.f, 0.f, 0.f};
    for (int ks2 = 0; ks2 < 2; ks2++) {
        s8v af[4][3];
#pragma unroll
        for (int jf = 0; jf < 4; jf++)
#pragma unroll
            for (int pl = 0; pl < 3; pl++)
                af[jf][pl] = *(const s8v*)&A1buf[(((ks2 * 4 + jf) * 3 + pl) * 64 + l) * 8];
        const s8v* wr = (const s8v*)w3f + (size_t)(ks2 * 8) * 3 * 64;
        s8v gw[2][3];
#pragma unroll
        for (int oi = 0; oi < 2; oi++)
#pragma unroll
            for (int pl = 0; pl < 3; pl++)
                gw[oi][pl] = wr[((w * 2 + oi) * 3 + pl) * 64 + l];
        MM_P2(2, 0) MM_P2(0, 2) MM_P2(1, 1)
        MM_P2(1, 0) MM_P2(0, 1) MM_P2(0, 0)
    }
#pragma unroll
    for (int oi = 0; oi < 2; oi++) {
        float m0 = fmaxf(fmaxf(acc2[oi][0][0], acc2[oi][0][1]),
                         fmaxf(acc2[oi][0][2], acc2[oi][0][3]));
        m0 = fmaxf(m0, fmaxf(fmaxf(acc2[oi][1][0], acc2[oi][1][1]),
                             fmaxf(acc2[oi][1][2], acc2[oi][1][3])));
        float m1 = fmaxf(fmaxf(acc2[oi][2][0], acc2[oi][2][1]),
                         fmaxf(acc2[oi][2][2], acc2[oi][2][3]));
        m1 = fmaxf(m1, fmaxf(fmaxf(acc2[oi][3][0], acc2[oi][3][1]),
                             fmaxf(acc2[oi][3][2], acc2[oi][3][3])));
        m0 = fmaxf(m0, __shfl_xor(m0, 16));
        m0 = fmaxf(m0, __shfl_xor(m0, 32));
        m1 = fmaxf(m1, __shfl_xor(m1, 16));
        m1 = fmaxf(m1, __shfl_xor(m1, 32));
        if (og == 0) {
            MX[0][(w * 2 + oi) * 16 + n16] = m0;
            MX[1][(w * 2 + oi) * 16 + n16] = m1;
        }
    }
    __syncthreads();
    {
        int o = t & 127, qq = t >> 7;
        p1[((size_t)b * 128 + o) * 512 + p0 + qq] = MX[qq][o] + b3[o];
    }
}

// ---------------------------------------------------------------------------
// SA2 precompute (unchanged).
// ---------------------------------------------------------------------------
__global__ __launch_bounds__(256) void sa2_pre_kernel(
    const float* __restrict__ x, const float* __restrict__ p1,
    const float* __restrict__ w1, const float* __restrict__ b1,
    float* __restrict__ a2t) {
    int bid = blockIdx.x;
    int b = bid >> 2, nt = bid & 3, n0 = nt << 7;
    __shared__ float ins[2][16 * 128];
    __shared__ float wt[2][16 * 132];
    const float* xb = x + (size_t)b * 24576;
    const float* p1b = p1 + (size_t)b * 65536;
    int t = threadIdx.x;
    int og = t >> 3, pg = t & 7;
    int o0 = og * 4;
    float acc[4][16];
    {
        float bl[4] = {b1[o0], b1[o0 + 1], b1[o0 + 2], b1[o0 + 3]};
#pragma unroll
        for (int oi = 0; oi < 4; oi++)
#pragma unroll
            for (int j = 0; j < 16; j++) acc[oi][j] = bl[oi];
    }
    for (int id = t; id < 16 * 128; id += 256) {
        int n = id & 127, c = id >> 7;
        ins[0][c * 128 + n] = (c < 3) ? xb[c * 4096 + n0 + n]
                                      : p1b[(size_t)(c - 3) * 512 + n0 + n];
    }
    for (int id = t; id < 2048; id += 256) {
        int c = id & 15, oo = id >> 4;
        wt[0][c * 132 + oo] = w1[oo * 131 + c];
    }
    __syncthreads();
    for (int ch = 0; ch < 9; ch++) {
        int cs = (ch == 8) ? 3 : 16;
        if (ch < 8) {
            int c0n = (ch + 1) * 16;
            int csn = (ch == 7) ? 3 : 16;
            int nb = (ch + 1) & 1;
            for (int id = t; id < csn * 128; id += 256) {
                int n = id & 127, c = id >> 7;
                int cg = c0n + c;
                ins[nb][c * 128 + n] = (cg < 3) ? xb[cg * 4096 + n0 + n]
                                                : p1b[(size_t)(cg - 3) * 512 + n0 + n];
            }
            for (int id = t; id < 2048; id += 256) {
                int c = id & 15, oo = id >> 4;
                if (c < csn) wt[nb][c * 132 + oo] = w1[oo * 131 + c0n + c];
            }
        }
        const float* wb = wt[ch & 1];
        const float* ib = ins[ch & 1];
        for (int cc = 0; cc < cs; cc++) {
            float4 wv = *(const float4*)&wb[cc * 132 + o0];
            float wl[4] = {wv.x, wv.y, wv.z, wv.w};
#pragma unroll
            for (int c4 = 0; c4 < 4; c4++) {
                float4 fv = *(const float4*)&ib[cc * 128 + pg * 4 + c4 * 32];
                float fl[4] = {fv.x, fv.y, fv.z, fv.w};
#pragma unroll
                for (int j = 0; j < 4; j++)
#pragma unroll
                    for (int oi = 0; oi < 4; oi++) acc[oi][c4 * 4 + j] += wl[oi] * fl[j];
            }
        }
        __syncthreads();
    }
#pragma unroll
    for (int c4 = 0; c4 < 4; c4++)
#pragma unroll
        for (int j = 0; j < 4; j++) {
            int n = n0 + pg * 4 + c4 * 32 + j;
            float4 v;
            v.x = acc[0][c4 * 4 + j]; v.y = acc[1][c4 * 4 + j];
            v.z = acc[2][c4 * 4 + j]; v.w = acc[3][c4 * 4 + j];
            *(float4*)&a2t[((size_t)b * 512 + n) * 128 + o0] = v;
        }
}

// ---------------------------------------------------------------------------
// SA2 MFMA fused v2 (unchanged from round 7).
// ---------------------------------------------------------------------------
__global__ __launch_bounds__(256) void sa2_mfma_kernel(
    const float* __restrict__ x, const float* __restrict__ a2t,
    const int* __restrict__ idx2, const float* __restrict__ w1,
    const unsigned short* __restrict__ w2f, const float* __restrict__ b2,
    const unsigned short* __restrict__ w3f, const float* __restrict__ b3,
    float* __restrict__ p2) {
    int bp = blockIdx.x;  // 32*128
    int b = bp >> 7, p = bp & 127;
    __shared__ float dsh[128];
    __shared__ int nbr[64];
    __shared__ unsigned short A2buf[16 * 3 * 64 * 8];  // 48KB; first 12KB doubles as BF
    __shared__ float MX[256];
    unsigned short* BF = A2buf;
    const float* xb = x + (size_t)b * 24576;
    int t = threadIdx.x;
    int w = t >> 6, l = t & 63;
    int n16 = l & 15, og = l >> 4;
    if (t < 64) nbr[t] = idx2[((size_t)b * 128 + p) * 64 + t];
    if (t < 128) {
        float qx = xb[p], qy = xb[4096 + p], qz = xb[8192 + p];
        dsh[t] = -(w1[t * 131 + 0] * qx + w1[t * 131 + 1] * qy + w1[t * 131 + 2] * qz);
    }
    __syncthreads();
    f4v acc1[2][4];
#pragma unroll
    for (int oi = 0; oi < 2; oi++)
#pragma unroll
        for (int jf = 0; jf < 4; jf++) acc1[oi][jf] = (f4v){0.f, 0.f, 0.f, 0.f};
    const float* gsrc = a2t + ((size_t)b * 512 + nbr[w * 16 + n16]) * 128 + og * 8;
    for (int ks = 0; ks < 4; ks++) {
        f4v v0 = *(const f4v*)(gsrc + ks * 32);
        f4v v1 = *(const f4v*)(gsrc + ks * 32 + 4);
        const float* d = &dsh[ks * 32 + og * 8];
        s8v sp0, sp1, sp2;
#pragma unroll
        for (int e = 0; e < 8; e++) {
            float hv = fmaxf(((e < 4) ? v0[e] : v1[e - 4]) + d[e], 0.f);
            unsigned short h0, h1, h2;
            split3(hv, h0, h1, h2);
            sp0[e] = (short)h0; sp1[e] = (short)h1; sp2[e] = (short)h2;
        }
        *(s8v*)&BF[((w * 3 + 0) * 64 + l) * 8] = sp0;
        *(s8v*)&BF[((w * 3 + 1) * 64 + l) * 8] = sp1;
        *(s8v*)&BF[((w * 3 + 2) * 64 + l) * 8] = sp2;
        __syncthreads();
        s8v bfr[4][3];
#pragma unroll
        for (int jf = 0; jf < 4; jf++)
#pragma unroll
            for (int pl = 0; pl < 3; pl++)
                bfr[jf][pl] = *(const s8v*)&BF[((jf * 3 + pl) * 64 + l) * 8];
        const s8v* wr = (const s8v*)w2f + (size_t)(ks * 8) * 3 * 64;
        s8v aw[2][3];
#pragma unroll
        for (int oi = 0; oi < 2; oi++)
#pragma unroll
            for (int pl = 0; pl < 3; pl++)
                aw[oi][pl] = wr[((w * 2 + oi) * 3 + pl) * 64 + l];
        SA2_P1(2, 0) SA2_P1(0, 2) SA2_P1(1, 1)
        SA2_P1(1, 0) SA2_P1(0, 1) SA2_P1(0, 0)
        __syncthreads();
    }
#pragma unroll
    for (int oi = 0; oi < 2; oi++) {
        int ot = w * 2 + oi;
        f4v bv = *(const f4v*)(b2 + ot * 16 + og * 4);
        int l2 = n16 + (oi * 2 + (og >> 1)) * 16;
        int half = og & 1;
#pragma unroll
        for (int jf = 0; jf < 4; jf++) {
            unsigned short hh[3][4];
#pragma unroll
            for (int r = 0; r < 4; r++) {
                float y = fmaxf(acc1[oi][jf][r] + bv[r], 0.f);
                split3(y, hh[0][r], hh[1][r], hh[2][r]);
            }
            int slot = w * 4 + jf;
#pragma unroll
            for (int pl = 0; pl < 3; pl++) {
                unsigned long long pk = (unsigned long long)hh[pl][0] |
                    ((unsigned long long)hh[pl][1] << 16) |
                    ((unsigned long long)hh[pl][2] << 32) |
                    ((unsigned long long)hh[pl][3] << 48);
                *(unsigned long long*)&A2buf[((slot * 3 + pl) * 64 + l2) * 8 + half * 4] = pk;
            }
        }
    }
    __syncthreads();
#pragma unroll
    for (int half2 = 0; half2 < 2; half2++) {
        f4v acc2[2][4];
#pragma unroll
        for (int oi = 0; oi < 2; oi++)
#pragma unroll
            for (int jf = 0; jf < 4; jf++) acc2[oi][jf] = (f4v){0.f, 0.f, 0.f, 0.f};
        for (int ks2 = 0; ks2 < 4; ks2++) {
            s8v af[4][3];
#pragma unroll
            for (int jf = 0; jf < 4; jf++)
#pragma unroll
                for (int pl = 0; pl < 3; pl++)
                    af[jf][pl] = *(const s8v*)&A2buf[(((ks2 * 4 + jf) * 3 + pl) * 64 + l) * 8];
            const s8v* wr = (const s8v*)w3f + (size_t)(ks2 * 16) * 3 * 64;
            s8v gw[2][3];
#pragma unroll
            for (int oi = 0; oi < 2; oi++)
#pragma unroll
                for (int pl = 0; pl < 3; pl++)
                    gw[oi][pl] = wr[((w * 4 + half2 * 2 + oi) * 3 + pl) * 64 + l];
            MM_P2(2, 0) MM_P2(0, 2) MM_P2(1, 1)
            MM_P2(1, 0) MM_P2(0, 1) MM_P2(0, 0)
        }
#pragma unroll
        for (int oi = 0; oi < 2; oi++) {
            float m = -FLT_BIG;
#pragma unroll
            for (int jf = 0; jf < 4; jf++) {
                float mj = fmaxf(fmaxf(acc2[oi][jf][0], acc2[oi][jf][1]),
                                 fmaxf(acc2[oi][jf][2], acc2[oi][jf][3]));
                m = fmaxf(m, mj);
            }
            m = fmaxf(m, __shfl_xor(m, 16));
            m = fmaxf(m, __shfl_xor(m, 32));
            if (og == 0) MX[(w * 4 + half2 * 2 + oi) * 16 + n16] = m;
        }
    }
    __syncthreads();
    p2[((size_t)b * 256 + t) * 128 + p] = MX[t] + b3[t];
}

// ---------------------------------------------------------------------------
// SA3 batched GEMM over 128 points (unchanged).
// ---------------------------------------------------------------------------
__global__ __launch_bounds__(256) void mlp128_kernel(
    const float* __restrict__ in, const float* __restrict__ W,
    const float* __restrict__ bias, float* __restrict__ out,
    int Cin, int Cout, int relu, int wstride, int woff, int reduce) {
    int bid = blockIdx.x;
    int tiles = Cout >> 6;
    int b = bid / tiles, ot = bid - b * tiles;
    int o0t = ot << 6;
    __shared__ float ins[64 * 128];
    __shared__ float wt[2][16 * 68];
    __shared__ float gmx[64 * 8];
    int t = threadIdx.x;
    int og = t >> 3, pg = t & 7;
    int o = o0t + og * 2;
    float acc[2][16];
    {
        float bb0 = bias[o], bb1 = bias[o + 1];
#pragma unroll
        for (int j = 0; j < 16; j++) { acc[0][j] = bb0; acc[1][j] = bb1; }
    }
    int nslab = Cin >> 6;
    for (int sl = 0; sl < nslab; sl++) {
        __syncthreads();
        for (int id = t; id < 2048; id += 256) {
            int p4 = id & 31, c = id >> 5;
            *(float4*)&ins[c * 128 + p4 * 4] =
                *(const float4*)&in[((size_t)b * Cin + sl * 64 + c) * 128 + p4 * 4];
        }
        for (int id = t; id < 1024; id += 256) {
            int c = id & 15, oo = id >> 4;
            wt[0][c * 68 + oo] = W[(size_t)(o0t + oo) * wstride + woff + sl * 64 + c];
        }
        __syncthreads();
        for (int ch = 0; ch < 4; ch++) {
            if (ch < 3) {
                int nb = (ch + 1) & 1;
                for (int id = t; id < 1024; id += 256) {
                    int c = id & 15, oo = id >> 4;
                    wt[nb][c * 68 + oo] =
                        W[(size_t)(o0t + oo) * wstride + woff + sl * 64 + (ch + 1) * 16 + c];
                }
            }
            const float* wb = wt[ch & 1];
#pragma unroll
            for (int cc = 0; cc < 16; cc++) {
                float2 wv = *(const float2*)&wb[cc * 68 + og * 2];
                const float* f = &ins[(ch * 16 + cc) * 128 + pg * 4];
#pragma unroll
                for (int c4 = 0; c4 < 4; c4++) {
                    float4 fv = *(const float4*)&f[c4 * 32];
                    float fl[4] = {fv.x, fv.y, fv.z, fv.w};
#pragma unroll
                    for (int j = 0; j < 4; j++) {
                        acc[0][c4 * 4 + j] += wv.x * fl[j];
                        acc[1][c4 * 4 + j] += wv.y * fl[j];
                    }
                }
            }
            __syncthreads();
        }
    }
    if (!reduce) {
#pragma unroll
        for (int oi = 0; oi < 2; oi++)
#pragma unroll
            for (int c4 = 0; c4 < 4; c4++) {
                float4 v;
                v.x = acc[oi][c4 * 4 + 0]; v.y = acc[oi][c4 * 4 + 1];
                v.z = acc[oi][c4 * 4 + 2]; v.w = acc[oi][c4 * 4 + 3];
                if (relu) {
                    v.x = fmaxf(v.x, 0.f); v.y = fmaxf(v.y, 0.f);
                    v.z = fmaxf(v.z, 0.f); v.w = fmaxf(v.w, 0.f);
                }
                *(float4*)&out[((size_t)b * Cout + o + oi) * 128 + pg * 4 + c4 * 32] = v;
            }
    } else {
#pragma unroll
        for (int oi = 0; oi < 2; oi++) {
            float mm = acc[oi][0];
#pragma unroll
            for (int j = 1; j < 16; j++) mm = fmaxf(mm, acc[oi][j]);
            gmx[(og * 2 + oi) * 8 + pg] = mm;
        }
        __syncthreads();
        if (t < 64) {
            float mm = gmx[t * 8];
#pragma unroll
            for (int i = 1; i < 8; i++) mm = fmaxf(mm, gmx[t * 8 + i]);
            out[(size_t)b * Cout + o0t + t] = mm;
        }
    }
}

// ---------------------------------------------------------------------------
// Head: FC 1024->512->256->40 (unchanged).
// ---------------------------------------------------------------------------
__global__ __launch_bounds__(256) void head_kernel(
    const float* __restrict__ g,
    const float* __restrict__ fw1, const float* __restrict__ fb1,
    const float* __restrict__ fw2, const float* __restrict__ fb2,
    const float* __restrict__ fw3, const float* __restrict__ fb3,
    float* __restrict__ out) {
    int b = blockIdx.x;
    int t = threadIdx.x;
    __shared__ float gs[1024];
    __shared__ float h1[512];
    __shared__ float h2[256];
    for (int i = t; i < 1024; i += 256) gs[i] = g[(size_t)b * 1024 + i];
    __syncthreads();
    for (int oo = 0; oo < 2; oo++) {
        int o = t + oo * 256;
        float acc = fb1[o];
        const float4* wr = (const float4*)&fw1[(size_t)o * 1024];
        for (int c = 0; c < 256; c++) {
            float4 wv = wr[c];
            acc += wv.x * gs[c * 4] + wv.y * gs[c * 4 + 1] + wv.z * gs[c * 4 + 2] + wv.w * gs[c * 4 + 3];
        }
        h1[o] = fmaxf(acc, 0.f);
    }
    __syncthreads();
    {
        float acc = fb2[t];
        const float4* wr = (const float4*)&fw2[(size_t)t * 512];
        for (int c = 0; c < 128; c++) {
            float4 wv = wr[c];
            acc += wv.x * h1[c * 4] + wv.y * h1[c * 4 + 1] + wv.z * h1[c * 4 + 2] + wv.w * h1[c * 4 + 3];
        }
        h2[t] = fmaxf(acc, 0.f);
    }
    __syncthreads();
    if (t < 40) {
        float acc = fb3[t];
        const float4* wr = (const float4*)&fw3[(size_t)t * 256];
        for (int c = 0; c < 64; c++) {
            float4 wv = wr[c];
            acc += wv.x * h2[c * 4] + wv.y * h2[c * 4 + 1] + wv.z * h2[c * 4 + 2] + wv.w * h2[c * 4 + 3];
        }
        out[b * 40 + t] = acc;
    }
}

extern "C" void kernel_launch(void* const* d_in, const int* in_sizes, int n_in,
                              void* d_out, int out_size, void* d_ws, size_t ws_size,
                              hipStream_t stream) {
    const float* x      = (const float*)d_in[0];
    const float* sa1_w1 = (const float*)d_in[1];
    const float* sa1_b1 = (const float*)d_in[2];
    const float* sa1_w2 = (const float*)d_in[3];
    const float* sa1_b2 = (const float*)d_in[4];
    const float* sa1_w3 = (const float*)d_in[5];
    const float* sa1_b3 = (const float*)d_in[6];
    const float* sa2_w1 = (const float*)d_in[7];
    const float* sa2_b1 = (const float*)d_in[8];
    const float* sa2_w2 = (const float*)d_in[9];
    const float* sa2_b2 = (const float*)d_in[10];
    const float* sa2_w3 = (const float*)d_in[11];
    const float* sa2_b3 = (const float*)d_in[12];
    const float* sa3_w1 = (const float*)d_in[13];
    const float* sa3_b1 = (const float*)d_in[14];
    const float* sa3_w2 = (const float*)d_in[15];
    const float* sa3_b2 = (const float*)d_in[16];
    const float* sa3_w3 = (const float*)d_in[17];
    const float* sa3_b3 = (const float*)d_in[18];
    const float* fc1_w  = (const float*)d_in[19];
    const float* fc1_b  = (const float*)d_in[20];
    const float* fc2_w  = (const float*)d_in[21];
    const float* fc2_b  = (const float*)d_in[22];
    const float* fc3_w  = (const float*)d_in[23];
    const float* fc3_b  = (const float*)d_in[24];

    char* ws = (char*)d_ws;
    const size_t MB = 1048576;
    const size_t KB = 1024;
    // Fragment buffers live in [0, 0.5MB) — nothing else touches this range.
    unsigned short* s1w2f = (unsigned short*)(ws + 0);          //  24 KB
    unsigned short* s1w3f = (unsigned short*)(ws + 32 * KB);    //  48 KB
    unsigned short* s2w2f = (unsigned short*)(ws + 128 * KB);   //  96 KB
    unsigned short* s2w3f = (unsigned short*)(ws + 224 * KB);   // 192 KB (ends 416KB)
    int*   idx1 = (int*)  (ws + 512 * KB);  //  2 MB: (32,512,32)  [0.5..2.5MB)
    float* a1t  = (float*)(ws + 3 * MB);    // 32 MB: (32,4096,64) [3..35MB) dead after sa1_mfma
    float* p1   = (float*)(ws + 35 * MB);   //  8 MB: (32,128,512) [35..43MB)
    int*   idx2 = (int*)  (ws + 3 * MB);    //  1 MB: overlays dead a1t
    float* a2t  = (float*)(ws + 4 * MB);    //  8 MB: overlays dead a1t [4..12MB)
    float* p2   = (float*)(ws + 12 * MB);   //  4 MB: [12..16MB)
    float* h1s  = (float*)(ws + 16 * MB);   //  4 MB: [16..20MB)
    float* h2s  = (float*)(ws + 20 * MB);   //  8 MB: [20..28MB)
    float* g    = (float*)(ws + 28 * MB);   //  128 KB

    // Weight fragment precompute (tiny): grid = (K/32) * (O/16), 64 thr.
    wfrag_kernel<<<2 * 4, 64, 0, stream>>>(sa1_w2, 64, 4, s1w2f);
    wfrag_kernel<<<2 * 8, 64, 0, stream>>>(sa1_w3, 64, 8, s1w3f);
    wfrag_kernel<<<4 * 8, 64, 0, stream>>>(sa2_w2, 128, 8, s2w2f);
    wfrag_kernel<<<4 * 16, 64, 0, stream>>>(sa2_w3, 128, 16, s2w3f);

    knn4_kernel<<<32 * 128, 256, 0, stream>>>(x, 4096, 32, 512, idx1);
    sa1_pre_kernel<<<32 * 32, 256, 0, stream>>>(x, sa1_w1, sa1_b1, a1t);
    sa1_mfma_kernel<<<32 * 256, 256, 0, stream>>>(x, a1t, idx1, sa1_w1,
                                                  s1w2f, sa1_b2, s1w3f, sa1_b3, p1);
    knn4_kernel<<<32 * 32, 256, 0, stream>>>(x, 512, 64, 128, idx2);
    sa2_pre_kernel<<<32 * 4, 256, 0, stream>>>(x, p1, sa2_w1, sa2_b1, a2t);
    sa2_mfma_kernel<<<32 * 128, 256, 0, stream>>>(x, a2t, idx2, sa2_w1,
                                                  s2w2f, sa2_b2, s2w3f, sa2_b3, p2);
    mlp128_kernel<<<32 * 4, 256, 0, stream>>>(p2, sa3_w1, sa3_b1, h1s, 256, 256, 1, 259, 3, 0);
    mlp128_kernel<<<32 * 8, 256, 0, stream>>>(h1s, sa3_w2, sa3_b2, h2s, 256, 512, 1, 256, 0, 0);
    mlp128_kernel<<<32 * 16, 256, 0, stream>>>(h2s, sa3_w3, sa3_b3, g, 512, 1024, 0, 512, 0, 1);
    head_kernel<<<32, 256, 0, stream>>>(g, fc1_w, fc1_b, fc2_w, fc2_b, fc3_w, fc3_b,
                                        (float*)d_out);
}

// Round 9
// 519.019 us; speedup vs baseline: 1.8084x; 1.1551x over previous
//
#include <hip/hip_runtime.h>
#include <hip/hip_bf16.h>

#define FLT_BIG 3.0e38f

typedef __attribute__((ext_vector_type(8))) short s8v;
typedef __attribute__((ext_vector_type(4))) float f4v;

// ---------------------------------------------------------------------------
// bf16 3-plane split helpers (RNE). x ~= x0 + x1 + x2 exactly to ~2^-27 rel.
// ---------------------------------------------------------------------------
__device__ inline unsigned short bf_hi(float v, float& res) {
    unsigned int u = __float_as_uint(v);
    unsigned int r = (u + 0x7FFFu + ((u >> 16) & 1u)) >> 16;
    res = v - __uint_as_float(r << 16);
    return (unsigned short)r;
}
__device__ inline void split3(float v, unsigned short& h0, unsigned short& h1,
                              unsigned short& h2) {
    float r1, r2, r3;
    h0 = bf_hi(v, r1);
    h1 = bf_hi(r1, r2);
    h2 = bf_hi(r2, r3);
}

// MFMA plane-combo steps, smallest products first.
#define SA2_P1(AI, BI)                                                          \
    _Pragma("unroll") for (int oi = 0; oi < 2; oi++) {                          \
        _Pragma("unroll") for (int jf = 0; jf < 4; jf++)                        \
            acc1[oi][jf] = __builtin_amdgcn_mfma_f32_16x16x32_bf16(             \
                aw[oi][AI], bfr[jf][BI], acc1[oi][jf], 0, 0, 0);                \
    }
#define SA1_P1(AI, BI)                                                          \
    _Pragma("unroll") for (int jf = 0; jf < 4; jf++)                            \
        acc1[jf] = __builtin_amdgcn_mfma_f32_16x16x32_bf16(                     \
            aw[AI], bfr[jf][BI], acc1[jf], 0, 0, 0);
#define MM_P2(AI, BI)                                                           \
    _Pragma("unroll") for (int oi = 0; oi < 2; oi++) {                          \
        _Pragma("unroll") for (int jf = 0; jf < 4; jf++)                        \
            acc2[oi][jf] = __builtin_amdgcn_mfma_f32_16x16x32_bf16(             \
                af[jf][AI], gw[oi][BI], acc2[oi][jf], 0, 0, 0);                 \
    }
#define SA3_P(AI, BI)                                                           \
    _Pragma("unroll") for (int oi = 0; oi < 2; oi++) {                          \
        _Pragma("unroll") for (int j = 0; j < 4; j++)                           \
            acc[oi][ph * 4 + j] = __builtin_amdgcn_mfma_f32_16x16x32_bf16(      \
                aw[oi][AI], bfh[j][BI], acc[oi][ph * 4 + j], 0, 0, 0);          \
    }

// Monotonic key for d2, pinned FMA order (identical in both kNN passes).
#define MKKEY(QX, QY, QZ, XS)                                                   \
    ({  float dot_ = fmaf((QZ), yz, fmaf((QY), yy, (QX) * yx));                 \
        float d2_ = fmaf(-2.0f, dot_, (XS) + ys);                               \
        unsigned int kk_ = __float_as_uint(d2_);                                \
        (kk_ & 0x80000000u) ? ~kk_ : (kk_ | 0x80000000u); })

// ---------------------------------------------------------------------------
// Weight fragment precompute: W[O][stride] fp32 (cols off..off+K) -> bf16
// frag planes. Fragment (ks, ot): lane l holds W[ot*16+(l&15)][off+ks*32+
// (l>>4)*8+e], at out[((ks*no + ot)*3 + pl)*512 + l*8 + e].
// ---------------------------------------------------------------------------
__global__ __launch_bounds__(64) void wfrag_kernel(
    const float* __restrict__ W, int K, int stride, int off, int no,
    unsigned short* __restrict__ out) {
    int bid = blockIdx.x;              // = ks*no + ot
    int l = threadIdx.x;
    int ks = bid / no, ot = bid - ks * no;
    int o = ot * 16 + (l & 15);
    int k0 = ks * 32 + (l >> 4) * 8;
    const float* src = W + (size_t)o * stride + off + k0;
    unsigned short h[3][8];
#pragma unroll
    for (int e = 0; e < 8; e++) split3(src[e], h[0][e], h[1][e], h[2][e]);
#pragma unroll
    for (int p = 0; p < 3; p++) {
        s8v v;
#pragma unroll
        for (int e = 0; e < 8; e++) v[e] = (short)h[p][e];
        *(s8v*)(out + ((size_t)(bid * 3 + p) * 64 + l) * 8) = v;
    }
}

// ---------------------------------------------------------------------------
// kNN v2 (unchanged from round 8): 4 queries/block, hist + classify passes.
// ---------------------------------------------------------------------------
__global__ __launch_bounds__(256) void knn4_kernel(
    const float* __restrict__ x, int N_pts, int K, int P, int* __restrict__ idx_out) {
#define KNN_CAP 192
    int bq = blockIdx.x;
    int pg = P >> 2;
    int b = bq / pg, p0 = (bq - b * pg) * 4;
    const float* xyz = x + (size_t)b * 24576;
    __shared__ unsigned int hist[2][2048];
    __shared__ unsigned int candK[4][KNN_CAP];
    __shared__ int candI[4][KNN_CAP];
    __shared__ int outIdx[4][64];
    __shared__ unsigned int cnts[4][2];
    __shared__ int sB[4], sM[4];
    __shared__ float qcoord[4][4];
    int t = threadIdx.x;
    int w = t >> 6, lane = t & 63;
    for (int i = t; i < 4096; i += 256) ((unsigned int*)hist)[i] = 0u;
    if (t < 8) cnts[t >> 1][t & 1] = 0u;
    float qx[4], qy[4], qz[4], xs[4];
#pragma unroll
    for (int q = 0; q < 4; q++) {
        float a = xyz[p0 + q], c1 = xyz[4096 + p0 + q], c2 = xyz[8192 + p0 + q];
        qx[q] = a; qy[q] = c1; qz[q] = c2;
        xs[q] = fmaf(c2, c2, fmaf(c1, c1, a * a));
    }
    if (t < 4) {
        qcoord[t][0] = qx[t]; qcoord[t][1] = qy[t];
        qcoord[t][2] = qz[t]; qcoord[t][3] = xs[t];
    }
    __syncthreads();
    for (int n = t; n < N_pts; n += 256) {
        float yx = xyz[n], yy = xyz[4096 + n], yz = xyz[8192 + n];
        float ys = fmaf(yz, yz, fmaf(yy, yy, yx * yx));
#pragma unroll
        for (int q = 0; q < 4; q++) {
            unsigned int key = MKKEY(qx[q], qy[q], qz[q], xs[q]);
            atomicAdd(&hist[q >> 1][key >> 21], 1u << ((q & 1) * 16));
        }
    }
    __syncthreads();
    {
        int pair = w >> 1, sh = (w & 1) * 16;
        unsigned int lsum = 0;
        for (int i = 0; i < 32; i++)
            lsum += (hist[pair][lane * 32 + i] >> sh) & 0xFFFFu;
        unsigned int incl = lsum;
        for (int s = 1; s < 64; s <<= 1) {
            unsigned int v = (unsigned int)__shfl_up((int)incl, s);
            if (lane >= s) incl += v;
        }
        unsigned int excl = incl - lsum;
        if (excl < (unsigned)K && excl + lsum >= (unsigned)K) {
            unsigned int cum = excl;
            for (int i = 0; i < 32; i++) {
                unsigned int h = (hist[pair][lane * 32 + i] >> sh) & 0xFFFFu;
                if (cum < (unsigned)K && cum + h >= (unsigned)K) {
                    sB[w] = lane * 32 + i; sM[w] = (int)cum; break;
                }
                cum += h;
            }
        }
    }
    __syncthreads();
    for (int n = t; n < N_pts; n += 256) {
        float yx = xyz[n], yy = xyz[4096 + n], yz = xyz[8192 + n];
        float ys = fmaf(yz, yz, fmaf(yy, yy, yx * yx));
#pragma unroll
        for (int q = 0; q < 4; q++) {
            unsigned int key = MKKEY(qx[q], qy[q], qz[q], xs[q]);
            int bin = (int)(key >> 21);
            int Bq = sB[q];
            if (bin < Bq) {
                outIdx[q][atomicAdd(&cnts[q][0], 1u)] = n;
            } else if (bin == Bq) {
                unsigned int ci = atomicAdd(&cnts[q][1], 1u);
                if (ci < KNN_CAP) { candK[q][ci] = key; candI[q][ci] = n; }
            }
        }
    }
    __syncthreads();
    {
        int nc = (int)cnts[w][1];
        int m = sM[w], r = K - m, Bw = sB[w];
        if (nc <= KNN_CAP) {
            for (int ci = lane; ci < nc; ci += 64) {
                unsigned int ki = candK[w][ci];
                int ii = candI[w][ci];
                int rank = 0;
                for (int j = 0; j < nc; j++) {
                    unsigned int kj = candK[w][j];
                    rank += (kj < ki || (kj == ki && candI[w][j] < ii)) ? 1 : 0;
                }
                if (rank < r) outIdx[w][m + rank] = ii;
            }
        } else {
            float fqx = qcoord[w][0], fqy = qcoord[w][1];
            float fqz = qcoord[w][2], fxs = qcoord[w][3];
            unsigned int lastK = 0u; int lastI = -1;
            for (int rr = 0; rr < r; rr++) {
                unsigned int bk = 0xFFFFFFFFu; int bi = 0x7fffffff;
                for (int n = lane; n < N_pts; n += 64) {
                    float yx = xyz[n], yy = xyz[4096 + n], yz = xyz[8192 + n];
                    float ys = fmaf(yz, yz, fmaf(yy, yy, yx * yx));
                    unsigned int key = MKKEY(fqx, fqy, fqz, fxs);
                    if ((int)(key >> 21) == Bw) {
                        bool gt = (key > lastK) || (key == lastK && n > lastI);
                        if (gt && (key < bk || (key == bk && n < bi))) { bk = key; bi = n; }
                    }
                }
#pragma unroll
                for (int s = 32; s > 0; s >>= 1) {
                    unsigned int ok = (unsigned int)__shfl_xor((int)bk, s);
                    int oi = __shfl_xor(bi, s);
                    if (ok < bk || (ok == bk && oi < bi)) { bk = ok; bi = oi; }
                }
                if (lane == 0) outIdx[w][m + rr] = bi;
                lastK = bk; lastI = bi;
            }
        }
    }
    __syncthreads();
    if (t < 4 * K) {
        int q = t / K, k = t - q * K;
        idx_out[((size_t)(b * P) + p0 + q) * K + k] = outIdx[q][k];
    }
}

// ---------------------------------------------------------------------------
// SA1 precompute (unchanged).
// ---------------------------------------------------------------------------
__global__ __launch_bounds__(256) void sa1_pre_kernel(
    const float* __restrict__ x, const float* __restrict__ w1, const float* __restrict__ b1,
    float* __restrict__ a1t) {
    int bid = blockIdx.x;
    int b = bid >> 5, nt = bid & 31, n0 = nt << 7;
    __shared__ float xsh[6 * 128];
    __shared__ float wt[6 * 68];
    const float* xb = x + (size_t)b * 24576;
    int t = threadIdx.x;
    for (int id = t; id < 768; id += 256) {
        int c = id >> 7, n = id & 127;
        xsh[c * 128 + n] = xb[c * 4096 + n0 + n];
    }
    for (int id = t; id < 384; id += 256) {
        int c = id >> 6, o = id & 63;
        wt[c * 68 + o] = w1[o * 6 + c];
    }
    __syncthreads();
    int o = t & 63, ng = t >> 6;
    float acc[32];
    float bias = b1[o];
#pragma unroll
    for (int j = 0; j < 32; j++) acc[j] = bias;
    for (int c = 0; c < 6; c++) {
        float w = wt[c * 68 + o];
        const float* f = &xsh[c * 128 + ng * 32];
#pragma unroll
        for (int j = 0; j < 32; j++) acc[j] += w * f[j];
    }
#pragma unroll
    for (int j = 0; j < 32; j++)
        a1t[((size_t)b * 4096 + n0 + ng * 32 + j) * 64 + o] = acc[j];
}

// ---------------------------------------------------------------------------
// SA1 MFMA fused v3: dbuf BF staging (1 barrier/kstep) + 1-step prefetch.
// ---------------------------------------------------------------------------
__global__ __launch_bounds__(256) void sa1_mfma_kernel(
    const float* __restrict__ x, const float* __restrict__ a1t,
    const int* __restrict__ idx1, const float* __restrict__ w1,
    const unsigned short* __restrict__ w2f, const float* __restrict__ b2,
    const unsigned short* __restrict__ w3f, const float* __restrict__ b3,
    float* __restrict__ p1) {
    int bp = blockIdx.x;  // 32*256
    int b = bp >> 8, pp = bp & 255, p0 = pp * 2;
    __shared__ float dshq[2][64];
    __shared__ int nbr[64];
    __shared__ unsigned short A1buf[8 * 3 * 64 * 8];  // 24KB; halves double as BF dbuf
    __shared__ float MX[2][128];
    const float* xb = x + (size_t)b * 24576;
    int t = threadIdx.x;
    int w = t >> 6, l = t & 63;
    int n16 = l & 15, og = l >> 4;
    if (t < 64) nbr[t] = idx1[((size_t)b * 512 + p0) * 32 + t];
    if (t < 128) {
        int qi = t >> 6, c = t & 63;
        float qx = xb[p0 + qi], qy = xb[4096 + p0 + qi], qz = xb[8192 + p0 + qi];
        dshq[qi][c] = -(w1[c * 6 + 0] * qx + w1[c * 6 + 1] * qy + w1[c * 6 + 2] * qz);
    }
    __syncthreads();
    int q = w >> 1;
    f4v acc1[4];
#pragma unroll
    for (int jf = 0; jf < 4; jf++) acc1[jf] = (f4v){0.f, 0.f, 0.f, 0.f};
    const float* gsrc = a1t + ((size_t)b * 4096 + nbr[w * 16 + n16]) * 64 + og * 8;
    f4v nv0 = *(const f4v*)(gsrc);
    f4v nv1 = *(const f4v*)(gsrc + 4);
    s8v nw[3];
    {
        const s8v* wr = (const s8v*)w2f;
#pragma unroll
        for (int pl = 0; pl < 3; pl++) nw[pl] = wr[(w * 3 + pl) * 64 + l];
    }
    for (int ks = 0; ks < 2; ks++) {
        f4v v0 = nv0, v1 = nv1;
        s8v aw[3];
#pragma unroll
        for (int pl = 0; pl < 3; pl++) aw[pl] = nw[pl];
        if (ks < 1) {
            nv0 = *(const f4v*)(gsrc + 32);
            nv1 = *(const f4v*)(gsrc + 36);
            const s8v* wr = (const s8v*)w2f + (size_t)4 * 3 * 64;
#pragma unroll
            for (int pl = 0; pl < 3; pl++) nw[pl] = wr[(w * 3 + pl) * 64 + l];
        }
        unsigned short* BFD = A1buf + (ks & 1) * 6144;
        const float* d = &dshq[q][ks * 32 + og * 8];
        s8v sp0, sp1, sp2;
#pragma unroll
        for (int e = 0; e < 8; e++) {
            float hv = fmaxf(((e < 4) ? v0[e] : v1[e - 4]) + d[e], 0.f);
            unsigned short h0, h1, h2;
            split3(hv, h0, h1, h2);
            sp0[e] = (short)h0; sp1[e] = (short)h1; sp2[e] = (short)h2;
        }
        *(s8v*)&BFD[((w * 3 + 0) * 64 + l) * 8] = sp0;
        *(s8v*)&BFD[((w * 3 + 1) * 64 + l) * 8] = sp1;
        *(s8v*)&BFD[((w * 3 + 2) * 64 + l) * 8] = sp2;
        __syncthreads();
        s8v bfr[4][3];
#pragma unroll
        for (int jf = 0; jf < 4; jf++)
#pragma unroll
            for (int pl = 0; pl < 3; pl++)
                bfr[jf][pl] = *(const s8v*)&BFD[((jf * 3 + pl) * 64 + l) * 8];
        SA1_P1(2, 0) SA1_P1(0, 2) SA1_P1(1, 1)
        SA1_P1(1, 0) SA1_P1(0, 1) SA1_P1(0, 0)
    }
    __syncthreads();  // all waves done reading BF before handoff overwrites
    {
        f4v bv = *(const f4v*)(b2 + w * 16 + og * 4);
        int l2 = n16 + ((w & 1) * 2 + (og >> 1)) * 16;
        int half = og & 1;
#pragma unroll
        for (int jf = 0; jf < 4; jf++) {
            unsigned short hh[3][4];
#pragma unroll
            for (int r = 0; r < 4; r++) {
                float y = fmaxf(acc1[jf][r] + bv[r], 0.f);
                split3(y, hh[0][r], hh[1][r], hh[2][r]);
            }
            int slot = (w >> 1) * 4 + jf;
#pragma unroll
            for (int pl = 0; pl < 3; pl++) {
                unsigned long long pk = (unsigned long long)hh[pl][0] |
                    ((unsigned long long)hh[pl][1] << 16) |
                    ((unsigned long long)hh[pl][2] << 32) |
                    ((unsigned long long)hh[pl][3] << 48);
                *(unsigned long long*)&A1buf[((slot * 3 + pl) * 64 + l2) * 8 + half * 4] = pk;
            }
        }
    }
    __syncthreads();
    f4v acc2[2][4];
#pragma unroll
    for (int oi = 0; oi < 2; oi++)
#pragma unroll
        for (int jf = 0; jf < 4; jf++) acc2[oi][jf] = (f4v){0.f, 0.f, 0.f, 0.f};
    for (int ks2 = 0; ks2 < 2; ks2++) {
        s8v af[4][3];
#pragma unroll
        for (int jf = 0; jf < 4; jf++)
#pragma unroll
            for (int pl = 0; pl < 3; pl++)
                af[jf][pl] = *(const s8v*)&A1buf[(((ks2 * 4 + jf) * 3 + pl) * 64 + l) * 8];
        const s8v* wr = (const s8v*)w3f + (size_t)(ks2 * 8) * 3 * 64;
        s8v gw[2][3];
#pragma unroll
        for (int oi = 0; oi < 2; oi++)
#pragma unroll
            for (int pl = 0; pl < 3; pl++)
                gw[oi][pl] = wr[((w * 2 + oi) * 3 + pl) * 64 + l];
        MM_P2(2, 0) MM_P2(0, 2) MM_P2(1, 1)
        MM_P2(1, 0) MM_P2(0, 1) MM_P2(0, 0)
    }
#pragma unroll
    for (int oi = 0; oi < 2; oi++) {
        float m0 = fmaxf(fmaxf(acc2[oi][0][0], acc2[oi][0][1]),
                         fmaxf(acc2[oi][0][2], acc2[oi][0][3]));
        m0 = fmaxf(m0, fmaxf(fmaxf(acc2[oi][1][0], acc2[oi][1][1]),
                             fmaxf(acc2[oi][1][2], acc2[oi][1][3])));
        float m1 = fmaxf(fmaxf(acc2[oi][2][0], acc2[oi][2][1]),
                         fmaxf(acc2[oi][2][2], acc2[oi][2][3]));
        m1 = fmaxf(m1, fmaxf(fmaxf(acc2[oi][3][0], acc2[oi][3][1]),
                             fmaxf(acc2[oi][3][2], acc2[oi][3][3])));
        m0 = fmaxf(m0, __shfl_xor(m0, 16));
        m0 = fmaxf(m0, __shfl_xor(m0, 32));
        m1 = fmaxf(m1, __shfl_xor(m1, 16));
        m1 = fmaxf(m1, __shfl_xor(m1, 32));
        if (og == 0) {
            MX[0][(w * 2 + oi) * 16 + n16] = m0;
            MX[1][(w * 2 + oi) * 16 + n16] = m1;
        }
    }
    __syncthreads();
    {
        int o = t & 127, qq = t >> 7;
        p1[((size_t)b * 128 + o) * 512 + p0 + qq] = MX[qq][o] + b3[o];
    }
}

// ---------------------------------------------------------------------------
// SA2 precompute (unchanged).
// ---------------------------------------------------------------------------
__global__ __launch_bounds__(256) void sa2_pre_kernel(
    const float* __restrict__ x, const float* __restrict__ p1,
    const float* __restrict__ w1, const float* __restrict__ b1,
    float* __restrict__ a2t) {
    int bid = blockIdx.x;
    int b = bid >> 2, nt = bid & 3, n0 = nt << 7;
    __shared__ float ins[2][16 * 128];
    __shared__ float wt[2][16 * 132];
    const float* xb = x + (size_t)b * 24576;
    const float* p1b = p1 + (size_t)b * 65536;
    int t = threadIdx.x;
    int og = t >> 3, pg = t & 7;
    int o0 = og * 4;
    float acc[4][16];
    {
        float bl[4] = {b1[o0], b1[o0 + 1], b1[o0 + 2], b1[o0 + 3]};
#pragma unroll
        for (int oi = 0; oi < 4; oi++)
#pragma unroll
            for (int j = 0; j < 16; j++) acc[oi][j] = bl[oi];
    }
    for (int id = t; id < 16 * 128; id += 256) {
        int n = id & 127, c = id >> 7;
        ins[0][c * 128 + n] = (c < 3) ? xb[c * 4096 + n0 + n]
                                      : p1b[(size_t)(c - 3) * 512 + n0 + n];
    }
    for (int id = t; id < 2048; id += 256) {
        int c = id & 15, oo = id >> 4;
        wt[0][c * 132 + oo] = w1[oo * 131 + c];
    }
    __syncthreads();
    for (int ch = 0; ch < 9; ch++) {
        int cs = (ch == 8) ? 3 : 16;
        if (ch < 8) {
            int c0n = (ch + 1) * 16;
            int csn = (ch == 7) ? 3 : 16;
            int nb = (ch + 1) & 1;
            for (int id = t; id < csn * 128; id += 256) {
                int n = id & 127, c = id >> 7;
                int cg = c0n + c;
                ins[nb][c * 128 + n] = (cg < 3) ? xb[cg * 4096 + n0 + n]
                                                : p1b[(size_t)(cg - 3) * 512 + n0 + n];
            }
            for (int id = t; id < 2048; id += 256) {
                int c = id & 15, oo = id >> 4;
                if (c < csn) wt[nb][c * 132 + oo] = w1[oo * 131 + c0n + c];
            }
        }
        const float* wb = wt[ch & 1];
        const float* ib = ins[ch & 1];
        for (int cc = 0; cc < cs; cc++) {
            float4 wv = *(const float4*)&wb[cc * 132 + o0];
            float wl[4] = {wv.x, wv.y, wv.z, wv.w};
#pragma unroll
            for (int c4 = 0; c4 < 4; c4++) {
                float4 fv = *(const float4*)&ib[cc * 128 + pg * 4 + c4 * 32];
                float fl[4] = {fv.x, fv.y, fv.z, fv.w};
#pragma unroll
                for (int j = 0; j < 4; j++)
#pragma unroll
                    for (int oi = 0; oi < 4; oi++) acc[oi][c4 * 4 + j] += wl[oi] * fl[j];
            }
        }
        __syncthreads();
    }
#pragma unroll
    for (int c4 = 0; c4 < 4; c4++)
#pragma unroll
        for (int j = 0; j < 4; j++) {
            int n = n0 + pg * 4 + c4 * 32 + j;
            float4 v;
            v.x = acc[0][c4 * 4 + j]; v.y = acc[1][c4 * 4 + j];
            v.z = acc[2][c4 * 4 + j]; v.w = acc[3][c4 * 4 + j];
            *(float4*)&a2t[((size_t)b * 512 + n) * 128 + o0] = v;
        }
}

// ---------------------------------------------------------------------------
// SA2 MFMA fused v3: dbuf BF staging + prefetch; epilogue writes p2 directly
// as next-GEMM B-frag planes (p2f).
// ---------------------------------------------------------------------------
__global__ __launch_bounds__(256) void sa2_mfma_kernel(
    const float* __restrict__ x, const float* __restrict__ a2t,
    const int* __restrict__ idx2, const float* __restrict__ w1,
    const unsigned short* __restrict__ w2f, const float* __restrict__ b2,
    const unsigned short* __restrict__ w3f, const float* __restrict__ b3,
    unsigned short* __restrict__ p2f) {
    int bp = blockIdx.x;  // 32*128
    int b = bp >> 7, p = bp & 127;
    __shared__ float dsh[128];
    __shared__ int nbr[64];
    __shared__ unsigned short A2buf[16 * 3 * 64 * 8];  // 48KB; first 24KB doubles as BF dbuf
    __shared__ float MX[256];
    const float* xb = x + (size_t)b * 24576;
    int t = threadIdx.x;
    int w = t >> 6, l = t & 63;
    int n16 = l & 15, og = l >> 4;
    if (t < 64) nbr[t] = idx2[((size_t)b * 128 + p) * 64 + t];
    if (t < 128) {
        float qx = xb[p], qy = xb[4096 + p], qz = xb[8192 + p];
        dsh[t] = -(w1[t * 131 + 0] * qx + w1[t * 131 + 1] * qy + w1[t * 131 + 2] * qz);
    }
    __syncthreads();
    f4v acc1[2][4];
#pragma unroll
    for (int oi = 0; oi < 2; oi++)
#pragma unroll
        for (int jf = 0; jf < 4; jf++) acc1[oi][jf] = (f4v){0.f, 0.f, 0.f, 0.f};
    const float* gsrc = a2t + ((size_t)b * 512 + nbr[w * 16 + n16]) * 128 + og * 8;
    f4v nv0 = *(const f4v*)(gsrc);
    f4v nv1 = *(const f4v*)(gsrc + 4);
    s8v nw[2][3];
    {
        const s8v* wr = (const s8v*)w2f;
#pragma unroll
        for (int oi = 0; oi < 2; oi++)
#pragma unroll
            for (int pl = 0; pl < 3; pl++)
                nw[oi][pl] = wr[((w * 2 + oi) * 3 + pl) * 64 + l];
    }
    for (int ks = 0; ks < 4; ks++) {
        f4v v0 = nv0, v1 = nv1;
        s8v aw[2][3];
#pragma unroll
        for (int oi = 0; oi < 2; oi++)
#pragma unroll
            for (int pl = 0; pl < 3; pl++) aw[oi][pl] = nw[oi][pl];
        if (ks < 3) {
            nv0 = *(const f4v*)(gsrc + (ks + 1) * 32);
            nv1 = *(const f4v*)(gsrc + (ks + 1) * 32 + 4);
            const s8v* wr = (const s8v*)w2f + (size_t)((ks + 1) * 8) * 3 * 64;
#pragma unroll
            for (int oi = 0; oi < 2; oi++)
#pragma unroll
                for (int pl = 0; pl < 3; pl++)
                    nw[oi][pl] = wr[((w * 2 + oi) * 3 + pl) * 64 + l];
        }
        unsigned short* BFD = A2buf + (ks & 1) * 6144;
        const float* d = &dsh[ks * 32 + og * 8];
        s8v sp0, sp1, sp2;
#pragma unroll
        for (int e = 0; e < 8; e++) {
            float hv = fmaxf(((e < 4) ? v0[e] : v1[e - 4]) + d[e], 0.f);
            unsigned short h0, h1, h2;
            split3(hv, h0, h1, h2);
            sp0[e] = (short)h0; sp1[e] = (short)h1; sp2[e] = (short)h2;
        }
        *(s8v*)&BFD[((w * 3 + 0) * 64 + l) * 8] = sp0;
        *(s8v*)&BFD[((w * 3 + 1) * 64 + l) * 8] = sp1;
        *(s8v*)&BFD[((w * 3 + 2) * 64 + l) * 8] = sp2;
        __syncthreads();
        s8v bfr[4][3];
#pragma unroll
        for (int jf = 0; jf < 4; jf++)
#pragma unroll
            for (int pl = 0; pl < 3; pl++)
                bfr[jf][pl] = *(const s8v*)&BFD[((jf * 3 + pl) * 64 + l) * 8];
        SA2_P1(2, 0) SA2_P1(0, 2) SA2_P1(1, 1)
        SA2_P1(1, 0) SA2_P1(0, 1) SA2_P1(0, 0)
    }
    __syncthreads();  // all waves done reading BF before handoff overwrites
#pragma unroll
    for (int oi = 0; oi < 2; oi++) {
        int ot = w * 2 + oi;
        f4v bv = *(const f4v*)(b2 + ot * 16 + og * 4);
        int l2 = n16 + (oi * 2 + (og >> 1)) * 16;
        int half = og & 1;
#pragma unroll
        for (int jf = 0; jf < 4; jf++) {
            unsigned short hh[3][4];
#pragma unroll
            for (int r = 0; r < 4; r++) {
                float y = fmaxf(acc1[oi][jf][r] + bv[r], 0.f);
                split3(y, hh[0][r], hh[1][r], hh[2][r]);
            }
            int slot = w * 4 + jf;
#pragma unroll
            for (int pl = 0; pl < 3; pl++) {
                unsigned long long pk = (unsigned long long)hh[pl][0] |
                    ((unsigned long long)hh[pl][1] << 16) |
                    ((unsigned long long)hh[pl][2] << 32) |
                    ((unsigned long long)hh[pl][3] << 48);
                *(unsigned long long*)&A2buf[((slot * 3 + pl) * 64 + l2) * 8 + half * 4] = pk;
            }
        }
    }
    __syncthreads();
#pragma unroll
    for (int half2 = 0; half2 < 2; half2++) {
        f4v acc2[2][4];
#pragma unroll
        for (int oi = 0; oi < 2; oi++)
#pragma unroll
            for (int jf = 0; jf < 4; jf++) acc2[oi][jf] = (f4v){0.f, 0.f, 0.f, 0.f};
        for (int ks2 = 0; ks2 < 4; ks2++) {
            s8v af[4][3];
#pragma unroll
            for (int jf = 0; jf < 4; jf++)
#pragma unroll
                for (int pl = 0; pl < 3; pl++)
                    af[jf][pl] = *(const s8v*)&A2buf[(((ks2 * 4 + jf) * 3 + pl) * 64 + l) * 8];
            const s8v* wr = (const s8v*)w3f + (size_t)(ks2 * 16) * 3 * 64;
            s8v gw[2][3];
#pragma unroll
            for (int oi = 0; oi < 2; oi++)
#pragma unroll
                for (int pl = 0; pl < 3; pl++)
                    gw[oi][pl] = wr[((w * 4 + half2 * 2 + oi) * 3 + pl) * 64 + l];
            MM_P2(2, 0) MM_P2(0, 2) MM_P2(1, 1)
            MM_P2(1, 0) MM_P2(0, 1) MM_P2(0, 0)
        }
#pragma unroll
        for (int oi = 0; oi < 2; oi++) {
            float m = -FLT_BIG;
#pragma unroll
            for (int jf = 0; jf < 4; jf++) {
                float mj = fmaxf(fmaxf(acc2[oi][jf][0], acc2[oi][jf][1]),
                                 fmaxf(acc2[oi][jf][2], acc2[oi][jf][3]));
                m = fmaxf(m, mj);
            }
            m = fmaxf(m, __shfl_xor(m, 16));
            m = fmaxf(m, __shfl_xor(m, 32));
            if (og == 0) MX[(w * 4 + half2 * 2 + oi) * 16 + n16] = m;
        }
    }
    __syncthreads();
    {   // write p2 channel t for point p as SA3-layer1 B-frag planes
        float val = MX[t] + b3[t];
        unsigned short h0, h1, h2;
        split3(val, h0, h1, h2);
        int pt = p >> 4;
        int ks = t >> 5, kl = t & 31;
        int l2 = (p & 15) + (kl >> 3) * 16;
        int e = kl & 7;
        size_t fb = (((size_t)b * 64 + ks * 8 + pt) * 3) * 512 + l2 * 8 + e;
        p2f[fb] = h0;
        p2f[fb + 512] = h1;
        p2f[fb + 1024] = h2;
    }
}

// ---------------------------------------------------------------------------
// SA3 GEMM over 128 points, MFMA, frag-plane I/O. 1 wave per block.
// Block = (b, 2 otiles = 32 out channels). acc[2][8 ptiles].
// reduce=0: out = relu(bias + W*H) written as next-layer B-frag planes.
// reduce=1: g[b][o] = max_p(W*H) + bias (no relu).
// ---------------------------------------------------------------------------
__global__ __launch_bounds__(64) void sa3_mfma_kernel(
    const unsigned short* __restrict__ hf_in, const unsigned short* __restrict__ wf,
    const float* __restrict__ bias, int nks, int noCout,
    unsigned short* __restrict__ hf_out, int nksOut,
    float* __restrict__ gout, int reduce) {
    int nb = noCout >> 1;
    int bid = blockIdx.x;
    int b = bid / nb, u = bid - b * nb;
    int ot0 = u * 2;
    int l = threadIdx.x;
    f4v acc[2][8];
#pragma unroll
    for (int oi = 0; oi < 2; oi++)
#pragma unroll
        for (int j = 0; j < 8; j++) acc[oi][j] = (f4v){0.f, 0.f, 0.f, 0.f};
    const unsigned short* hb = hf_in + (size_t)b * nks * 8 * 3 * 512;
    for (int ks = 0; ks < nks; ks++) {
        s8v aw[2][3];
#pragma unroll
        for (int oi = 0; oi < 2; oi++)
#pragma unroll
            for (int pl = 0; pl < 3; pl++)
                aw[oi][pl] = *(const s8v*)&wf[(((size_t)(ks * noCout + ot0 + oi)) * 3 + pl) * 512 + l * 8];
#pragma unroll
        for (int ph = 0; ph < 2; ph++) {
            s8v bfh[4][3];
#pragma unroll
            for (int j = 0; j < 4; j++)
#pragma unroll
                for (int pl = 0; pl < 3; pl++)
                    bfh[j][pl] = *(const s8v*)&hb[(((size_t)(ks * 8 + ph * 4 + j)) * 3 + pl) * 512 + l * 8];
            SA3_P(2, 0) SA3_P(0, 2) SA3_P(1, 1)
            SA3_P(1, 0) SA3_P(0, 1) SA3_P(0, 0)
        }
    }
    if (!reduce) {
#pragma unroll
        for (int oi = 0; oi < 2; oi++) {
            int OT = ot0 + oi;
            f4v bv = *(const f4v*)(bias + OT * 16 + (l >> 4) * 4);
            int ksp = OT >> 1;
            int l2 = (l & 15) + ((OT & 1) * 2 + ((l >> 4) >> 1)) * 16;
            int base4 = ((l >> 4) & 1) * 4;
#pragma unroll
            for (int pt = 0; pt < 8; pt++) {
                unsigned short hh[3][4];
#pragma unroll
                for (int r = 0; r < 4; r++) {
                    float y = fmaxf(acc[oi][pt][r] + bv[r], 0.f);
                    split3(y, hh[0][r], hh[1][r], hh[2][r]);
                }
#pragma unroll
                for (int pl = 0; pl < 3; pl++) {
                    unsigned long long pk = (unsigned long long)hh[pl][0] |
                        ((unsigned long long)hh[pl][1] << 16) |
                        ((unsigned long long)hh[pl][2] << 32) |
                        ((unsigned long long)hh[pl][3] << 48);
                    *(unsigned long long*)&hf_out[
                        (((size_t)b * nksOut * 8 + ksp * 8 + pt) * 3 + pl) * 512 + l2 * 8 + base4] = pk;
                }
            }
        }
    } else {
        int Cout = noCout * 16;
#pragma unroll
        for (int oi = 0; oi < 2; oi++) {
            int OT = ot0 + oi;
#pragma unroll
            for (int r = 0; r < 4; r++) {
                float m = acc[oi][0][r];
#pragma unroll
                for (int pt = 1; pt < 8; pt++) m = fmaxf(m, acc[oi][pt][r]);
                m = fmaxf(m, __shfl_xor(m, 1));
                m = fmaxf(m, __shfl_xor(m, 2));
                m = fmaxf(m, __shfl_xor(m, 4));
                m = fmaxf(m, __shfl_xor(m, 8));
                if ((l & 15) == 0) {
                    int o = OT * 16 + ((l >> 4) << 2) + r;
                    gout[(size_t)b * Cout + o] = m + bias[o];
                }
            }
        }
    }
}

// ---------------------------------------------------------------------------
// Head: FC 1024->512->256->40 (unchanged).
// ---------------------------------------------------------------------------
__global__ __launch_bounds__(256) void head_kernel(
    const float* __restrict__ g,
    const float* __restrict__ fw1, const float* __restrict__ fb1,
    const float* __restrict__ fw2, const float* __restrict__ fb2,
    const float* __restrict__ fw3, const float* __restrict__ fb3,
    float* __restrict__ out) {
    int b = blockIdx.x;
    int t = threadIdx.x;
    __shared__ float gs[1024];
    __shared__ float h1[512];
    __shared__ float h2[256];
    for (int i = t; i < 1024; i += 256) gs[i] = g[(size_t)b * 1024 + i];
    __syncthreads();
    for (int oo = 0; oo < 2; oo++) {
        int o = t + oo * 256;
        float acc = fb1[o];
        const float4* wr = (const float4*)&fw1[(size_t)o * 1024];
        for (int c = 0; c < 256; c++) {
            float4 wv = wr[c];
            acc += wv.x * gs[c * 4] + wv.y * gs[c * 4 + 1] + wv.z * gs[c * 4 + 2] + wv.w * gs[c * 4 + 3];
        }
        h1[o] = fmaxf(acc, 0.f);
    }
    __syncthreads();
    {
        float acc = fb2[t];
        const float4* wr = (const float4*)&fw2[(size_t)t * 512];
        for (int c = 0; c < 128; c++) {
            float4 wv = wr[c];
            acc += wv.x * h1[c * 4] + wv.y * h1[c * 4 + 1] + wv.z * h1[c * 4 + 2] + wv.w * h1[c * 4 + 3];
        }
        h2[t] = fmaxf(acc, 0.f);
    }
    __syncthreads();
    if (t < 40) {
        float acc = fb3[t];
        const float4* wr = (const float4*)&fw3[(size_t)t * 256];
        for (int c = 0; c < 64; c++) {
            float4 wv = wr[c];
            acc += wv.x * h2[c * 4] + wv.y * h2[c * 4 + 1] + wv.z * h2[c * 4 + 2] + wv.w * h2[c * 4 + 3];
        }
        out[b * 40 + t] = acc;
    }
}

extern "C" void kernel_launch(void* const* d_in, const int* in_sizes, int n_in,
                              void* d_out, int out_size, void* d_ws, size_t ws_size,
                              hipStream_t stream) {
    const float* x      = (const float*)d_in[0];
    const float* sa1_w1 = (const float*)d_in[1];
    const float* sa1_b1 = (const float*)d_in[2];
    const float* sa1_w2 = (const float*)d_in[3];
    const float* sa1_b2 = (const float*)d_in[4];
    const float* sa1_w3 = (const float*)d_in[5];
    const float* sa1_b3 = (const float*)d_in[6];
    const float* sa2_w1 = (const float*)d_in[7];
    const float* sa2_b1 = (const float*)d_in[8];
    const float* sa2_w2 = (const float*)d_in[9];
    const float* sa2_b2 = (const float*)d_in[10];
    const float* sa2_w3 = (const float*)d_in[11];
    const float* sa2_b3 = (const float*)d_in[12];
    const float* sa3_w1 = (const float*)d_in[13];
    const float* sa3_b1 = (const float*)d_in[14];
    const float* sa3_w2 = (const float*)d_in[15];
    const float* sa3_b2 = (const float*)d_in[16];
    const float* sa3_w3 = (const float*)d_in[17];
    const float* sa3_b3 = (const float*)d_in[18];
    const float* fc1_w  = (const float*)d_in[19];
    const float* fc1_b  = (const float*)d_in[20];
    const float* fc2_w  = (const float*)d_in[21];
    const float* fc2_b  = (const float*)d_in[22];
    const float* fc3_w  = (const float*)d_in[23];
    const float* fc3_b  = (const float*)d_in[24];

    char* ws = (char*)d_ws;
    const size_t MB = 1048576;
    const size_t KB = 1024;
    // [0, 416KB): SA1/SA2 weight frag planes (written first, read mid-pipeline)
    unsigned short* s1w2f = (unsigned short*)(ws + 0);          //  24 KB
    unsigned short* s1w3f = (unsigned short*)(ws + 32 * KB);    //  48 KB
    unsigned short* s2w2f = (unsigned short*)(ws + 128 * KB);   //  96 KB
    unsigned short* s2w3f = (unsigned short*)(ws + 224 * KB);   // 192 KB (ends 416KB)
    int*   idx1 = (int*)  (ws + 512 * KB);  //  2 MB  [0.5..2.5MB)
    float* a1t  = (float*)(ws + 3 * MB);    // 32 MB  [3..35MB)   dead after sa1_mfma
    float* p1   = (float*)(ws + 35 * MB);   //  8 MB  [35..43MB)  dead after sa2_pre
    int*   idx2 = (int*)  (ws + 3 * MB);    //  1 MB  overlays dead a1t
    float* a2t  = (float*)(ws + 4 * MB);    //  8 MB  [4..12MB)   dead after sa2_mfma
    unsigned short* p2f = (unsigned short*)(ws + 12 * MB);  //  6 MB [12..18MB)
    unsigned short* h1f = (unsigned short*)(ws + 18 * MB);  //  6 MB [18..24MB)
    unsigned short* h2f = (unsigned short*)(ws + 24 * MB);  // 12 MB [24..36MB) (p1 dead)
    float* g = (float*)(ws + 36 * MB);                      // 128 KB [36..36.125MB)
    // SA3 weight frags [36.5..41MB): written after sa2_pre (p1/a1t dead there)
    unsigned short* w1f3 = (unsigned short*)(ws + 36 * MB + 512 * KB);   // 384 KB
    unsigned short* w2f3 = (unsigned short*)(ws + 37 * MB);              // 768 KB
    unsigned short* w3f3 = (unsigned short*)(ws + 38 * MB);              //   3 MB

    // SA1/SA2 weight fragments: grid = (K/32) * (O/16), 64 thr.
    wfrag_kernel<<<2 * 4, 64, 0, stream>>>(sa1_w2, 64, 64, 0, 4, s1w2f);
    wfrag_kernel<<<2 * 8, 64, 0, stream>>>(sa1_w3, 64, 64, 0, 8, s1w3f);
    wfrag_kernel<<<4 * 8, 64, 0, stream>>>(sa2_w2, 128, 128, 0, 8, s2w2f);
    wfrag_kernel<<<4 * 16, 64, 0, stream>>>(sa2_w3, 128, 128, 0, 16, s2w3f);

    knn4_kernel<<<32 * 128, 256, 0, stream>>>(x, 4096, 32, 512, idx1);
    sa1_pre_kernel<<<32 * 32, 256, 0, stream>>>(x, sa1_w1, sa1_b1, a1t);
    sa1_mfma_kernel<<<32 * 256, 256, 0, stream>>>(x, a1t, idx1, sa1_w1,
                                                  s1w2f, sa1_b2, s1w3f, sa1_b3, p1);
    knn4_kernel<<<32 * 32, 256, 0, stream>>>(x, 512, 64, 128, idx2);
    sa2_pre_kernel<<<32 * 4, 256, 0, stream>>>(x, p1, sa2_w1, sa2_b1, a2t);
    // SA3 weight fragments (p1/a1t regions now dead): sa3_w1 skips 3 zero cols.
    wfrag_kernel<<<8 * 16, 64, 0, stream>>>(sa3_w1, 256, 259, 3, 16, w1f3);
    wfrag_kernel<<<8 * 32, 64, 0, stream>>>(sa3_w2, 256, 256, 0, 32, w2f3);
    wfrag_kernel<<<16 * 64, 64, 0, stream>>>(sa3_w3, 512, 512, 0, 64, w3f3);
    sa2_mfma_kernel<<<32 * 128, 256, 0, stream>>>(x, a2t, idx2, sa2_w1,
                                                  s2w2f, sa2_b2, s2w3f, sa2_b3, p2f);
    // SA3 chain, MFMA: 32 out-channels per 1-wave block.
    sa3_mfma_kernel<<<32 * 8, 64, 0, stream>>>(p2f, w1f3, sa3_b1, 8, 16, h1f, 8, nullptr, 0);
    sa3_mfma_kernel<<<32 * 16, 64, 0, stream>>>(h1f, w2f3, sa3_b2, 8, 32, h2f, 16, nullptr, 0);
    sa3_mfma_kernel<<<32 * 32, 64, 0, stream>>>(h2f, w3f3, sa3_b3, 16, 64, nullptr, 0, g, 1);
    head_kernel<<<32, 256, 0, stream>>>(g, fc1_w, fc1_b, fc2_w, fc2_b, fc3_w, fc3_b,
                                        (float*)d_out);
}

// Round 10
// 462.609 us; speedup vs baseline: 2.0290x; 1.1219x over previous
//
#include <hip/hip_runtime.h>
#include <hip/hip_bf16.h>

#define FLT_BIG 3.0e38f

typedef __attribute__((ext_vector_type(8))) short s8v;
typedef __attribute__((ext_vector_type(4))) float f4v;

// ---------------------------------------------------------------------------
// bf16 3-plane split, truncation-based. EXACT: x == x0 + x1 + x2.
// (x0 = top 16 bits; r = x - x0 exact, <=16 mantissa bits; x1 = top 8 of r;
//  r2 = r - x1 exact, <=8 bits -> fits bf16 exactly.)  ~8 VALU ops.
// ---------------------------------------------------------------------------
__device__ inline void split3(float v, unsigned short& h0, unsigned short& h1,
                              unsigned short& h2) {
    unsigned int u = __float_as_uint(v);
    h0 = (unsigned short)(u >> 16);
    float r = v - __uint_as_float(u & 0xFFFF0000u);
    unsigned int ru = __float_as_uint(r);
    h1 = (unsigned short)(ru >> 16);
    float r2 = r - __uint_as_float(ru & 0xFFFF0000u);
    h2 = (unsigned short)(__float_as_uint(r2) >> 16);
}

// MFMA plane-combo steps, smallest products first.
#define SA2_P1(AI, BI)                                                          \
    _Pragma("unroll") for (int oi = 0; oi < 2; oi++) {                          \
        _Pragma("unroll") for (int jf = 0; jf < 4; jf++)                        \
            acc1[oi][jf] = __builtin_amdgcn_mfma_f32_16x16x32_bf16(             \
                aw[oi][AI], bfr[jf][BI], acc1[oi][jf], 0, 0, 0);                \
    }
#define SA1_P1(AI, BI)                                                          \
    _Pragma("unroll") for (int jf = 0; jf < 4; jf++)                            \
        acc1[jf] = __builtin_amdgcn_mfma_f32_16x16x32_bf16(                     \
            aw[AI], bfr[jf][BI], acc1[jf], 0, 0, 0);
#define MM_P2(AI, BI)                                                           \
    _Pragma("unroll") for (int oi = 0; oi < 2; oi++) {                          \
        _Pragma("unroll") for (int jf = 0; jf < 4; jf++)                        \
            acc2[oi][jf] = __builtin_amdgcn_mfma_f32_16x16x32_bf16(             \
                af[jf][AI], gw[oi][BI], acc2[oi][jf], 0, 0, 0);                 \
    }
#define SA3_P(AI, BI)                                                           \
    _Pragma("unroll") for (int oi = 0; oi < 2; oi++) {                          \
        _Pragma("unroll") for (int j = 0; j < 4; j++)                           \
            acc[oi][ph * 4 + j] = __builtin_amdgcn_mfma_f32_16x16x32_bf16(      \
                aw[oi][AI], bfh[j][BI], acc[oi][ph * 4 + j], 0, 0, 0);          \
    }

// Monotonic key for d2, pinned FMA order (identical in both kNN passes).
#define MKKEY(QX, QY, QZ, XS)                                                   \
    ({  float dot_ = fmaf((QZ), yz, fmaf((QY), yy, (QX) * yx));                 \
        float d2_ = fmaf(-2.0f, dot_, (XS) + ys);                               \
        unsigned int kk_ = __float_as_uint(d2_);                                \
        (kk_ & 0x80000000u) ? ~kk_ : (kk_ | 0x80000000u); })

// ---------------------------------------------------------------------------
// Weight fragment precompute: W[O][stride] fp32 (cols off..off+K) -> bf16
// frag planes. Fragment (ks, ot): lane l holds W[ot*16+(l&15)][off+ks*32+
// (l>>4)*8+e], at out[((ks*no + ot)*3 + pl)*512 + l*8 + e].
// ---------------------------------------------------------------------------
__global__ __launch_bounds__(64) void wfrag_kernel(
    const float* __restrict__ W, int K, int stride, int off, int no,
    unsigned short* __restrict__ out) {
    int bid = blockIdx.x;              // = ks*no + ot
    int l = threadIdx.x;
    int ks = bid / no, ot = bid - ks * no;
    int o = ot * 16 + (l & 15);
    int k0 = ks * 32 + (l >> 4) * 8;
    const float* src = W + (size_t)o * stride + off + k0;
    unsigned short h[3][8];
#pragma unroll
    for (int e = 0; e < 8; e++) split3(src[e], h[0][e], h[1][e], h[2][e]);
#pragma unroll
    for (int p = 0; p < 3; p++) {
        s8v v;
#pragma unroll
        for (int e = 0; e < 8; e++) v[e] = (short)h[p][e];
        *(s8v*)(out + ((size_t)(bid * 3 + p) * 64 + l) * 8) = v;
    }
}

// ---------------------------------------------------------------------------
// kNN v2 (unchanged): 4 queries/block, hist + classify passes.
// ---------------------------------------------------------------------------
__global__ __launch_bounds__(256) void knn4_kernel(
    const float* __restrict__ x, int N_pts, int K, int P, int* __restrict__ idx_out) {
#define KNN_CAP 192
    int bq = blockIdx.x;
    int pg = P >> 2;
    int b = bq / pg, p0 = (bq - b * pg) * 4;
    const float* xyz = x + (size_t)b * 24576;
    __shared__ unsigned int hist[2][2048];
    __shared__ unsigned int candK[4][KNN_CAP];
    __shared__ int candI[4][KNN_CAP];
    __shared__ int outIdx[4][64];
    __shared__ unsigned int cnts[4][2];
    __shared__ int sB[4], sM[4];
    __shared__ float qcoord[4][4];
    int t = threadIdx.x;
    int w = t >> 6, lane = t & 63;
    for (int i = t; i < 4096; i += 256) ((unsigned int*)hist)[i] = 0u;
    if (t < 8) cnts[t >> 1][t & 1] = 0u;
    float qx[4], qy[4], qz[4], xs[4];
#pragma unroll
    for (int q = 0; q < 4; q++) {
        float a = xyz[p0 + q], c1 = xyz[4096 + p0 + q], c2 = xyz[8192 + p0 + q];
        qx[q] = a; qy[q] = c1; qz[q] = c2;
        xs[q] = fmaf(c2, c2, fmaf(c1, c1, a * a));
    }
    if (t < 4) {
        qcoord[t][0] = qx[t]; qcoord[t][1] = qy[t];
        qcoord[t][2] = qz[t]; qcoord[t][3] = xs[t];
    }
    __syncthreads();
    for (int n = t; n < N_pts; n += 256) {
        float yx = xyz[n], yy = xyz[4096 + n], yz = xyz[8192 + n];
        float ys = fmaf(yz, yz, fmaf(yy, yy, yx * yx));
#pragma unroll
        for (int q = 0; q < 4; q++) {
            unsigned int key = MKKEY(qx[q], qy[q], qz[q], xs[q]);
            atomicAdd(&hist[q >> 1][key >> 21], 1u << ((q & 1) * 16));
        }
    }
    __syncthreads();
    {
        int pair = w >> 1, sh = (w & 1) * 16;
        unsigned int lsum = 0;
        for (int i = 0; i < 32; i++)
            lsum += (hist[pair][lane * 32 + i] >> sh) & 0xFFFFu;
        unsigned int incl = lsum;
        for (int s = 1; s < 64; s <<= 1) {
            unsigned int v = (unsigned int)__shfl_up((int)incl, s);
            if (lane >= s) incl += v;
        }
        unsigned int excl = incl - lsum;
        if (excl < (unsigned)K && excl + lsum >= (unsigned)K) {
            unsigned int cum = excl;
            for (int i = 0; i < 32; i++) {
                unsigned int h = (hist[pair][lane * 32 + i] >> sh) & 0xFFFFu;
                if (cum < (unsigned)K && cum + h >= (unsigned)K) {
                    sB[w] = lane * 32 + i; sM[w] = (int)cum; break;
                }
                cum += h;
            }
        }
    }
    __syncthreads();
    for (int n = t; n < N_pts; n += 256) {
        float yx = xyz[n], yy = xyz[4096 + n], yz = xyz[8192 + n];
        float ys = fmaf(yz, yz, fmaf(yy, yy, yx * yx));
#pragma unroll
        for (int q = 0; q < 4; q++) {
            unsigned int key = MKKEY(qx[q], qy[q], qz[q], xs[q]);
            int bin = (int)(key >> 21);
            int Bq = sB[q];
            if (bin < Bq) {
                outIdx[q][atomicAdd(&cnts[q][0], 1u)] = n;
            } else if (bin == Bq) {
                unsigned int ci = atomicAdd(&cnts[q][1], 1u);
                if (ci < KNN_CAP) { candK[q][ci] = key; candI[q][ci] = n; }
            }
        }
    }
    __syncthreads();
    {
        int nc = (int)cnts[w][1];
        int m = sM[w], r = K - m, Bw = sB[w];
        if (nc <= KNN_CAP) {
            for (int ci = lane; ci < nc; ci += 64) {
                unsigned int ki = candK[w][ci];
                int ii = candI[w][ci];
                int rank = 0;
                for (int j = 0; j < nc; j++) {
                    unsigned int kj = candK[w][j];
                    rank += (kj < ki || (kj == ki && candI[w][j] < ii)) ? 1 : 0;
                }
                if (rank < r) outIdx[w][m + rank] = ii;
            }
        } else {
            float fqx = qcoord[w][0], fqy = qcoord[w][1];
            float fqz = qcoord[w][2], fxs = qcoord[w][3];
            unsigned int lastK = 0u; int lastI = -1;
            for (int rr = 0; rr < r; rr++) {
                unsigned int bk = 0xFFFFFFFFu; int bi = 0x7fffffff;
                for (int n = lane; n < N_pts; n += 64) {
                    float yx = xyz[n], yy = xyz[4096 + n], yz = xyz[8192 + n];
                    float ys = fmaf(yz, yz, fmaf(yy, yy, yx * yx));
                    unsigned int key = MKKEY(fqx, fqy, fqz, fxs);
                    if ((int)(key >> 21) == Bw) {
                        bool gt = (key > lastK) || (key == lastK && n > lastI);
                        if (gt && (key < bk || (key == bk && n < bi))) { bk = key; bi = n; }
                    }
                }
#pragma unroll
                for (int s = 32; s > 0; s >>= 1) {
                    unsigned int ok = (unsigned int)__shfl_xor((int)bk, s);
                    int oi = __shfl_xor(bi, s);
                    if (ok < bk || (ok == bk && oi < bi)) { bk = ok; bi = oi; }
                }
                if (lane == 0) outIdx[w][m + rr] = bi;
                lastK = bk; lastI = bi;
            }
        }
    }
    __syncthreads();
    if (t < 4 * K) {
        int q = t / K, k = t - q * K;
        idx_out[((size_t)(b * P) + p0 + q) * K + k] = outIdx[q][k];
    }
}

// ---------------------------------------------------------------------------
// SA1 precompute (unchanged).
// ---------------------------------------------------------------------------
__global__ __launch_bounds__(256) void sa1_pre_kernel(
    const float* __restrict__ x, const float* __restrict__ w1, const float* __restrict__ b1,
    float* __restrict__ a1t) {
    int bid = blockIdx.x;
    int b = bid >> 5, nt = bid & 31, n0 = nt << 7;
    __shared__ float xsh[6 * 128];
    __shared__ float wt[6 * 68];
    const float* xb = x + (size_t)b * 24576;
    int t = threadIdx.x;
    for (int id = t; id < 768; id += 256) {
        int c = id >> 7, n = id & 127;
        xsh[c * 128 + n] = xb[c * 4096 + n0 + n];
    }
    for (int id = t; id < 384; id += 256) {
        int c = id >> 6, o = id & 63;
        wt[c * 68 + o] = w1[o * 6 + c];
    }
    __syncthreads();
    int o = t & 63, ng = t >> 6;
    float acc[32];
    float bias = b1[o];
#pragma unroll
    for (int j = 0; j < 32; j++) acc[j] = bias;
    for (int c = 0; c < 6; c++) {
        float w = wt[c * 68 + o];
        const float* f = &xsh[c * 128 + ng * 32];
#pragma unroll
        for (int j = 0; j < 32; j++) acc[j] += w * f[j];
    }
#pragma unroll
    for (int j = 0; j < 32; j++)
        a1t[((size_t)b * 4096 + n0 + ng * 32 + j) * 64 + o] = acc[j];
}

// ---------------------------------------------------------------------------
// SA1 MFMA fused v3 (unchanged structure; split3 now truncation-exact).
// ---------------------------------------------------------------------------
__global__ __launch_bounds__(256) void sa1_mfma_kernel(
    const float* __restrict__ x, const float* __restrict__ a1t,
    const int* __restrict__ idx1, const float* __restrict__ w1,
    const unsigned short* __restrict__ w2f, const float* __restrict__ b2,
    const unsigned short* __restrict__ w3f, const float* __restrict__ b3,
    float* __restrict__ p1) {
    int bp = blockIdx.x;  // 32*256
    int b = bp >> 8, pp = bp & 255, p0 = pp * 2;
    __shared__ float dshq[2][64];
    __shared__ int nbr[64];
    __shared__ unsigned short A1buf[8 * 3 * 64 * 8];  // 24KB; halves double as BF dbuf
    __shared__ float MX[2][128];
    const float* xb = x + (size_t)b * 24576;
    int t = threadIdx.x;
    int w = t >> 6, l = t & 63;
    int n16 = l & 15, og = l >> 4;
    if (t < 64) nbr[t] = idx1[((size_t)b * 512 + p0) * 32 + t];
    if (t < 128) {
        int qi = t >> 6, c = t & 63;
        float qx = xb[p0 + qi], qy = xb[4096 + p0 + qi], qz = xb[8192 + p0 + qi];
        dshq[qi][c] = -(w1[c * 6 + 0] * qx + w1[c * 6 + 1] * qy + w1[c * 6 + 2] * qz);
    }
    __syncthreads();
    int q = w >> 1;
    f4v acc1[4];
#pragma unroll
    for (int jf = 0; jf < 4; jf++) acc1[jf] = (f4v){0.f, 0.f, 0.f, 0.f};
    const float* gsrc = a1t + ((size_t)b * 4096 + nbr[w * 16 + n16]) * 64 + og * 8;
    f4v nv0 = *(const f4v*)(gsrc);
    f4v nv1 = *(const f4v*)(gsrc + 4);
    s8v nw[3];
    {
        const s8v* wr = (const s8v*)w2f;
#pragma unroll
        for (int pl = 0; pl < 3; pl++) nw[pl] = wr[(w * 3 + pl) * 64 + l];
    }
    for (int ks = 0; ks < 2; ks++) {
        f4v v0 = nv0, v1 = nv1;
        s8v aw[3];
#pragma unroll
        for (int pl = 0; pl < 3; pl++) aw[pl] = nw[pl];
        if (ks < 1) {
            nv0 = *(const f4v*)(gsrc + 32);
            nv1 = *(const f4v*)(gsrc + 36);
            const s8v* wr = (const s8v*)w2f + (size_t)4 * 3 * 64;
#pragma unroll
            for (int pl = 0; pl < 3; pl++) nw[pl] = wr[(w * 3 + pl) * 64 + l];
        }
        unsigned short* BFD = A1buf + (ks & 1) * 6144;
        const float* d = &dshq[q][ks * 32 + og * 8];
        s8v sp0, sp1, sp2;
#pragma unroll
        for (int e = 0; e < 8; e++) {
            float hv = fmaxf(((e < 4) ? v0[e] : v1[e - 4]) + d[e], 0.f);
            unsigned short h0, h1, h2;
            split3(hv, h0, h1, h2);
            sp0[e] = (short)h0; sp1[e] = (short)h1; sp2[e] = (short)h2;
        }
        *(s8v*)&BFD[((w * 3 + 0) * 64 + l) * 8] = sp0;
        *(s8v*)&BFD[((w * 3 + 1) * 64 + l) * 8] = sp1;
        *(s8v*)&BFD[((w * 3 + 2) * 64 + l) * 8] = sp2;
        __syncthreads();
        s8v bfr[4][3];
#pragma unroll
        for (int jf = 0; jf < 4; jf++)
#pragma unroll
            for (int pl = 0; pl < 3; pl++)
                bfr[jf][pl] = *(const s8v*)&BFD[((jf * 3 + pl) * 64 + l) * 8];
        SA1_P1(2, 0) SA1_P1(0, 2) SA1_P1(1, 1)
        SA1_P1(1, 0) SA1_P1(0, 1) SA1_P1(0, 0)
    }
    __syncthreads();  // all waves done reading BF before handoff overwrites
    {
        f4v bv = *(const f4v*)(b2 + w * 16 + og * 4);
        int l2 = n16 + ((w & 1) * 2 + (og >> 1)) * 16;
        int half = og & 1;
#pragma unroll
        for (int jf = 0; jf < 4; jf++) {
            unsigned short hh[3][4];
#pragma unroll
            for (int r = 0; r < 4; r++) {
                float y = fmaxf(acc1[jf][r] + bv[r], 0.f);
                split3(y, hh[0][r], hh[1][r], hh[2][r]);
            }
            int slot = (w >> 1) * 4 + jf;
#pragma unroll
            for (int pl = 0; pl < 3; pl++) {
                unsigned long long pk = (unsigned long long)hh[pl][0] |
                    ((unsigned long long)hh[pl][1] << 16) |
                    ((unsigned long long)hh[pl][2] << 32) |
                    ((unsigned long long)hh[pl][3] << 48);
                *(unsigned long long*)&A1buf[((slot * 3 + pl) * 64 + l2) * 8 + half * 4] = pk;
            }
        }
    }
    __syncthreads();
    f4v acc2[2][4];
#pragma unroll
    for (int oi = 0; oi < 2; oi++)
#pragma unroll
        for (int jf = 0; jf < 4; jf++) acc2[oi][jf] = (f4v){0.f, 0.f, 0.f, 0.f};
    for (int ks2 = 0; ks2 < 2; ks2++) {
        s8v af[4][3];
#pragma unroll
        for (int jf = 0; jf < 4; jf++)
#pragma unroll
            for (int pl = 0; pl < 3; pl++)
                af[jf][pl] = *(const s8v*)&A1buf[(((ks2 * 4 + jf) * 3 + pl) * 64 + l) * 8];
        const s8v* wr = (const s8v*)w3f + (size_t)(ks2 * 8) * 3 * 64;
        s8v gw[2][3];
#pragma unroll
        for (int oi = 0; oi < 2; oi++)
#pragma unroll
            for (int pl = 0; pl < 3; pl++)
                gw[oi][pl] = wr[((w * 2 + oi) * 3 + pl) * 64 + l];
        MM_P2(2, 0) MM_P2(0, 2) MM_P2(1, 1)
        MM_P2(1, 0) MM_P2(0, 1) MM_P2(0, 0)
    }
#pragma unroll
    for (int oi = 0; oi < 2; oi++) {
        float m0 = fmaxf(fmaxf(acc2[oi][0][0], acc2[oi][0][1]),
                         fmaxf(acc2[oi][0][2], acc2[oi][0][3]));
        m0 = fmaxf(m0, fmaxf(fmaxf(acc2[oi][1][0], acc2[oi][1][1]),
                             fmaxf(acc2[oi][1][2], acc2[oi][1][3])));
        float m1 = fmaxf(fmaxf(acc2[oi][2][0], acc2[oi][2][1]),
                         fmaxf(acc2[oi][2][2], acc2[oi][2][3]));
        m1 = fmaxf(m1, fmaxf(fmaxf(acc2[oi][3][0], acc2[oi][3][1]),
                             fmaxf(acc2[oi][3][2], acc2[oi][3][3])));
        m0 = fmaxf(m0, __shfl_xor(m0, 16));
        m0 = fmaxf(m0, __shfl_xor(m0, 32));
        m1 = fmaxf(m1, __shfl_xor(m1, 16));
        m1 = fmaxf(m1, __shfl_xor(m1, 32));
        if (og == 0) {
            MX[0][(w * 2 + oi) * 16 + n16] = m0;
            MX[1][(w * 2 + oi) * 16 + n16] = m1;
        }
    }
    __syncthreads();
    {
        int o = t & 127, qq = t >> 7;
        p1[((size_t)b * 128 + o) * 512 + p0 + qq] = MX[qq][o] + b3[o];
    }
}

// ---------------------------------------------------------------------------
// SA2 precompute (unchanged).
// ---------------------------------------------------------------------------
__global__ __launch_bounds__(256) void sa2_pre_kernel(
    const float* __restrict__ x, const float* __restrict__ p1,
    const float* __restrict__ w1, const float* __restrict__ b1,
    float* __restrict__ a2t) {
    int bid = blockIdx.x;
    int b = bid >> 2, nt = bid & 3, n0 = nt << 7;
    __shared__ float ins[2][16 * 128];
    __shared__ float wt[2][16 * 132];
    const float* xb = x + (size_t)b * 24576;
    const float* p1b = p1 + (size_t)b * 65536;
    int t = threadIdx.x;
    int og = t >> 3, pg = t & 7;
    int o0 = og * 4;
    float acc[4][16];
    {
        float bl[4] = {b1[o0], b1[o0 + 1], b1[o0 + 2], b1[o0 + 3]};
#pragma unroll
        for (int oi = 0; oi < 4; oi++)
#pragma unroll
            for (int j = 0; j < 16; j++) acc[oi][j] = bl[oi];
    }
    for (int id = t; id < 16 * 128; id += 256) {
        int n = id & 127, c = id >> 7;
        ins[0][c * 128 + n] = (c < 3) ? xb[c * 4096 + n0 + n]
                                      : p1b[(size_t)(c - 3) * 512 + n0 + n];
    }
    for (int id = t; id < 2048; id += 256) {
        int c = id & 15, oo = id >> 4;
        wt[0][c * 132 + oo] = w1[oo * 131 + c];
    }
    __syncthreads();
    for (int ch = 0; ch < 9; ch++) {
        int cs = (ch == 8) ? 3 : 16;
        if (ch < 8) {
            int c0n = (ch + 1) * 16;
            int csn = (ch == 7) ? 3 : 16;
            int nb = (ch + 1) & 1;
            for (int id = t; id < csn * 128; id += 256) {
                int n = id & 127, c = id >> 7;
                int cg = c0n + c;
                ins[nb][c * 128 + n] = (cg < 3) ? xb[cg * 4096 + n0 + n]
                                                : p1b[(size_t)(cg - 3) * 512 + n0 + n];
            }
            for (int id = t; id < 2048; id += 256) {
                int c = id & 15, oo = id >> 4;
                if (c < csn) wt[nb][c * 132 + oo] = w1[oo * 131 + c0n + c];
            }
        }
        const float* wb = wt[ch & 1];
        const float* ib = ins[ch & 1];
        for (int cc = 0; cc < cs; cc++) {
            float4 wv = *(const float4*)&wb[cc * 132 + o0];
            float wl[4] = {wv.x, wv.y, wv.z, wv.w};
#pragma unroll
            for (int c4 = 0; c4 < 4; c4++) {
                float4 fv = *(const float4*)&ib[cc * 128 + pg * 4 + c4 * 32];
                float fl[4] = {fv.x, fv.y, fv.z, fv.w};
#pragma unroll
                for (int j = 0; j < 4; j++)
#pragma unroll
                    for (int oi = 0; oi < 4; oi++) acc[oi][c4 * 4 + j] += wl[oi] * fl[j];
            }
        }
        __syncthreads();
    }
#pragma unroll
    for (int c4 = 0; c4 < 4; c4++)
#pragma unroll
        for (int j = 0; j < 4; j++) {
            int n = n0 + pg * 4 + c4 * 32 + j;
            float4 v;
            v.x = acc[0][c4 * 4 + j]; v.y = acc[1][c4 * 4 + j];
            v.z = acc[2][c4 * 4 + j]; v.w = acc[3][c4 * 4 + j];
            *(float4*)&a2t[((size_t)b * 512 + n) * 128 + o0] = v;
        }
}

// ---------------------------------------------------------------------------
// SA2 MFMA fused v3 (unchanged structure; split3 now truncation-exact).
// ---------------------------------------------------------------------------
__global__ __launch_bounds__(256) void sa2_mfma_kernel(
    const float* __restrict__ x, const float* __restrict__ a2t,
    const int* __restrict__ idx2, const float* __restrict__ w1,
    const unsigned short* __restrict__ w2f, const float* __restrict__ b2,
    const unsigned short* __restrict__ w3f, const float* __restrict__ b3,
    unsigned short* __restrict__ p2f) {
    int bp = blockIdx.x;  // 32*128
    int b = bp >> 7, p = bp & 127;
    __shared__ float dsh[128];
    __shared__ int nbr[64];
    __shared__ unsigned short A2buf[16 * 3 * 64 * 8];  // 48KB; first 24KB doubles as BF dbuf
    __shared__ float MX[256];
    const float* xb = x + (size_t)b * 24576;
    int t = threadIdx.x;
    int w = t >> 6, l = t & 63;
    int n16 = l & 15, og = l >> 4;
    if (t < 64) nbr[t] = idx2[((size_t)b * 128 + p) * 64 + t];
    if (t < 128) {
        float qx = xb[p], qy = xb[4096 + p], qz = xb[8192 + p];
        dsh[t] = -(w1[t * 131 + 0] * qx + w1[t * 131 + 1] * qy + w1[t * 131 + 2] * qz);
    }
    __syncthreads();
    f4v acc1[2][4];
#pragma unroll
    for (int oi = 0; oi < 2; oi++)
#pragma unroll
        for (int jf = 0; jf < 4; jf++) acc1[oi][jf] = (f4v){0.f, 0.f, 0.f, 0.f};
    const float* gsrc = a2t + ((size_t)b * 512 + nbr[w * 16 + n16]) * 128 + og * 8;
    f4v nv0 = *(const f4v*)(gsrc);
    f4v nv1 = *(const f4v*)(gsrc + 4);
    s8v nw[2][3];
    {
        const s8v* wr = (const s8v*)w2f;
#pragma unroll
        for (int oi = 0; oi < 2; oi++)
#pragma unroll
            for (int pl = 0; pl < 3; pl++)
                nw[oi][pl] = wr[((w * 2 + oi) * 3 + pl) * 64 + l];
    }
    for (int ks = 0; ks < 4; ks++) {
        f4v v0 = nv0, v1 = nv1;
        s8v aw[2][3];
#pragma unroll
        for (int oi = 0; oi < 2; oi++)
#pragma unroll
            for (int pl = 0; pl < 3; pl++) aw[oi][pl] = nw[oi][pl];
        if (ks < 3) {
            nv0 = *(const f4v*)(gsrc + (ks + 1) * 32);
            nv1 = *(const f4v*)(gsrc + (ks + 1) * 32 + 4);
            const s8v* wr = (const s8v*)w2f + (size_t)((ks + 1) * 8) * 3 * 64;
#pragma unroll
            for (int oi = 0; oi < 2; oi++)
#pragma unroll
                for (int pl = 0; pl < 3; pl++)
                    nw[oi][pl] = wr[((w * 2 + oi) * 3 + pl) * 64 + l];
        }
        unsigned short* BFD = A2buf + (ks & 1) * 6144;
        const float* d = &dsh[ks * 32 + og * 8];
        s8v sp0, sp1, sp2;
#pragma unroll
        for (int e = 0; e < 8; e++) {
            float hv = fmaxf(((e < 4) ? v0[e] : v1[e - 4]) + d[e], 0.f);
            unsigned short h0, h1, h2;
            split3(hv, h0, h1, h2);
            sp0[e] = (short)h0; sp1[e] = (short)h1; sp2[e] = (short)h2;
        }
        *(s8v*)&BFD[((w * 3 + 0) * 64 + l) * 8] = sp0;
        *(s8v*)&BFD[((w * 3 + 1) * 64 + l) * 8] = sp1;
        *(s8v*)&BFD[((w * 3 + 2) * 64 + l) * 8] = sp2;
        __syncthreads();
        s8v bfr[4][3];
#pragma unroll
        for (int jf = 0; jf < 4; jf++)
#pragma unroll
            for (int pl = 0; pl < 3; pl++)
                bfr[jf][pl] = *(const s8v*)&BFD[((jf * 3 + pl) * 64 + l) * 8];
        SA2_P1(2, 0) SA2_P1(0, 2) SA2_P1(1, 1)
        SA2_P1(1, 0) SA2_P1(0, 1) SA2_P1(0, 0)
    }
    __syncthreads();  // all waves done reading BF before handoff overwrites
#pragma unroll
    for (int oi = 0; oi < 2; oi++) {
        int ot = w * 2 + oi;
        f4v bv = *(const f4v*)(b2 + ot * 16 + og * 4);
        int l2 = n16 + (oi * 2 + (og >> 1)) * 16;
        int half = og & 1;
#pragma unroll
        for (int jf = 0; jf < 4; jf++) {
            unsigned short hh[3][4];
#pragma unroll
            for (int r = 0; r < 4; r++) {
                float y = fmaxf(acc1[oi][jf][r] + bv[r], 0.f);
                split3(y, hh[0][r], hh[1][r], hh[2][r]);
            }
            int slot = w * 4 + jf;
#pragma unroll
            for (int pl = 0; pl < 3; pl++) {
                unsigned long long pk = (unsigned long long)hh[pl][0] |
                    ((unsigned long long)hh[pl][1] << 16) |
                    ((unsigned long long)hh[pl][2] << 32) |
                    ((unsigned long long)hh[pl][3] << 48);
                *(unsigned long long*)&A2buf[((slot * 3 + pl) * 64 + l2) * 8 + half * 4] = pk;
            }
        }
    }
    __syncthreads();
#pragma unroll
    for (int half2 = 0; half2 < 2; half2++) {
        f4v acc2[2][4];
#pragma unroll
        for (int oi = 0; oi < 2; oi++)
#pragma unroll
            for (int jf = 0; jf < 4; jf++) acc2[oi][jf] = (f4v){0.f, 0.f, 0.f, 0.f};
        for (int ks2 = 0; ks2 < 4; ks2++) {
            s8v af[4][3];
#pragma unroll
            for (int jf = 0; jf < 4; jf++)
#pragma unroll
                for (int pl = 0; pl < 3; pl++)
                    af[jf][pl] = *(const s8v*)&A2buf[(((ks2 * 4 + jf) * 3 + pl) * 64 + l) * 8];
            const s8v* wr = (const s8v*)w3f + (size_t)(ks2 * 16) * 3 * 64;
            s8v gw[2][3];
#pragma unroll
            for (int oi = 0; oi < 2; oi++)
#pragma unroll
                for (int pl = 0; pl < 3; pl++)
                    gw[oi][pl] = wr[((w * 4 + half2 * 2 + oi) * 3 + pl) * 64 + l];
            MM_P2(2, 0) MM_P2(0, 2) MM_P2(1, 1)
            MM_P2(1, 0) MM_P2(0, 1) MM_P2(0, 0)
        }
#pragma unroll
        for (int oi = 0; oi < 2; oi++) {
            float m = -FLT_BIG;
#pragma unroll
            for (int jf = 0; jf < 4; jf++) {
                float mj = fmaxf(fmaxf(acc2[oi][jf][0], acc2[oi][jf][1]),
                                 fmaxf(acc2[oi][jf][2], acc2[oi][jf][3]));
                m = fmaxf(m, mj);
            }
            m = fmaxf(m, __shfl_xor(m, 16));
            m = fmaxf(m, __shfl_xor(m, 32));
            if (og == 0) MX[(w * 4 + half2 * 2 + oi) * 16 + n16] = m;
        }
    }
    __syncthreads();
    {   // write p2 channel t for point p as SA3-layer1 B-frag planes
        float val = MX[t] + b3[t];
        unsigned short h0, h1, h2;
        split3(val, h0, h1, h2);
        int pt = p >> 4;
        int ks = t >> 5, kl = t & 31;
        int l2 = (p & 15) + (kl >> 3) * 16;
        int e = kl & 7;
        size_t fb = (((size_t)b * 64 + ks * 8 + pt) * 3) * 512 + l2 * 8 + e;
        p2f[fb] = h0;
        p2f[fb + 512] = h1;
        p2f[fb + 1024] = h2;
    }
}

// ---------------------------------------------------------------------------
// SA3 GEMM over 128 points, MFMA, frag-plane I/O (unchanged).
// ---------------------------------------------------------------------------
__global__ __launch_bounds__(64) void sa3_mfma_kernel(
    const unsigned short* __restrict__ hf_in, const unsigned short* __restrict__ wf,
    const float* __restrict__ bias, int nks, int noCout,
    unsigned short* __restrict__ hf_out, int nksOut,
    float* __restrict__ gout, int reduce) {
    int nb = noCout >> 1;
    int bid = blockIdx.x;
    int b = bid / nb, u = bid - b * nb;
    int ot0 = u * 2;
    int l = threadIdx.x;
    f4v acc[2][8];
#pragma unroll
    for (int oi = 0; oi < 2; oi++)
#pragma unroll
        for (int j = 0; j < 8; j++) acc[oi][j] = (f4v){0.f, 0.f, 0.f, 0.f};
    const unsigned short* hb = hf_in + (size_t)b * nks * 8 * 3 * 512;
    for (int ks = 0; ks < nks; ks++) {
        s8v aw[2][3];
#pragma unroll
        for (int oi = 0; oi < 2; oi++)
#pragma unroll
            for (int pl = 0; pl < 3; pl++)
                aw[oi][pl] = *(const s8v*)&wf[(((size_t)(ks * noCout + ot0 + oi)) * 3 + pl) * 512 + l * 8];
#pragma unroll
        for (int ph = 0; ph < 2; ph++) {
            s8v bfh[4][3];
#pragma unroll
            for (int j = 0; j < 4; j++)
#pragma unroll
                for (int pl = 0; pl < 3; pl++)
                    bfh[j][pl] = *(const s8v*)&hb[(((size_t)(ks * 8 + ph * 4 + j)) * 3 + pl) * 512 + l * 8];
            SA3_P(2, 0) SA3_P(0, 2) SA3_P(1, 1)
            SA3_P(1, 0) SA3_P(0, 1) SA3_P(0, 0)
        }
    }
    if (!reduce) {
#pragma unroll
        for (int oi = 0; oi < 2; oi++) {
            int OT = ot0 + oi;
            f4v bv = *(const f4v*)(bias + OT * 16 + (l >> 4) * 4);
            int ksp = OT >> 1;
            int l2 = (l & 15) + ((OT & 1) * 2 + ((l >> 4) >> 1)) * 16;
            int base4 = ((l >> 4) & 1) * 4;
#pragma unroll
            for (int pt = 0; pt < 8; pt++) {
                unsigned short hh[3][4];
#pragma unroll
                for (int r = 0; r < 4; r++) {
                    float y = fmaxf(acc[oi][pt][r] + bv[r], 0.f);
                    split3(y, hh[0][r], hh[1][r], hh[2][r]);
                }
#pragma unroll
                for (int pl = 0; pl < 3; pl++) {
                    unsigned long long pk = (unsigned long long)hh[pl][0] |
                        ((unsigned long long)hh[pl][1] << 16) |
                        ((unsigned long long)hh[pl][2] << 32) |
                        ((unsigned long long)hh[pl][3] << 48);
                    *(unsigned long long*)&hf_out[
                        (((size_t)b * nksOut * 8 + ksp * 8 + pt) * 3 + pl) * 512 + l2 * 8 + base4] = pk;
                }
            }
        }
    } else {
        int Cout = noCout * 16;
#pragma unroll
        for (int oi = 0; oi < 2; oi++) {
            int OT = ot0 + oi;
#pragma unroll
            for (int r = 0; r < 4; r++) {
                float m = acc[oi][0][r];
#pragma unroll
                for (int pt = 1; pt < 8; pt++) m = fmaxf(m, acc[oi][pt][r]);
                m = fmaxf(m, __shfl_xor(m, 1));
                m = fmaxf(m, __shfl_xor(m, 2));
                m = fmaxf(m, __shfl_xor(m, 4));
                m = fmaxf(m, __shfl_xor(m, 8));
                if ((l & 15) == 0) {
                    int o = OT * 16 + ((l >> 4) << 2) + r;
                    gout[(size_t)b * Cout + o] = m + bias[o];
                }
            }
        }
    }
}

// ---------------------------------------------------------------------------
// Head part 1: h1 = relu(g @ fw1^T + fb1). Grid 32*8; block = 64 outputs.
// 4 threads per output (segmented dot + shfl reduce).
// ---------------------------------------------------------------------------
__global__ __launch_bounds__(256) void head1_kernel(
    const float* __restrict__ g, const float* __restrict__ fw1,
    const float* __restrict__ fb1, float* __restrict__ h1out) {
    int bid = blockIdx.x;
    int b = bid >> 3, u = bid & 7;
    int o0 = u * 64;
    __shared__ float gs[1024];
    int t = threadIdx.x;
    for (int i = t; i < 1024; i += 256) gs[i] = g[(size_t)b * 1024 + i];
    __syncthreads();
    int o = o0 + (t >> 2), seg = t & 3;
    const float4* wr = (const float4*)&fw1[(size_t)o * 1024 + seg * 256];
    const float* gg0 = &gs[seg * 256];
    float acc = 0.f;
    for (int c = 0; c < 64; c++) {
        float4 wv = wr[c];
        const float* gg = &gg0[c * 4];
        acc += wv.x * gg[0] + wv.y * gg[1] + wv.z * gg[2] + wv.w * gg[3];
    }
    acc += __shfl_down(acc, 1);
    acc += __shfl_down(acc, 2);
    if (seg == 0) h1out[(size_t)b * 512 + o] = fmaxf(acc + fb1[o], 0.f);
}

// ---------------------------------------------------------------------------
// Head part 2: FC 512->256->40. One block per batch.
// ---------------------------------------------------------------------------
__global__ __launch_bounds__(256) void head2_kernel(
    const float* __restrict__ h1in,
    const float* __restrict__ fw2, const float* __restrict__ fb2,
    const float* __restrict__ fw3, const float* __restrict__ fb3,
    float* __restrict__ out) {
    int b = blockIdx.x;
    int t = threadIdx.x;
    __shared__ float h1[512];
    __shared__ float h2[256];
    for (int i = t; i < 512; i += 256) h1[i] = h1in[(size_t)b * 512 + i];
    __syncthreads();
    {
        float acc = fb2[t];
        const float4* wr = (const float4*)&fw2[(size_t)t * 512];
        for (int c = 0; c < 128; c++) {
            float4 wv = wr[c];
            acc += wv.x * h1[c * 4] + wv.y * h1[c * 4 + 1] + wv.z * h1[c * 4 + 2] + wv.w * h1[c * 4 + 3];
        }
        h2[t] = fmaxf(acc, 0.f);
    }
    __syncthreads();
    if (t < 40) {
        float acc = fb3[t];
        const float4* wr = (const float4*)&fw3[(size_t)t * 256];
        for (int c = 0; c < 64; c++) {
            float4 wv = wr[c];
            acc += wv.x * h2[c * 4] + wv.y * h2[c * 4 + 1] + wv.z * h2[c * 4 + 2] + wv.w * h2[c * 4 + 3];
        }
        out[b * 40 + t] = acc;
    }
}

extern "C" void kernel_launch(void* const* d_in, const int* in_sizes, int n_in,
                              void* d_out, int out_size, void* d_ws, size_t ws_size,
                              hipStream_t stream) {
    const float* x      = (const float*)d_in[0];
    const float* sa1_w1 = (const float*)d_in[1];
    const float* sa1_b1 = (const float*)d_in[2];
    const float* sa1_w2 = (const float*)d_in[3];
    const float* sa1_b2 = (const float*)d_in[4];
    const float* sa1_w3 = (const float*)d_in[5];
    const float* sa1_b3 = (const float*)d_in[6];
    const float* sa2_w1 = (const float*)d_in[7];
    const float* sa2_b1 = (const float*)d_in[8];
    const float* sa2_w2 = (const float*)d_in[9];
    const float* sa2_b2 = (const float*)d_in[10];
    const float* sa2_w3 = (const float*)d_in[11];
    const float* sa2_b3 = (const float*)d_in[12];
    const float* sa3_w1 = (const float*)d_in[13];
    const float* sa3_b1 = (const float*)d_in[14];
    const float* sa3_w2 = (const float*)d_in[15];
    const float* sa3_b2 = (const float*)d_in[16];
    const float* sa3_w3 = (const float*)d_in[17];
    const float* sa3_b3 = (const float*)d_in[18];
    const float* fc1_w  = (const float*)d_in[19];
    const float* fc1_b  = (const float*)d_in[20];
    const float* fc2_w  = (const float*)d_in[21];
    const float* fc2_b  = (const float*)d_in[22];
    const float* fc3_w  = (const float*)d_in[23];
    const float* fc3_b  = (const float*)d_in[24];

    char* ws = (char*)d_ws;
    const size_t MB = 1048576;
    const size_t KB = 1024;
    // [0, 416KB): SA1/SA2 weight frag planes
    unsigned short* s1w2f = (unsigned short*)(ws + 0);          //  24 KB
    unsigned short* s1w3f = (unsigned short*)(ws + 32 * KB);    //  48 KB
    unsigned short* s2w2f = (unsigned short*)(ws + 128 * KB);   //  96 KB
    unsigned short* s2w3f = (unsigned short*)(ws + 224 * KB);   // 192 KB (ends 416KB)
    int*   idx1 = (int*)  (ws + 512 * KB);  //  2 MB  [0.5..2.5MB)
    float* a1t  = (float*)(ws + 3 * MB);    // 32 MB  [3..35MB)   dead after sa1_mfma
    float* p1   = (float*)(ws + 35 * MB);   //  8 MB  [35..43MB)  dead after sa2_pre
    int*   idx2 = (int*)  (ws + 3 * MB);    //  1 MB  overlays dead a1t
    float* a2t  = (float*)(ws + 4 * MB);    //  8 MB  [4..12MB)   dead after sa2_mfma
    unsigned short* p2f = (unsigned short*)(ws + 12 * MB);  //  6 MB [12..18MB)
    unsigned short* h1f = (unsigned short*)(ws + 18 * MB);  //  6 MB [18..24MB)
    unsigned short* h2f = (unsigned short*)(ws + 24 * MB);  // 12 MB [24..36MB)
    float* g     = (float*)(ws + 36 * MB);                  // 128 KB [36..36.125MB)
    float* h1hd  = (float*)(ws + 36 * MB + 128 * KB);       //  64 KB [36.125..36.19MB)
    // SA3 weight frags [36.5..41MB): written after sa2_pre (p1/a1t dead there)
    unsigned short* w1f3 = (unsigned short*)(ws + 36 * MB + 512 * KB);   // 384 KB
    unsigned short* w2f3 = (unsigned short*)(ws + 37 * MB);              // 768 KB
    unsigned short* w3f3 = (unsigned short*)(ws + 38 * MB);              //   3 MB

    // SA1/SA2 weight fragments: grid = (K/32) * (O/16), 64 thr.
    wfrag_kernel<<<2 * 4, 64, 0, stream>>>(sa1_w2, 64, 64, 0, 4, s1w2f);
    wfrag_kernel<<<2 * 8, 64, 0, stream>>>(sa1_w3, 64, 64, 0, 8, s1w3f);
    wfrag_kernel<<<4 * 8, 64, 0, stream>>>(sa2_w2, 128, 128, 0, 8, s2w2f);
    wfrag_kernel<<<4 * 16, 64, 0, stream>>>(sa2_w3, 128, 128, 0, 16, s2w3f);

    knn4_kernel<<<32 * 128, 256, 0, stream>>>(x, 4096, 32, 512, idx1);
    sa1_pre_kernel<<<32 * 32, 256, 0, stream>>>(x, sa1_w1, sa1_b1, a1t);
    sa1_mfma_kernel<<<32 * 256, 256, 0, stream>>>(x, a1t, idx1, sa1_w1,
                                                  s1w2f, sa1_b2, s1w3f, sa1_b3, p1);
    knn4_kernel<<<32 * 32, 256, 0, stream>>>(x, 512, 64, 128, idx2);
    sa2_pre_kernel<<<32 * 4, 256, 0, stream>>>(x, p1, sa2_w1, sa2_b1, a2t);
    // SA3 weight fragments (p1/a1t regions now dead): sa3_w1 skips 3 zero cols.
    wfrag_kernel<<<8 * 16, 64, 0, stream>>>(sa3_w1, 256, 259, 3, 16, w1f3);
    wfrag_kernel<<<8 * 32, 64, 0, stream>>>(sa3_w2, 256, 256, 0, 32, w2f3);
    wfrag_kernel<<<16 * 64, 64, 0, stream>>>(sa3_w3, 512, 512, 0, 64, w3f3);
    sa2_mfma_kernel<<<32 * 128, 256, 0, stream>>>(x, a2t, idx2, sa2_w1,
                                                  s2w2f, sa2_b2, s2w3f, sa2_b3, p2f);
    // SA3 chain, MFMA: 32 out-channels per 1-wave block.
    sa3_mfma_kernel<<<32 * 8, 64, 0, stream>>>(p2f, w1f3, sa3_b1, 8, 16, h1f, 8, nullptr, 0);
    sa3_mfma_kernel<<<32 * 16, 64, 0, stream>>>(h1f, w2f3, sa3_b2, 8, 32, h2f, 16, nullptr, 0);
    sa3_mfma_kernel<<<32 * 32, 64, 0, stream>>>(h2f, w3f3, sa3_b3, 16, 64, nullptr, 0, g, 1);
    head1_kernel<<<32 * 8, 256, 0, stream>>>(g, fc1_w, fc1_b, h1hd);
    head2_kernel<<<32, 256, 0, stream>>>(h1hd, fc2_w, fc2_b, fc3_w, fc3_b,
                                         (float*)d_out);
}